// Round 1
// baseline (1197.099 us; speedup 1.0000x reference)
//
#include <hip/hip_runtime.h>

#define B_ 8
#define L_ 2048
#define N_ 512
#define H_ 16
#define C_ 16
#define D_ 64
#define TK_ 45

__device__ __forceinline__ float sigmoidf_(float v) { return 1.f / (1.f + expf(-v)); }

// ---------------- 1. batch stats -> normed [L,N] ----------------
__global__ __launch_bounds__(256) void k_normed(const float* __restrict__ x,
                                                float* __restrict__ normed) {
  int i = blockIdx.x * 256 + threadIdx.x;  // i = l*N + n
  float s = 0.f, ss = 0.f;
#pragma unroll
  for (int b = 0; b < B_; ++b) {
    float v = x[b * (L_ * N_) + i];
    s += v; ss += v * v;
  }
  float mean = s * (1.f / B_);
  float var  = fmaxf((ss - s * mean) * (1.f / (B_ - 1)), 0.f);
  normed[i] = mean / (sqrtf(var) + 1e-5f);  // mask path: std + 1e-5 (outside sqrt)
}

// ---------------- 2. sim = normed^T @ normed  [N,N], K=L ----------------
__global__ __launch_bounds__(256) void k_sim(const float* __restrict__ nrm,
                                             float* __restrict__ sim) {
  __shared__ float As[32][33];
  __shared__ float Bs[32][33];
  int bi = blockIdx.x & 15, bj = blockIdx.x >> 4;
  int t = threadIdx.x, tx = t & 15, ty = t >> 4;
  float acc[2][2] = {{0.f, 0.f}, {0.f, 0.f}};
  for (int kc = 0; kc < L_; kc += 32) {
    for (int e = t; e < 1024; e += 256) {
      int kk = e >> 5, i = e & 31;
      As[kk][i] = nrm[(kc + kk) * N_ + bi * 32 + i];
      Bs[kk][i] = nrm[(kc + kk) * N_ + bj * 32 + i];
    }
    __syncthreads();
#pragma unroll
    for (int kk = 0; kk < 32; ++kk) {
      float a0 = As[kk][ty * 2], a1 = As[kk][ty * 2 + 1];
      float b0 = Bs[kk][tx * 2], b1 = Bs[kk][tx * 2 + 1];
      acc[0][0] += a0 * b0; acc[0][1] += a0 * b1;
      acc[1][0] += a1 * b0; acc[1][1] += a1 * b1;
    }
    __syncthreads();
  }
#pragma unroll
  for (int i = 0; i < 2; ++i)
#pragma unroll
    for (int j = 0; j < 2; ++j)
      sim[(bi * 32 + ty * 2 + i) * N_ + bj * 32 + tx * 2 + j] = acc[i][j];
}

// ---------------- 3. top-45 per row -> idx_t [45][N] ----------------
__global__ __launch_bounds__(256) void k_topk(const float* __restrict__ sim,
                                              int* __restrict__ idx_t) {
  __shared__ float vals[N_];
  __shared__ float rv[256];
  __shared__ int   ri[256];
  int n = blockIdx.x, t = threadIdx.x;
  for (int e = t; e < N_; e += 256) vals[e] = (e == n) ? -3e38f : sim[n * N_ + e];
  __syncthreads();
  for (int k = 0; k < TK_; ++k) {
    float v0 = vals[t], v1 = vals[t + 256];
    float bv = v0; int bi = t;
    if (v1 > v0) { bv = v1; bi = t + 256; }   // tie -> lower index, matches lax.top_k
    rv[t] = bv; ri[t] = bi;
    __syncthreads();
    for (int s = 128; s > 0; s >>= 1) {
      if (t < s) {
        float ov = rv[t + s]; int oi = ri[t + s];
        if (ov > rv[t] || (ov == rv[t] && oi < ri[t])) { rv[t] = ov; ri[t] = oi; }
      }
      __syncthreads();
    }
    if (t == 0) { idx_t[k * N_ + n] = ri[0]; vals[ri[0]] = -3e38f; }
    __syncthreads();
  }
}

// ---------------- 4. router: per-(b,n) stats + Q/K/importance/summary ----------------
__global__ __launch_bounds__(256) void k_router(
    const float* __restrict__ x, const float* __restrict__ var_embed,
    const float* __restrict__ temp_w, const float* __restrict__ temp_b,
    const float* __restrict__ q_w, const float* __restrict__ q_b,
    const float* __restrict__ k_w, const float* __restrict__ k_b,
    const float* __restrict__ imp_w, const float* __restrict__ imp_b,
    float* __restrict__ Q, float* __restrict__ Kv,
    float* __restrict__ imp, float* __restrict__ summary) {
  __shared__ float ps[4][64];
  __shared__ float pss[4][64];
  int b = blockIdx.x >> 3;
  int n0 = (blockIdx.x & 7) * 64;
  int t = threadIdx.x;
  int nn = t & 63, lg = t >> 6;
  {
    int n = n0 + nn;
    float s = 0.f, ss = 0.f;
    for (int l = lg; l < L_; l += 4) {
      float v = x[(b * L_ + l) * N_ + n];
      s += v; ss += v * v;
    }
    ps[lg][nn] = s; pss[lg][nn] = ss;
  }
  __syncthreads();
  if (t < 64) {
    int n = n0 + t;
    float s  = ps[0][t] + ps[1][t] + ps[2][t] + ps[3][t];
    float ss = pss[0][t] + pss[1][t] + pss[2][t] + pss[3][t];
    float mean = s * (1.f / L_);
    float var  = fmaxf((ss - s * mean) * (1.f / (L_ - 1)), 0.f);
    float stdv = sqrtf(var + 1e-5f);            // router path: eps inside sqrt
    summary[b * N_ + n] = mean;
    float vf[32];
#pragma unroll
    for (int i = 0; i < 16; ++i) vf[i] = var_embed[n * 16 + i];
#pragma unroll
    for (int h = 0; h < 16; ++h)
      vf[16 + h] = mean * temp_w[h] + stdv * temp_w[16 + h] + temp_b[h];
#pragma unroll
    for (int h = 0; h < 16; ++h) {
      float qa = q_b[h], ka = k_b[h];
#pragma unroll
      for (int i = 0; i < 32; ++i) {
        qa += vf[i] * q_w[i * 16 + h];
        ka += vf[i] * k_w[i * 16 + h];
      }
      Q[(b * N_ + n) * 16 + h]  = qa;
      Kv[(b * N_ + n) * 16 + h] = ka;
    }
    float ia = imp_b[0];
#pragma unroll
    for (int i = 0; i < 32; ++i) ia += vf[i] * imp_w[i];
    imp[b * N_ + n] = sigmoidf_(ia);
  }
}

// ---------------- 5. cw = softmax(cluster_score, axis=-1) [N,C] ----------------
__global__ __launch_bounds__(64) void k_cw(const float* __restrict__ cs,
                                           float* __restrict__ cw) {
  int n = blockIdx.x * 64 + threadIdx.x;
  if (n >= N_) return;
  float v[16], mx = -3e38f;
#pragma unroll
  for (int c = 0; c < 16; ++c) { v[c] = cs[n * 16 + c]; mx = fmaxf(mx, v[c]); }
  float s = 0.f;
#pragma unroll
  for (int c = 0; c < 16; ++c) { v[c] = expf(v[c] - mx); s += v[c]; }
  float inv = 1.f / s;
#pragma unroll
  for (int c = 0; c < 16; ++c) cw[n * 16 + c] = v[c] * inv;
}

// ---------------- 6. center tokens ct[b, c*64+d] ----------------
__global__ __launch_bounds__(256) void k_ct(const float* __restrict__ summary,
                                            const float* __restrict__ cg_w,
                                            const float* __restrict__ cg_b,
                                            float* __restrict__ ct) {
  int i = blockIdx.x * 256 + threadIdx.x;  // b*1024 + o
  int b = i >> 10, o = i & 1023;
  float a = cg_b[o];
  for (int n = 0; n < N_; ++n) a += summary[b * N_ + n] * cg_w[n * 1024 + o];
  ct[i] = a;
}

// ---------------- 7. ctp = ct @ cp1_w + cp1_b  [B*C, D] ----------------
__global__ __launch_bounds__(256) void k_ctp(const float* __restrict__ ct,
                                             const float* __restrict__ cp1_w,
                                             const float* __restrict__ cp1_b,
                                             float* __restrict__ ctp) {
  int i = blockIdx.x * 256 + threadIdx.x;  // row*64 + d2
  int row = i >> 6, d2 = i & 63;
  float a = cp1_b[d2];
#pragma unroll 8
  for (int d = 0; d < 64; ++d) a += ct[row * 64 + d] * cp1_w[d * 64 + d2];
  ctp[i] = a;
}

// ---------------- 8. cp2 row-sums + bias sum ----------------
__global__ __launch_bounds__(64) void k_cp2s(const float* __restrict__ cp2_w,
                                             const float* __restrict__ cp2_b,
                                             float* __restrict__ cp2s) {
  int t = threadIdx.x;
  float a = 0.f;
#pragma unroll 8
  for (int d = 0; d < 64; ++d) a += cp2_w[t * 64 + d];
  cp2s[t] = a;
  if (t == 0) {
    float bsum = 0.f;
    for (int d = 0; d < 64; ++d) bsum += cp2_b[d];
    cp2s[64] = bsum;
  }
}

// ---------------- 9. attention weights over 45 selected m's ----------------
__global__ __launch_bounds__(64) void k_attn(const float* __restrict__ Q,
                                             const float* __restrict__ Kv,
                                             const int* __restrict__ idx_t,
                                             float* __restrict__ w_t) {
  int bn = blockIdx.x;
  int b = bn >> 9, n = bn & (N_ - 1);
  int j = threadIdx.x;
  float s = -3e38f;
  if (j < TK_) {
    int m = idx_t[j * N_ + n];
    const float* qp = Q + (b * N_ + n) * H_;
    const float* kp = Kv + (b * N_ + m) * H_;
    float a = 0.f;
#pragma unroll
    for (int h = 0; h < H_; ++h) a += qp[h] * kp[h];
    s = a * 0.25f;  // 1/sqrt(16)
  }
  float mx = s;
#pragma unroll
  for (int o = 32; o > 0; o >>= 1) mx = fmaxf(mx, __shfl_xor(mx, o));
  float e = (j < TK_) ? expf(s - mx) : 0.f;
  float sum = e;
#pragma unroll
  for (int o = 32; o > 0; o >>= 1) sum += __shfl_xor(sum, o);
  if (j < TK_) w_t[(b * TK_ + j) * N_ + n] = e / sum;
}

// ---------------- 10. routed + ring_out, 8 l-rows per block ----------------
__global__ __launch_bounds__(256) void k_ring(const float* __restrict__ x,
                                              const float* __restrict__ w_t,
                                              const int* __restrict__ idx_t,
                                              const float* __restrict__ imp,
                                              float* __restrict__ ring) {
  __shared__ float xs[8 * 516];
  int b = blockIdx.x >> 8;
  int l0 = (blockIdx.x & 255) * 8;
  int t = threadIdx.x;
  for (int e = t; e < 8 * N_; e += 256) {
    int r = e >> 9, n = e & 511;
    xs[r * 516 + n] = x[(b * L_ + l0 + r) * N_ + n];
  }
  __syncthreads();
#pragma unroll
  for (int u = 0; u < 2; ++u) {
    int n = t + u * 256;
    float acc[8] = {0.f, 0.f, 0.f, 0.f, 0.f, 0.f, 0.f, 0.f};
    for (int j = 0; j < TK_; ++j) {
      float wv = w_t[(b * TK_ + j) * N_ + n];
      int m = idx_t[j * N_ + n];
#pragma unroll
      for (int r = 0; r < 8; ++r) acc[r] += wv * xs[r * 516 + m];
    }
    float iv = imp[b * N_ + n];
#pragma unroll
    for (int r = 0; r < 8; ++r) {
      float xv = xs[r * 516 + n];
      ring[(b * L_ + l0 + r) * N_ + n] = iv * acc[r] + (1.f - iv) * xv;
    }
  }
}

// ---------------- 11. center path -> center_to_var [B,L,N], 4 l-rows/block ----------------
__global__ __launch_bounds__(256) void k_center(const float* __restrict__ x,
                                                const float* __restrict__ cw,
                                                const float* __restrict__ vp_w,
                                                const float* __restrict__ vp_b,
                                                const float* __restrict__ cp1_w,
                                                const float* __restrict__ ctp,
                                                const float* __restrict__ cp2s,
                                                float* __restrict__ ctv) {
  __shared__ float xs[4][512];
  __shared__ float tpart[4][4][16];
  __shared__ float tls[4][16];
  __shared__ float xcls[4][64];
  __shared__ float xcpls[4][64];
  __shared__ float spart[4][16][4];
  __shared__ float sls[4][16];
  int b = blockIdx.x >> 9;
  int l0 = (blockIdx.x & 511) * 4;
  int t = threadIdx.x;
  for (int e = t; e < 4 * 512; e += 256)
    xs[e >> 9][e & 511] = x[(b * L_ + l0 + (e >> 9)) * N_ + (e & 511)];
  __syncthreads();
  {  // t[c] = sum_n x*cw  (each thread: one (r, slice, c), 128 n's)
    int r = t >> 6, j = t & 63, c = j & 15, sl = j >> 4;
    float a = 0.f;
    for (int n = sl * 128; n < sl * 128 + 128; ++n) a += xs[r][n] * cw[n * 16 + c];
    tpart[r][sl][c] = a;
  }
  __syncthreads();
  if (t < 64) {
    int r = t >> 4, c = t & 15;
    tls[r][c] = tpart[r][0][c] + tpart[r][1][c] + tpart[r][2][c] + tpart[r][3][c];
  }
  __syncthreads();
  {  // xc = t @ varproj + b
    int r = t >> 6, d = t & 63;
    float a = vp_b[d];
#pragma unroll
    for (int c = 0; c < 16; ++c) a += tls[r][c] * vp_w[c * 64 + d];
    xcls[r][d] = a;
  }
  __syncthreads();
  {  // xcp = xc @ cp1
    int r = t >> 6, d2 = t & 63;
    float a = 0.f;
#pragma unroll 8
    for (int d = 0; d < 64; ++d) a += xcls[r][d] * cp1_w[d * 64 + d2];
    xcpls[r][d2] = a;
  }
  __syncthreads();
  {  // s[c] = sum_d gelu(ctp + xcp) * cp2s  (4 threads per (r,c), 16 d's each)
    int r = t >> 6, j = t & 63, c = j >> 2, q = j & 3;
    float a = 0.f;
    for (int d2 = q * 16; d2 < q * 16 + 16; ++d2) {
      float u = ctp[(b * C_ + c) * D_ + d2] + xcpls[r][d2];
      float g = 0.5f * u * (1.f + erff(u * 0.70710678118654752f));
      a += g * cp2s[d2];
    }
    spart[r][c][q] = a;
  }
  __syncthreads();
  if (t < 64) {
    int r = t >> 4, c = t & 15;
    sls[r][c] = spart[r][c][0] + spart[r][c][1] + spart[r][c][2] + spart[r][c][3] + cp2s[64];
  }
  __syncthreads();
#pragma unroll
  for (int r = 0; r < 4; ++r) {
    for (int n = t; n < 512; n += 256) {
      float a = 0.f;
#pragma unroll
      for (int c = 0; c < 16; ++c) a += sls[r][c] * cw[n * 16 + c];
      ctv[(b * L_ + l0 + r) * N_ + n] = a;
    }
  }
}

// ---------------- 12. gate GEMM: fused written in-place over ring ----------------
__global__ __launch_bounds__(256) void k_gate(float* ringbuf,
                                              const float* __restrict__ ctv,
                                              const float* __restrict__ gate_w,
                                              const float* __restrict__ gate_b) {
  __shared__ float As[32][17];
  __shared__ float Ws[16][512];
  int r0 = blockIdx.x * 32;
  int t = threadIdx.x, tx = t & 15, ty = t >> 4;
  float acc[2][32];
#pragma unroll
  for (int i = 0; i < 2; ++i)
#pragma unroll
    for (int j = 0; j < 32; ++j) acc[i][j] = 0.f;
  for (int kc = 0; kc < 64; ++kc) {
    for (int e = t; e < 512; e += 256) {
      int rr = e >> 4, kk = e & 15, k = kc * 16 + kk;
      const float* src = (k < N_) ? ringbuf : ctv;
      As[rr][kk] = src[(r0 + rr) * N_ + (k & (N_ - 1))];
    }
    for (int e = t; e < 8192; e += 256) {
      int kk = e >> 9, n = e & 511;
      Ws[kk][n] = gate_w[(kc * 16 + kk) * N_ + n];
    }
    __syncthreads();
#pragma unroll
    for (int kk = 0; kk < 16; ++kk) {
      float a0 = As[ty * 2][kk], a1 = As[ty * 2 + 1][kk];
#pragma unroll
      for (int j = 0; j < 16; ++j) {
        float2 w = *(const float2*)&Ws[kk][tx * 2 + j * 32];
        acc[0][j * 2]     += a0 * w.x;
        acc[0][j * 2 + 1] += a0 * w.y;
        acc[1][j * 2]     += a1 * w.x;
        acc[1][j * 2 + 1] += a1 * w.y;
      }
    }
    __syncthreads();
  }
#pragma unroll
  for (int i = 0; i < 2; ++i) {
    int row = r0 + ty * 2 + i;
#pragma unroll
    for (int j = 0; j < 16; ++j) {
      int c = tx * 2 + j * 32;
      float2 rg = *(const float2*)&ringbuf[row * N_ + c];
      float2 cv = *(const float2*)&ctv[row * N_ + c];
      float g0 = sigmoidf_(acc[i][j * 2]     + gate_b[c]);
      float g1 = sigmoidf_(acc[i][j * 2 + 1] + gate_b[c + 1]);
      float2 o;
      o.x = g0 * rg.x + (1.f - g0) * cv.x;
      o.y = g1 * rg.y + (1.f - g1) * cv.y;
      *(float2*)&ringbuf[row * N_ + c] = o;
    }
  }
}

// ---------------- 13. fus GEMM + residual + LayerNorm -> out ----------------
__global__ __launch_bounds__(256) void k_fus(const float* __restrict__ fused,
                                             const float* __restrict__ x,
                                             const float* __restrict__ fus_w,
                                             const float* __restrict__ fus_b,
                                             const float* __restrict__ ln_g,
                                             const float* __restrict__ ln_b,
                                             float* __restrict__ out) {
  __shared__ float As[32][17];
  __shared__ float Ws[16][512];
  __shared__ float redS[32][16];
  __shared__ float redQ[32][16];
  __shared__ float mu_s[32], rs_s[32];
  int r0 = blockIdx.x * 32;
  int t = threadIdx.x, tx = t & 15, ty = t >> 4;
  float acc[2][32];
#pragma unroll
  for (int i = 0; i < 2; ++i)
#pragma unroll
    for (int j = 0; j < 32; ++j) acc[i][j] = 0.f;
  for (int kc = 0; kc < 32; ++kc) {
    for (int e = t; e < 512; e += 256) {
      int rr = e >> 4, kk = e & 15;
      As[rr][kk] = fused[(r0 + rr) * N_ + kc * 16 + kk];
    }
    for (int e = t; e < 8192; e += 256) {
      int kk = e >> 9, n = e & 511;
      Ws[kk][n] = fus_w[(kc * 16 + kk) * N_ + n];
    }
    __syncthreads();
#pragma unroll
    for (int kk = 0; kk < 16; ++kk) {
      float a0 = As[ty * 2][kk], a1 = As[ty * 2 + 1][kk];
#pragma unroll
      for (int j = 0; j < 16; ++j) {
        float2 w = *(const float2*)&Ws[kk][tx * 2 + j * 32];
        acc[0][j * 2]     += a0 * w.x;
        acc[0][j * 2 + 1] += a0 * w.y;
        acc[1][j * 2]     += a1 * w.x;
        acc[1][j * 2 + 1] += a1 * w.y;
      }
    }
    __syncthreads();
  }
  float hv[2][32];
  float psum[2] = {0.f, 0.f}, psq[2] = {0.f, 0.f};
#pragma unroll
  for (int i = 0; i < 2; ++i) {
    int row = r0 + ty * 2 + i;
#pragma unroll
    for (int j = 0; j < 16; ++j) {
      int c = tx * 2 + j * 32;
      float2 xv = *(const float2*)&x[row * N_ + c];
      float h0 = acc[i][j * 2]     + fus_b[c]     + xv.x;
      float h1 = acc[i][j * 2 + 1] + fus_b[c + 1] + xv.y;
      hv[i][j * 2] = h0; hv[i][j * 2 + 1] = h1;
      psum[i] += h0 + h1;
      psq[i]  += h0 * h0 + h1 * h1;
    }
  }
  redS[ty * 2][tx] = psum[0];     redS[ty * 2 + 1][tx] = psum[1];
  redQ[ty * 2][tx] = psq[0];      redQ[ty * 2 + 1][tx] = psq[1];
  __syncthreads();
  if (t < 32) {
    float s = 0.f, s2 = 0.f;
#pragma unroll
    for (int q = 0; q < 16; ++q) { s += redS[t][q]; s2 += redQ[t][q]; }
    float mu = s * (1.f / N_);
    float var = s2 * (1.f / N_) - mu * mu;   // biased, torch LayerNorm
    mu_s[t] = mu;
    rs_s[t] = rsqrtf(fmaxf(var, 0.f) + 1e-5f);
  }
  __syncthreads();
#pragma unroll
  for (int i = 0; i < 2; ++i) {
    int row = r0 + ty * 2 + i;
    float mu = mu_s[ty * 2 + i], rs = rs_s[ty * 2 + i];
#pragma unroll
    for (int j = 0; j < 16; ++j) {
      int c = tx * 2 + j * 32;
      float2 o;
      o.x = (hv[i][j * 2]     - mu) * rs * ln_g[c]     + ln_b[c];
      o.y = (hv[i][j * 2 + 1] - mu) * rs * ln_g[c + 1] + ln_b[c + 1];
      *(float2*)&out[row * N_ + c] = o;
    }
  }
}

extern "C" void kernel_launch(void* const* d_in, const int* in_sizes, int n_in,
                              void* d_out, int out_size, void* d_ws, size_t ws_size,
                              hipStream_t stream) {
  (void)in_sizes; (void)n_in; (void)out_size; (void)ws_size;
  const float* x         = (const float*)d_in[0];
  const float* var_embed = (const float*)d_in[1];
  const float* temp_w    = (const float*)d_in[2];
  const float* temp_b    = (const float*)d_in[3];
  const float* q_w       = (const float*)d_in[4];
  const float* q_b       = (const float*)d_in[5];
  const float* k_w       = (const float*)d_in[6];
  const float* k_b       = (const float*)d_in[7];
  const float* imp_w     = (const float*)d_in[8];
  const float* imp_b     = (const float*)d_in[9];
  const float* cluster   = (const float*)d_in[10];
  const float* vp_w      = (const float*)d_in[11];
  const float* vp_b      = (const float*)d_in[12];
  const float* cp1_w     = (const float*)d_in[13];
  const float* cp1_b     = (const float*)d_in[14];
  const float* cp2_w     = (const float*)d_in[15];
  const float* cp2_b     = (const float*)d_in[16];
  const float* cg_w      = (const float*)d_in[17];
  const float* cg_b      = (const float*)d_in[18];
  const float* gate_w    = (const float*)d_in[19];
  const float* gate_b    = (const float*)d_in[20];
  const float* fus_w     = (const float*)d_in[21];
  const float* fus_b     = (const float*)d_in[22];
  const float* ln_g      = (const float*)d_in[23];
  const float* ln_b      = (const float*)d_in[24];
  float* out = (float*)d_out;
  float* ws  = (float*)d_ws;

  // workspace layout (floats)
  float* normed = ws + 0;         // 1,048,576
  float* sim    = ws + 1048576;   //   262,144
  int*   idx_t  = (int*)(ws + 1310720);  // 45*512 ints
  float* Qb     = ws + 1333760;   //    65,536
  float* Kb     = ws + 1399296;   //    65,536
  float* impb   = ws + 1464832;   //     4,096
  float* summ   = ws + 1468928;   //     4,096
  float* w_t    = ws + 1473024;   //   184,320
  float* cw     = ws + 1657344;   //     8,192
  float* ct     = ws + 1665536;   //     8,192
  float* ctp    = ws + 1673728;   //     8,192
  float* cp2s   = ws + 1681920;   //       128
  float* ringb  = ws + 1682048;   // 8,388,608  (later reused as `fused`)
  float* ctvb   = ws + 10070656;  // 8,388,608  -> total ~73.8 MB

  k_normed<<<(L_ * N_) / 256, 256, 0, stream>>>(x, normed);
  k_sim<<<256, 256, 0, stream>>>(normed, sim);
  k_topk<<<N_, 256, 0, stream>>>(sim, idx_t);
  k_router<<<B_ * 8, 256, 0, stream>>>(x, var_embed, temp_w, temp_b, q_w, q_b,
                                       k_w, k_b, imp_w, imp_b, Qb, Kb, impb, summ);
  k_cw<<<8, 64, 0, stream>>>(cluster, cw);
  k_ct<<<(B_ * 1024) / 256, 256, 0, stream>>>(summ, cg_w, cg_b, ct);
  k_ctp<<<(B_ * C_ * D_) / 256, 256, 0, stream>>>(ct, cp1_w, cp1_b, ctp);
  k_cp2s<<<1, 64, 0, stream>>>(cp2_w, cp2_b, cp2s);
  k_attn<<<B_ * N_, 64, 0, stream>>>(Qb, Kb, idx_t, w_t);
  k_ring<<<B_ * (L_ / 8), 256, 0, stream>>>(x, w_t, idx_t, impb, ringb);
  k_center<<<B_ * (L_ / 4), 256, 0, stream>>>(x, cw, vp_w, vp_b, cp1_w, ctp, cp2s, ctvb);
  k_gate<<<(B_ * L_) / 32, 256, 0, stream>>>(ringb, ctvb, gate_w, gate_b);
  k_fus<<<(B_ * L_) / 32, 256, 0, stream>>>(ringb, x, fus_w, fus_b, ln_g, ln_b, out);
}

// Round 2
// 623.132 us; speedup vs baseline: 1.9211x; 1.9211x over previous
//
#include <hip/hip_runtime.h>

#define B_ 8
#define L_ 2048
#define N_ 512
#define H_ 16
#define C_ 16
#define D_ 64
#define TK_ 45

typedef __attribute__((ext_vector_type(8))) short bf16x8;
typedef __attribute__((ext_vector_type(4))) float f32x4;

__device__ __forceinline__ float sigmoidf_(float v) { return 1.f / (1.f + expf(-v)); }

__device__ __forceinline__ short f2bf(float f) {
  union { float f; unsigned u; } v; v.f = f;
  unsigned r = (v.u + 0x7fffu + ((v.u >> 16) & 1u)) >> 16;
  return (short)r;
}
__device__ __forceinline__ float bf2f(short s) {
  union { unsigned u; float f; } v; v.u = ((unsigned)(unsigned short)s) << 16;
  return v.f;
}
__device__ __forceinline__ void gload16(const void* g, void* l) {
  __builtin_amdgcn_global_load_lds((const __attribute__((address_space(1))) unsigned int*)g,
                                   (__attribute__((address_space(3))) unsigned int*)l, 16, 0, 0);
}

// ---------------- 1. batch stats -> normed [L,N] ----------------
__global__ __launch_bounds__(256) void k_normed(const float* __restrict__ x,
                                                float* __restrict__ normed) {
  int i = blockIdx.x * 256 + threadIdx.x;
  float s = 0.f, ss = 0.f;
#pragma unroll
  for (int b = 0; b < B_; ++b) {
    float v = x[b * (L_ * N_) + i];
    s += v; ss += v * v;
  }
  float mean = s * (1.f / B_);
  float var  = fmaxf((ss - s * mean) * (1.f / (B_ - 1)), 0.f);
  normed[i] = mean / (sqrtf(var) + 1e-5f);
}

// ---------------- 2. sim = normed^T @ normed  [N,N], K=L (fp32: feeds top-k) ----------------
__global__ __launch_bounds__(256) void k_sim(const float* __restrict__ nrm,
                                             float* __restrict__ sim) {
  __shared__ float As[32][33];
  __shared__ float Bs[32][33];
  int bi = blockIdx.x & 15, bj = blockIdx.x >> 4;
  int t = threadIdx.x, tx = t & 15, ty = t >> 4;
  float acc[2][2] = {{0.f, 0.f}, {0.f, 0.f}};
  for (int kc = 0; kc < L_; kc += 32) {
    for (int e = t; e < 1024; e += 256) {
      int kk = e >> 5, i = e & 31;
      As[kk][i] = nrm[(kc + kk) * N_ + bi * 32 + i];
      Bs[kk][i] = nrm[(kc + kk) * N_ + bj * 32 + i];
    }
    __syncthreads();
#pragma unroll
    for (int kk = 0; kk < 32; ++kk) {
      float a0 = As[kk][ty * 2], a1 = As[kk][ty * 2 + 1];
      float b0 = Bs[kk][tx * 2], b1 = Bs[kk][tx * 2 + 1];
      acc[0][0] += a0 * b0; acc[0][1] += a0 * b1;
      acc[1][0] += a1 * b0; acc[1][1] += a1 * b1;
    }
    __syncthreads();
  }
#pragma unroll
  for (int i = 0; i < 2; ++i)
#pragma unroll
    for (int j = 0; j < 2; ++j)
      sim[(bi * 32 + ty * 2 + i) * N_ + bj * 32 + tx * 2 + j] = acc[i][j];
}

// ---------------- 3. top-45 per row -> idx_t [45][N] ----------------
__global__ __launch_bounds__(256) void k_topk(const float* __restrict__ sim,
                                              int* __restrict__ idx_t) {
  __shared__ float vals[N_];
  __shared__ float rv[256];
  __shared__ int   ri[256];
  int n = blockIdx.x, t = threadIdx.x;
  for (int e = t; e < N_; e += 256) vals[e] = (e == n) ? -3e38f : sim[n * N_ + e];
  __syncthreads();
  for (int k = 0; k < TK_; ++k) {
    float v0 = vals[t], v1 = vals[t + 256];
    float bv = v0; int bi = t;
    if (v1 > v0) { bv = v1; bi = t + 256; }
    rv[t] = bv; ri[t] = bi;
    __syncthreads();
    for (int s = 128; s > 0; s >>= 1) {
      if (t < s) {
        float ov = rv[t + s]; int oi = ri[t + s];
        if (ov > rv[t] || (ov == rv[t] && oi < ri[t])) { rv[t] = ov; ri[t] = oi; }
      }
      __syncthreads();
    }
    if (t == 0) { idx_t[k * N_ + n] = ri[0]; vals[ri[0]] = -3e38f; }
    __syncthreads();
  }
}

// ---------------- 4. router ----------------
__global__ __launch_bounds__(256) void k_router(
    const float* __restrict__ x, const float* __restrict__ var_embed,
    const float* __restrict__ temp_w, const float* __restrict__ temp_b,
    const float* __restrict__ q_w, const float* __restrict__ q_b,
    const float* __restrict__ k_w, const float* __restrict__ k_b,
    const float* __restrict__ imp_w, const float* __restrict__ imp_b,
    float* __restrict__ Q, float* __restrict__ Kv,
    float* __restrict__ imp, float* __restrict__ summary) {
  __shared__ float ps[4][64];
  __shared__ float pss[4][64];
  int b = blockIdx.x >> 3;
  int n0 = (blockIdx.x & 7) * 64;
  int t = threadIdx.x;
  int nn = t & 63, lg = t >> 6;
  {
    int n = n0 + nn;
    float s = 0.f, ss = 0.f;
    for (int l = lg; l < L_; l += 4) {
      float v = x[(b * L_ + l) * N_ + n];
      s += v; ss += v * v;
    }
    ps[lg][nn] = s; pss[lg][nn] = ss;
  }
  __syncthreads();
  if (t < 64) {
    int n = n0 + t;
    float s  = ps[0][t] + ps[1][t] + ps[2][t] + ps[3][t];
    float ss = pss[0][t] + pss[1][t] + pss[2][t] + pss[3][t];
    float mean = s * (1.f / L_);
    float var  = fmaxf((ss - s * mean) * (1.f / (L_ - 1)), 0.f);
    float stdv = sqrtf(var + 1e-5f);
    summary[b * N_ + n] = mean;
    float vf[32];
#pragma unroll
    for (int i = 0; i < 16; ++i) vf[i] = var_embed[n * 16 + i];
#pragma unroll
    for (int h = 0; h < 16; ++h)
      vf[16 + h] = mean * temp_w[h] + stdv * temp_w[16 + h] + temp_b[h];
#pragma unroll
    for (int h = 0; h < 16; ++h) {
      float qa = q_b[h], ka = k_b[h];
#pragma unroll
      for (int i = 0; i < 32; ++i) {
        qa += vf[i] * q_w[i * 16 + h];
        ka += vf[i] * k_w[i * 16 + h];
      }
      Q[(b * N_ + n) * 16 + h]  = qa;
      Kv[(b * N_ + n) * 16 + h] = ka;
    }
    float ia = imp_b[0];
#pragma unroll
    for (int i = 0; i < 32; ++i) ia += vf[i] * imp_w[i];
    imp[b * N_ + n] = sigmoidf_(ia);
  }
}

// ---------------- 5. cw ----------------
__global__ __launch_bounds__(64) void k_cw(const float* __restrict__ cs,
                                           float* __restrict__ cw) {
  int n = blockIdx.x * 64 + threadIdx.x;
  if (n >= N_) return;
  float v[16], mx = -3e38f;
#pragma unroll
  for (int c = 0; c < 16; ++c) { v[c] = cs[n * 16 + c]; mx = fmaxf(mx, v[c]); }
  float s = 0.f;
#pragma unroll
  for (int c = 0; c < 16; ++c) { v[c] = expf(v[c] - mx); s += v[c]; }
  float inv = 1.f / s;
#pragma unroll
  for (int c = 0; c < 16; ++c) cw[n * 16 + c] = v[c] * inv;
}

// ---------------- 6. center tokens ----------------
__global__ __launch_bounds__(256) void k_ct(const float* __restrict__ summary,
                                            const float* __restrict__ cg_w,
                                            const float* __restrict__ cg_b,
                                            float* __restrict__ ct) {
  int i = blockIdx.x * 256 + threadIdx.x;
  int b = i >> 10, o = i & 1023;
  float a = cg_b[o];
  for (int n = 0; n < N_; ++n) a += summary[b * N_ + n] * cg_w[n * 1024 + o];
  ct[i] = a;
}

// ---------------- 7. ctp ----------------
__global__ __launch_bounds__(256) void k_ctp(const float* __restrict__ ct,
                                             const float* __restrict__ cp1_w,
                                             const float* __restrict__ cp1_b,
                                             float* __restrict__ ctp) {
  int i = blockIdx.x * 256 + threadIdx.x;
  int row = i >> 6, d2 = i & 63;
  float a = cp1_b[d2];
#pragma unroll 8
  for (int d = 0; d < 64; ++d) a += ct[row * 64 + d] * cp1_w[d * 64 + d2];
  ctp[i] = a;
}

// ---------------- 8. cp2 row-sums ----------------
__global__ __launch_bounds__(64) void k_cp2s(const float* __restrict__ cp2_w,
                                             const float* __restrict__ cp2_b,
                                             float* __restrict__ cp2s) {
  int t = threadIdx.x;
  float a = 0.f;
#pragma unroll 8
  for (int d = 0; d < 64; ++d) a += cp2_w[t * 64 + d];
  cp2s[t] = a;
  if (t == 0) {
    float bsum = 0.f;
    for (int d = 0; d < 64; ++d) bsum += cp2_b[d];
    cp2s[64] = bsum;
  }
}

// ---------------- 9. sparse attention weights ----------------
__global__ __launch_bounds__(64) void k_attn(const float* __restrict__ Q,
                                             const float* __restrict__ Kv,
                                             const int* __restrict__ idx_t,
                                             float* __restrict__ w_t) {
  int bn = blockIdx.x;
  int b = bn >> 9, n = bn & (N_ - 1);
  int j = threadIdx.x;
  float s = -3e38f;
  if (j < TK_) {
    int m = idx_t[j * N_ + n];
    const float* qp = Q + (b * N_ + n) * H_;
    const float* kp = Kv + (b * N_ + m) * H_;
    float a = 0.f;
#pragma unroll
    for (int h = 0; h < H_; ++h) a += qp[h] * kp[h];
    s = a * 0.25f;
  }
  float mx = s;
#pragma unroll
  for (int o = 32; o > 0; o >>= 1) mx = fmaxf(mx, __shfl_xor(mx, o));
  float e = (j < TK_) ? expf(s - mx) : 0.f;
  float sum = e;
#pragma unroll
  for (int o = 32; o > 0; o >>= 1) sum += __shfl_xor(sum, o);
  if (j < TK_) w_t[(b * TK_ + j) * N_ + n] = e / sum;
}

// ---------------- 10. ring -> abuf bf16 cols [0,512) ----------------
__global__ __launch_bounds__(256) void k_ring(const float* __restrict__ x,
                                              const float* __restrict__ w_t,
                                              const int* __restrict__ idx_t,
                                              const float* __restrict__ imp,
                                              short* __restrict__ abuf) {
  __shared__ float xs[8 * 516];
  int b = blockIdx.x >> 8;
  int l0 = (blockIdx.x & 255) * 8;
  int t = threadIdx.x;
  for (int e = t; e < 8 * N_; e += 256) {
    int r = e >> 9, n = e & 511;
    xs[r * 516 + n] = x[(b * L_ + l0 + r) * N_ + n];
  }
  __syncthreads();
#pragma unroll
  for (int u = 0; u < 2; ++u) {
    int n = t + u * 256;
    float acc[8] = {0.f, 0.f, 0.f, 0.f, 0.f, 0.f, 0.f, 0.f};
    for (int j = 0; j < TK_; ++j) {
      float wv = w_t[(b * TK_ + j) * N_ + n];
      int m = idx_t[j * N_ + n];
#pragma unroll
      for (int r = 0; r < 8; ++r) acc[r] += wv * xs[r * 516 + m];
    }
    float iv = imp[b * N_ + n];
#pragma unroll
    for (int r = 0; r < 8; ++r) {
      float xv = xs[r * 516 + n];
      abuf[(size_t)(b * L_ + l0 + r) * 1024 + n] = f2bf(iv * acc[r] + (1.f - iv) * xv);
    }
  }
}

// ---------------- 11. center path -> abuf bf16 cols [512,1024) ----------------
__global__ __launch_bounds__(256) void k_center(const float* __restrict__ x,
                                                const float* __restrict__ cw,
                                                const float* __restrict__ vp_w,
                                                const float* __restrict__ vp_b,
                                                const float* __restrict__ cp1_w,
                                                const float* __restrict__ ctp,
                                                const float* __restrict__ cp2s,
                                                short* __restrict__ abuf) {
  __shared__ float xs[4][512];
  __shared__ float tpart[4][4][16];
  __shared__ float tls[4][16];
  __shared__ float xcls[4][64];
  __shared__ float xcpls[4][64];
  __shared__ float spart[4][16][4];
  __shared__ float sls[4][16];
  int b = blockIdx.x >> 9;
  int l0 = (blockIdx.x & 511) * 4;
  int t = threadIdx.x;
  for (int e = t; e < 4 * 512; e += 256)
    xs[e >> 9][e & 511] = x[(b * L_ + l0 + (e >> 9)) * N_ + (e & 511)];
  __syncthreads();
  {
    int r = t >> 6, j = t & 63, c = j & 15, sl = j >> 4;
    float a = 0.f;
    for (int n = sl * 128; n < sl * 128 + 128; ++n) a += xs[r][n] * cw[n * 16 + c];
    tpart[r][sl][c] = a;
  }
  __syncthreads();
  if (t < 64) {
    int r = t >> 4, c = t & 15;
    tls[r][c] = tpart[r][0][c] + tpart[r][1][c] + tpart[r][2][c] + tpart[r][3][c];
  }
  __syncthreads();
  {
    int r = t >> 6, d = t & 63;
    float a = vp_b[d];
#pragma unroll
    for (int c = 0; c < 16; ++c) a += tls[r][c] * vp_w[c * 64 + d];
    xcls[r][d] = a;
  }
  __syncthreads();
  {
    int r = t >> 6, d2 = t & 63;
    float a = 0.f;
#pragma unroll 8
    for (int d = 0; d < 64; ++d) a += xcls[r][d] * cp1_w[d * 64 + d2];
    xcpls[r][d2] = a;
  }
  __syncthreads();
  {
    int r = t >> 6, j = t & 63, c = j >> 2, q = j & 3;
    float a = 0.f;
    for (int d2 = q * 16; d2 < q * 16 + 16; ++d2) {
      float u = ctp[(b * C_ + c) * D_ + d2] + xcpls[r][d2];
      float g = 0.5f * u * (1.f + erff(u * 0.70710678118654752f));
      a += g * cp2s[d2];
    }
    spart[r][c][q] = a;
  }
  __syncthreads();
  if (t < 64) {
    int r = t >> 4, c = t & 15;
    sls[r][c] = spart[r][c][0] + spart[r][c][1] + spart[r][c][2] + spart[r][c][3] + cp2s[64];
  }
  __syncthreads();
#pragma unroll
  for (int r = 0; r < 4; ++r) {
    for (int n = t; n < 512; n += 256) {
      float a = 0.f;
#pragma unroll
      for (int c = 0; c < 16; ++c) a += sls[r][c] * cw[n * 16 + c];
      abuf[(size_t)(b * L_ + l0 + r) * 1024 + 512 + n] = f2bf(a);
    }
  }
}

// ---------------- 12. W [K][N] f32 -> Wt [N][K] bf16 ----------------
__global__ __launch_bounds__(256) void k_wt(const float* __restrict__ W,
                                            short* __restrict__ Wt, int K, int N) {
  __shared__ float tile[32][33];
  int bk = blockIdx.x, bn = blockIdx.y;
  int t = threadIdx.x;
  int c = t & 31, r = t >> 5;
  for (int rr = r; rr < 32; rr += 8)
    tile[rr][c] = W[(bk * 32 + rr) * N + bn * 32 + c];
  __syncthreads();
  for (int rr = r; rr < 32; rr += 8)
    Wt[(bn * 32 + rr) * K + bk * 32 + c] = f2bf(tile[c][rr]);
}

// ---------------- 13. gate GEMM (MFMA): [16384,1024]@[1024,512] + blend ----------------
// A = abuf bf16 [M][1024] (ring | ctv). Wt bf16 [512][1024]. Out: fused_bf [M][512].
// LDS row-major tiles with chunk-XOR swizzle g(r) = (r>>1)&3 applied to BOTH the
// pre-swizzled global source and the ds_read (rule: both-sides-or-neither).
__global__ __launch_bounds__(512) void k_gemm_gate(const short* __restrict__ abuf,
                                                   const short* __restrict__ wt,
                                                   const float* __restrict__ gate_b,
                                                   short* __restrict__ fused_bf) {
  __shared__ __align__(16) short As[128 * 32];  // 8 KB
  __shared__ __align__(16) short Bs[256 * 32];  // 16 KB
  int t = threadIdx.x, lane = t & 63, w = t >> 6;
  int lo = lane & 15, hi = lane >> 4;
  int bm = blockIdx.x >> 1, bn = blockIdx.x & 1;
  int row0 = bm * 128, n0 = bn * 256;
  int wm = w >> 2, wn = w & 3;
  f32x4 acc[4][4] = {};
  // staging sources (pre-swizzled chunk)
  int pA = w * 64 + lane;
  int rA = pA >> 2, cA = (pA & 3) ^ ((rA >> 1) & 3);
  const short* srcA = abuf + (size_t)(row0 + rA) * 1024 + cA * 8;
  int pB0 = w * 128 + lane;
  int rB0 = pB0 >> 2, cB0 = (pB0 & 3) ^ ((rB0 >> 1) & 3);
  const short* srcB0 = wt + (size_t)(n0 + rB0) * 1024 + cB0 * 8;
  int pB1 = pB0 + 64;
  int rB1 = pB1 >> 2, cB1 = (pB1 & 3) ^ ((rB1 >> 1) & 3);
  const short* srcB1 = wt + (size_t)(n0 + rB1) * 1024 + cB1 * 8;
  int gl = (lo >> 1) & 3;
  int foff = (lo * 4 + (hi ^ gl)) * 8;  // short offset of this lane's fragment chunk
  for (int kt = 0; kt < 32; ++kt) {
    gload16(srcA + kt * 32, As + w * 512);
    gload16(srcB0 + kt * 32, Bs + w * 1024);
    gload16(srcB1 + kt * 32, Bs + w * 1024 + 512);
    __syncthreads();
    bf16x8 a[4], b[4];
#pragma unroll
    for (int m = 0; m < 4; ++m)
      a[m] = *(const bf16x8*)(As + (wm * 256 + m * 64) * 8 + foff);
#pragma unroll
    for (int n = 0; n < 4; ++n)
      b[n] = *(const bf16x8*)(Bs + (wn * 256 + n * 64) * 8 + foff);
#pragma unroll
    for (int m = 0; m < 4; ++m)
#pragma unroll
      for (int n = 0; n < 4; ++n)
        acc[m][n] = __builtin_amdgcn_mfma_f32_16x16x32_bf16(a[m], b[n], acc[m][n], 0, 0, 0);
    __syncthreads();
  }
  // epilogue: gate + blend, emit bf16 fused
#pragma unroll
  for (int m = 0; m < 4; ++m) {
    int rbase = row0 + wm * 64 + m * 16 + hi * 4;
#pragma unroll
    for (int j = 0; j < 4; ++j) {
      int row = rbase + j;
#pragma unroll
      for (int n = 0; n < 4; ++n) {
        int col = n0 + wn * 64 + n * 16 + lo;
        float g = sigmoidf_(acc[m][n][j] + gate_b[col]);
        float ringv = bf2f(abuf[(size_t)row * 1024 + col]);
        float ctvv  = bf2f(abuf[(size_t)row * 1024 + 512 + col]);
        fused_bf[(size_t)row * 512 + col] = f2bf(g * ringv + (1.f - g) * ctvv);
      }
    }
  }
}

// ---------------- 14. fus GEMM (MFMA) + residual + LayerNorm ----------------
// BM=64, BN=512 (full row in block -> LN in-block). 8 waves, wave n-slice 64.
__global__ __launch_bounds__(512) void k_gemm_fus(const short* __restrict__ fused_bf,
                                                  const short* __restrict__ wtf,
                                                  const float* __restrict__ x,
                                                  const float* __restrict__ fus_b,
                                                  const float* __restrict__ ln_g,
                                                  const float* __restrict__ ln_b,
                                                  float* __restrict__ out) {
  __shared__ __align__(16) short As[64 * 32];    // 4 KB
  __shared__ __align__(16) short Bs[512 * 32];   // 32 KB
  __shared__ float Ssh[8][64], Qsh[8][64];
  __shared__ float mus[64], rss[64];
  int t = threadIdx.x, lane = t & 63, w = t >> 6;
  int lo = lane & 15, hi = lane >> 4;
  int row0 = blockIdx.x * 64;
  f32x4 acc[4][4] = {};
  int pA = w * 64 + lane;                       // valid for w<4
  int rA = pA >> 2, cA = (pA & 3) ^ ((rA >> 1) & 3);
  const short* srcA = fused_bf + (size_t)(row0 + rA) * 512 + cA * 8;
  int gl = (lo >> 1) & 3;
  int foff = (lo * 4 + (hi ^ gl)) * 8;
  for (int kt = 0; kt < 16; ++kt) {
    if (w < 4) gload16(srcA + kt * 32, As + w * 512);
#pragma unroll
    for (int q = 0; q < 4; ++q) {
      int pB = w * 256 + q * 64 + lane;
      int rB = pB >> 2, cB = (pB & 3) ^ ((rB >> 1) & 3);
      gload16(wtf + (size_t)rB * 512 + kt * 32 + cB * 8, Bs + (w * 256 + q * 64) * 8);
    }
    __syncthreads();
    bf16x8 a[4], b[4];
#pragma unroll
    for (int m = 0; m < 4; ++m)
      a[m] = *(const bf16x8*)(As + (m * 64) * 8 + foff);
#pragma unroll
    for (int n = 0; n < 4; ++n)
      b[n] = *(const bf16x8*)(Bs + (w * 256 + n * 64) * 8 + foff);
#pragma unroll
    for (int m = 0; m < 4; ++m)
#pragma unroll
      for (int n = 0; n < 4; ++n)
        acc[m][n] = __builtin_amdgcn_mfma_f32_16x16x32_bf16(a[m], b[n], acc[m][n], 0, 0, 0);
    __syncthreads();
  }
  // h = acc + fus_b + x; per-row partial sums
#pragma unroll
  for (int m = 0; m < 4; ++m) {
#pragma unroll
    for (int j = 0; j < 4; ++j) {
      int rl = m * 16 + hi * 4 + j;
      int row = row0 + rl;
      float ps = 0.f, pq = 0.f;
#pragma unroll
      for (int n = 0; n < 4; ++n) {
        int col = w * 64 + n * 16 + lo;
        float h = acc[m][n][j] + fus_b[col] + x[(size_t)row * 512 + col];
        acc[m][n][j] = h;
        ps += h; pq += h * h;
      }
#pragma unroll
      for (int o = 1; o < 16; o <<= 1) {
        ps += __shfl_xor(ps, o);
        pq += __shfl_xor(pq, o);
      }
      if (lo == 0) { Ssh[w][rl] = ps; Qsh[w][rl] = pq; }
    }
  }
  __syncthreads();
  if (t < 64) {
    float s = 0.f, q = 0.f;
#pragma unroll
    for (int ww = 0; ww < 8; ++ww) { s += Ssh[ww][t]; q += Qsh[ww][t]; }
    float mu = s * (1.f / N_);
    float var = q * (1.f / N_) - mu * mu;
    mus[t] = mu;
    rss[t] = rsqrtf(fmaxf(var, 0.f) + 1e-5f);
  }
  __syncthreads();
#pragma unroll
  for (int m = 0; m < 4; ++m) {
#pragma unroll
    for (int j = 0; j < 4; ++j) {
      int rl = m * 16 + hi * 4 + j;
      int row = row0 + rl;
      float mu = mus[rl], rs = rss[rl];
#pragma unroll
      for (int n = 0; n < 4; ++n) {
        int col = w * 64 + n * 16 + lo;
        out[(size_t)row * 512 + col] = (acc[m][n][j] - mu) * rs * ln_g[col] + ln_b[col];
      }
    }
  }
}

extern "C" void kernel_launch(void* const* d_in, const int* in_sizes, int n_in,
                              void* d_out, int out_size, void* d_ws, size_t ws_size,
                              hipStream_t stream) {
  (void)in_sizes; (void)n_in; (void)out_size; (void)ws_size;
  const float* x         = (const float*)d_in[0];
  const float* var_embed = (const float*)d_in[1];
  const float* temp_w    = (const float*)d_in[2];
  const float* temp_b    = (const float*)d_in[3];
  const float* q_w       = (const float*)d_in[4];
  const float* q_b       = (const float*)d_in[5];
  const float* k_w       = (const float*)d_in[6];
  const float* k_b       = (const float*)d_in[7];
  const float* imp_w     = (const float*)d_in[8];
  const float* imp_b     = (const float*)d_in[9];
  const float* cluster   = (const float*)d_in[10];
  const float* vp_w      = (const float*)d_in[11];
  const float* vp_b      = (const float*)d_in[12];
  const float* cp1_w     = (const float*)d_in[13];
  const float* cp1_b     = (const float*)d_in[14];
  const float* cp2_w     = (const float*)d_in[15];
  const float* cp2_b     = (const float*)d_in[16];
  const float* cg_w      = (const float*)d_in[17];
  const float* cg_b      = (const float*)d_in[18];
  const float* gate_w    = (const float*)d_in[19];
  const float* gate_b    = (const float*)d_in[20];
  const float* fus_w     = (const float*)d_in[21];
  const float* fus_b     = (const float*)d_in[22];
  const float* ln_g      = (const float*)d_in[23];
  const float* ln_b      = (const float*)d_in[24];
  float* out = (float*)d_out;
  float* ws  = (float*)d_ws;

  // workspace layout (float offsets)
  float* normed = ws + 0;                 // 1,048,576
  float* sim    = ws + 1048576;           //   262,144
  int*   idx_t  = (int*)(ws + 1310720);   //    23,040 ints (pad 24,576)
  float* Qb     = ws + 1335296;           //    65,536
  float* Kb     = ws + 1400832;           //    65,536
  float* impb   = ws + 1466368;           //     4,096
  float* summ   = ws + 1470464;           //     4,096
  float* w_t    = ws + 1474560;           //   184,320
  float* cw     = ws + 1658880;           //     8,192
  float* ct     = ws + 1667072;           //     8,192
  float* ctp    = ws + 1675264;           //     8,192
  float* cp2s   = ws + 1683456;           //       128 (pad 1,024)
  short* abuf     = (short*)(ws + 1684480);   // 16384*1024 bf16 = 32 MB
  short* fused_bf = (short*)(ws + 10073088);  // 16384*512 bf16 = 16 MB
  short* wt_gate  = (short*)(ws + 14267392);  // 512*1024 bf16
  short* wt_fus   = (short*)(ws + 14529536);  // 512*512 bf16  -> total ~58.6 MB

  k_normed<<<(L_ * N_) / 256, 256, 0, stream>>>(x, normed);
  k_sim<<<256, 256, 0, stream>>>(normed, sim);
  k_topk<<<N_, 256, 0, stream>>>(sim, idx_t);
  k_router<<<B_ * 8, 256, 0, stream>>>(x, var_embed, temp_w, temp_b, q_w, q_b,
                                       k_w, k_b, imp_w, imp_b, Qb, Kb, impb, summ);
  k_cw<<<8, 64, 0, stream>>>(cluster, cw);
  k_ct<<<(B_ * 1024) / 256, 256, 0, stream>>>(summ, cg_w, cg_b, ct);
  k_ctp<<<(B_ * C_ * D_) / 256, 256, 0, stream>>>(ct, cp1_w, cp1_b, ctp);
  k_cp2s<<<1, 64, 0, stream>>>(cp2_w, cp2_b, cp2s);
  k_attn<<<B_ * N_, 64, 0, stream>>>(Qb, Kb, idx_t, w_t);
  k_wt<<<dim3(32, 16), 256, 0, stream>>>(gate_w, wt_gate, 1024, 512);
  k_wt<<<dim3(16, 16), 256, 0, stream>>>(fus_w, wt_fus, 512, 512);
  k_ring<<<B_ * (L_ / 8), 256, 0, stream>>>(x, w_t, idx_t, impb, abuf);
  k_center<<<B_ * (L_ / 4), 256, 0, stream>>>(x, cw, vp_w, vp_b, cp1_w, ctp, cp2s, abuf);
  k_gemm_gate<<<256, 512, 0, stream>>>(abuf, wt_gate, gate_b, fused_bf);
  k_gemm_fus<<<256, 512, 0, stream>>>(fused_bf, wt_fus, x, fus_b, ln_g, ln_b, out);
}

// Round 3
// 508.121 us; speedup vs baseline: 2.3559x; 1.2263x over previous
//
#include <hip/hip_runtime.h>

#define B_ 8
#define L_ 2048
#define N_ 512
#define H_ 16
#define C_ 16
#define D_ 64
#define TK_ 45

typedef __attribute__((ext_vector_type(8))) short bf16x8;
typedef __attribute__((ext_vector_type(4))) float f32x4;

__device__ __forceinline__ float sigmoidf_(float v) { return 1.f / (1.f + expf(-v)); }

__device__ __forceinline__ short f2bf(float f) {
  union { float f; unsigned u; } v; v.f = f;
  unsigned r = (v.u + 0x7fffu + ((v.u >> 16) & 1u)) >> 16;
  return (short)r;
}
__device__ __forceinline__ float bf2f(short s) {
  union { unsigned u; float f; } v; v.u = ((unsigned)(unsigned short)s) << 16;
  return v.f;
}
__device__ __forceinline__ void gload16(const void* g, void* l) {
  __builtin_amdgcn_global_load_lds((const __attribute__((address_space(1))) unsigned int*)g,
                                   (__attribute__((address_space(3))) unsigned int*)l, 16, 0, 0);
}

// ---------------- 1. batch stats -> normed [L,N] ----------------
__global__ __launch_bounds__(256) void k_normed(const float* __restrict__ x,
                                                float* __restrict__ normed) {
  int i = blockIdx.x * 256 + threadIdx.x;
  float s = 0.f, ss = 0.f;
#pragma unroll
  for (int b = 0; b < B_; ++b) {
    float v = x[b * (L_ * N_) + i];
    s += v; ss += v * v;
  }
  float mean = s * (1.f / B_);
  float var  = fmaxf((ss - s * mean) * (1.f / (B_ - 1)), 0.f);
  normed[i] = mean / (sqrtf(var) + 1e-5f);
}

// ---------------- 2. sim = normed^T @ normed  [N,N], K=L (fp32: feeds top-k) ----------------
__global__ __launch_bounds__(256) void k_sim(const float* __restrict__ nrm,
                                             float* __restrict__ sim) {
  __shared__ float As[32][33];
  __shared__ float Bs[32][33];
  int bi = blockIdx.x & 15, bj = blockIdx.x >> 4;
  int t = threadIdx.x, tx = t & 15, ty = t >> 4;
  float acc[2][2] = {{0.f, 0.f}, {0.f, 0.f}};
  for (int kc = 0; kc < L_; kc += 32) {
    for (int e = t; e < 1024; e += 256) {
      int kk = e >> 5, i = e & 31;
      As[kk][i] = nrm[(kc + kk) * N_ + bi * 32 + i];
      Bs[kk][i] = nrm[(kc + kk) * N_ + bj * 32 + i];
    }
    __syncthreads();
#pragma unroll
    for (int kk = 0; kk < 32; ++kk) {
      float a0 = As[kk][ty * 2], a1 = As[kk][ty * 2 + 1];
      float b0 = Bs[kk][tx * 2], b1 = Bs[kk][tx * 2 + 1];
      acc[0][0] += a0 * b0; acc[0][1] += a0 * b1;
      acc[1][0] += a1 * b0; acc[1][1] += a1 * b1;
    }
    __syncthreads();
  }
#pragma unroll
  for (int i = 0; i < 2; ++i)
#pragma unroll
    for (int j = 0; j < 2; ++j)
      sim[(bi * 32 + ty * 2 + i) * N_ + bj * 32 + tx * 2 + j] = acc[i][j];
}

// ---------------- 3. top-45 per row -> idx_t [45][N] ----------------
__global__ __launch_bounds__(256) void k_topk(const float* __restrict__ sim,
                                              int* __restrict__ idx_t) {
  __shared__ float vals[N_];
  __shared__ float rv[256];
  __shared__ int   ri[256];
  int n = blockIdx.x, t = threadIdx.x;
  for (int e = t; e < N_; e += 256) vals[e] = (e == n) ? -3e38f : sim[n * N_ + e];
  __syncthreads();
  for (int k = 0; k < TK_; ++k) {
    float v0 = vals[t], v1 = vals[t + 256];
    float bv = v0; int bi = t;
    if (v1 > v0) { bv = v1; bi = t + 256; }
    rv[t] = bv; ri[t] = bi;
    __syncthreads();
    for (int s = 128; s > 0; s >>= 1) {
      if (t < s) {
        float ov = rv[t + s]; int oi = ri[t + s];
        if (ov > rv[t] || (ov == rv[t] && oi < ri[t])) { rv[t] = ov; ri[t] = oi; }
      }
      __syncthreads();
    }
    if (t == 0) { idx_t[k * N_ + n] = ri[0]; vals[ri[0]] = -3e38f; }
    __syncthreads();
  }
}

// ---------------- 4a. router stats partials: 32 l-rows per block ----------------
__global__ __launch_bounds__(256) void k_rstats(const float* __restrict__ x,
                                                float* __restrict__ psum,
                                                float* __restrict__ psq) {
  int b  = blockIdx.x >> 6;
  int ch = blockIdx.x & 63;
  int t = threadIdx.x;
  const float* xp = x + ((size_t)b * L_ + ch * 32) * N_;
#pragma unroll
  for (int u = 0; u < 2; ++u) {
    int n = t + u * 256;
    float s = 0.f, ss = 0.f;
#pragma unroll 8
    for (int r = 0; r < 32; ++r) {
      float v = xp[r * N_ + n];
      s += v; ss += v * v;
    }
    psum[(b * 64 + ch) * N_ + n] = s;
    psq [(b * 64 + ch) * N_ + n] = ss;
  }
}

// ---------------- 4b. finalize: stats -> Q/K/importance/summary ----------------
__global__ __launch_bounds__(256) void k_rfinal(
    const float* __restrict__ psum, const float* __restrict__ psq,
    const float* __restrict__ var_embed,
    const float* __restrict__ temp_w, const float* __restrict__ temp_b,
    const float* __restrict__ q_w, const float* __restrict__ q_b,
    const float* __restrict__ k_w, const float* __restrict__ k_b,
    const float* __restrict__ imp_w, const float* __restrict__ imp_b,
    float* __restrict__ Q, float* __restrict__ Kv,
    float* __restrict__ imp, float* __restrict__ summary) {
  int gid = blockIdx.x * 256 + threadIdx.x;  // 4096 = B*N
  int b = gid >> 9, n = gid & 511;
  float s = 0.f, ss = 0.f;
#pragma unroll 8
  for (int c = 0; c < 64; ++c) {
    s  += psum[(b * 64 + c) * N_ + n];
    ss += psq [(b * 64 + c) * N_ + n];
  }
  float mean = s * (1.f / L_);
  float var  = fmaxf((ss - s * mean) * (1.f / (L_ - 1)), 0.f);
  float stdv = sqrtf(var + 1e-5f);
  summary[b * N_ + n] = mean;
  float vf[32];
#pragma unroll
  for (int i = 0; i < 16; ++i) vf[i] = var_embed[n * 16 + i];
#pragma unroll
  for (int h = 0; h < 16; ++h)
    vf[16 + h] = mean * temp_w[h] + stdv * temp_w[16 + h] + temp_b[h];
#pragma unroll
  for (int h = 0; h < 16; ++h) {
    float qa = q_b[h], ka = k_b[h];
#pragma unroll
    for (int i = 0; i < 32; ++i) {
      qa += vf[i] * q_w[i * 16 + h];
      ka += vf[i] * k_w[i * 16 + h];
    }
    Q[(b * N_ + n) * 16 + h]  = qa;
    Kv[(b * N_ + n) * 16 + h] = ka;
  }
  float ia = imp_b[0];
#pragma unroll
  for (int i = 0; i < 32; ++i) ia += vf[i] * imp_w[i];
  imp[b * N_ + n] = sigmoidf_(ia);
}

// ---------------- 5. cw ----------------
__global__ __launch_bounds__(64) void k_cw(const float* __restrict__ cs,
                                           float* __restrict__ cw) {
  int n = blockIdx.x * 64 + threadIdx.x;
  if (n >= N_) return;
  float v[16], mx = -3e38f;
#pragma unroll
  for (int c = 0; c < 16; ++c) { v[c] = cs[n * 16 + c]; mx = fmaxf(mx, v[c]); }
  float s = 0.f;
#pragma unroll
  for (int c = 0; c < 16; ++c) { v[c] = expf(v[c] - mx); s += v[c]; }
  float inv = 1.f / s;
#pragma unroll
  for (int c = 0; c < 16; ++c) cw[n * 16 + c] = v[c] * inv;
}

// ---------------- 6. center tokens ----------------
__global__ __launch_bounds__(256) void k_ct(const float* __restrict__ summary,
                                            const float* __restrict__ cg_w,
                                            const float* __restrict__ cg_b,
                                            float* __restrict__ ct) {
  int i = blockIdx.x * 256 + threadIdx.x;
  int b = i >> 10, o = i & 1023;
  float a = cg_b[o];
  for (int n = 0; n < N_; ++n) a += summary[b * N_ + n] * cg_w[n * 1024 + o];
  ct[i] = a;
}

// ---------------- 7. ctp ----------------
__global__ __launch_bounds__(256) void k_ctp(const float* __restrict__ ct,
                                             const float* __restrict__ cp1_w,
                                             const float* __restrict__ cp1_b,
                                             float* __restrict__ ctp) {
  int i = blockIdx.x * 256 + threadIdx.x;
  int row = i >> 6, d2 = i & 63;
  float a = cp1_b[d2];
#pragma unroll 8
  for (int d = 0; d < 64; ++d) a += ct[row * 64 + d] * cp1_w[d * 64 + d2];
  ctp[i] = a;
}

// ---------------- 8. cp2 row-sums ----------------
__global__ __launch_bounds__(64) void k_cp2s(const float* __restrict__ cp2_w,
                                             const float* __restrict__ cp2_b,
                                             float* __restrict__ cp2s) {
  int t = threadIdx.x;
  float a = 0.f;
#pragma unroll 8
  for (int d = 0; d < 64; ++d) a += cp2_w[t * 64 + d];
  cp2s[t] = a;
  if (t == 0) {
    float bsum = 0.f;
    for (int d = 0; d < 64; ++d) bsum += cp2_b[d];
    cp2s[64] = bsum;
  }
}

// ---------------- 9. sparse attention weights ----------------
__global__ __launch_bounds__(64) void k_attn(const float* __restrict__ Q,
                                             const float* __restrict__ Kv,
                                             const int* __restrict__ idx_t,
                                             float* __restrict__ w_t) {
  int bn = blockIdx.x;
  int b = bn >> 9, n = bn & (N_ - 1);
  int j = threadIdx.x;
  float s = -3e38f;
  if (j < TK_) {
    int m = idx_t[j * N_ + n];
    const float* qp = Q + (b * N_ + n) * H_;
    const float* kp = Kv + (b * N_ + m) * H_;
    float a = 0.f;
#pragma unroll
    for (int h = 0; h < H_; ++h) a += qp[h] * kp[h];
    s = a * 0.25f;
  }
  float mx = s;
#pragma unroll
  for (int o = 32; o > 0; o >>= 1) mx = fmaxf(mx, __shfl_xor(mx, o));
  float e = (j < TK_) ? expf(s - mx) : 0.f;
  float sum = e;
#pragma unroll
  for (int o = 32; o > 0; o >>= 1) sum += __shfl_xor(sum, o);
  if (j < TK_) w_t[(b * TK_ + j) * N_ + n] = e / sum;
}

// ---------------- 10. ring -> abuf bf16 cols [0,512) ----------------
__global__ __launch_bounds__(256) void k_ring(const float* __restrict__ x,
                                              const float* __restrict__ w_t,
                                              const int* __restrict__ idx_t,
                                              const float* __restrict__ imp,
                                              short* __restrict__ abuf) {
  __shared__ float xs[8 * 516];
  int b = blockIdx.x >> 8;
  int l0 = (blockIdx.x & 255) * 8;
  int t = threadIdx.x;
  for (int e = t; e < 8 * N_; e += 256) {
    int r = e >> 9, n = e & 511;
    xs[r * 516 + n] = x[(b * L_ + l0 + r) * N_ + n];
  }
  __syncthreads();
#pragma unroll
  for (int u = 0; u < 2; ++u) {
    int n = t + u * 256;
    float acc[8] = {0.f, 0.f, 0.f, 0.f, 0.f, 0.f, 0.f, 0.f};
    for (int j = 0; j < TK_; ++j) {
      float wv = w_t[(b * TK_ + j) * N_ + n];
      int m = idx_t[j * N_ + n];
#pragma unroll
      for (int r = 0; r < 8; ++r) acc[r] += wv * xs[r * 516 + m];
    }
    float iv = imp[b * N_ + n];
#pragma unroll
    for (int r = 0; r < 8; ++r) {
      float xv = xs[r * 516 + n];
      abuf[(size_t)(b * L_ + l0 + r) * 1024 + n] = f2bf(iv * acc[r] + (1.f - iv) * xv);
    }
  }
}

// ---------------- 11. center path -> abuf bf16 cols [512,1024) ----------------
__global__ __launch_bounds__(256) void k_center(const float* __restrict__ x,
                                                const float* __restrict__ cw,
                                                const float* __restrict__ vp_w,
                                                const float* __restrict__ vp_b,
                                                const float* __restrict__ cp1_w,
                                                const float* __restrict__ ctp,
                                                const float* __restrict__ cp2s,
                                                short* __restrict__ abuf) {
  __shared__ float xs[4][512];
  __shared__ float tpart[4][4][16];
  __shared__ float tls[4][16];
  __shared__ float xcls[4][64];
  __shared__ float xcpls[4][64];
  __shared__ float spart[4][16][4];
  __shared__ float sls[4][16];
  int b = blockIdx.x >> 9;
  int l0 = (blockIdx.x & 511) * 4;
  int t = threadIdx.x;
  for (int e = t; e < 4 * 512; e += 256)
    xs[e >> 9][e & 511] = x[(b * L_ + l0 + (e >> 9)) * N_ + (e & 511)];
  __syncthreads();
  {
    int r = t >> 6, j = t & 63, c = j & 15, sl = j >> 4;
    float a = 0.f;
    for (int n = sl * 128; n < sl * 128 + 128; ++n) a += xs[r][n] * cw[n * 16 + c];
    tpart[r][sl][c] = a;
  }
  __syncthreads();
  if (t < 64) {
    int r = t >> 4, c = t & 15;
    tls[r][c] = tpart[r][0][c] + tpart[r][1][c] + tpart[r][2][c] + tpart[r][3][c];
  }
  __syncthreads();
  {
    int r = t >> 6, d = t & 63;
    float a = vp_b[d];
#pragma unroll
    for (int c = 0; c < 16; ++c) a += tls[r][c] * vp_w[c * 64 + d];
    xcls[r][d] = a;
  }
  __syncthreads();
  {
    int r = t >> 6, d2 = t & 63;
    float a = 0.f;
#pragma unroll 8
    for (int d = 0; d < 64; ++d) a += xcls[r][d] * cp1_w[d * 64 + d2];
    xcpls[r][d2] = a;
  }
  __syncthreads();
  {
    int r = t >> 6, j = t & 63, c = j >> 2, q = j & 3;
    float a = 0.f;
    for (int d2 = q * 16; d2 < q * 16 + 16; ++d2) {
      float u = ctp[(b * C_ + c) * D_ + d2] + xcpls[r][d2];
      float g = 0.5f * u * (1.f + erff(u * 0.70710678118654752f));
      a += g * cp2s[d2];
    }
    spart[r][c][q] = a;
  }
  __syncthreads();
  if (t < 64) {
    int r = t >> 4, c = t & 15;
    sls[r][c] = spart[r][c][0] + spart[r][c][1] + spart[r][c][2] + spart[r][c][3] + cp2s[64];
  }
  __syncthreads();
#pragma unroll
  for (int r = 0; r < 4; ++r) {
    for (int n = t; n < 512; n += 256) {
      float a = 0.f;
#pragma unroll
      for (int c = 0; c < 16; ++c) a += sls[r][c] * cw[n * 16 + c];
      abuf[(size_t)(b * L_ + l0 + r) * 1024 + 512 + n] = f2bf(a);
    }
  }
}

// ---------------- 12. W [K][N] f32 -> Wt [N][K] bf16 ----------------
__global__ __launch_bounds__(256) void k_wt(const float* __restrict__ W,
                                            short* __restrict__ Wt, int K, int N) {
  __shared__ float tile[32][33];
  int bk = blockIdx.x, bn = blockIdx.y;
  int t = threadIdx.x;
  int c = t & 31, r = t >> 5;
  for (int rr = r; rr < 32; rr += 8)
    tile[rr][c] = W[(bk * 32 + rr) * N + bn * 32 + c];
  __syncthreads();
  for (int rr = r; rr < 32; rr += 8)
    Wt[(bn * 32 + rr) * K + bk * 32 + c] = f2bf(tile[c][rr]);
}

// ---------------- 13. gate GEMM (MFMA): [16384,1024]@[1024,512] + blend ----------------
__global__ __launch_bounds__(512) void k_gemm_gate(const short* __restrict__ abuf,
                                                   const short* __restrict__ wt,
                                                   const float* __restrict__ gate_b,
                                                   short* __restrict__ fused_bf) {
  __shared__ __align__(16) short As[128 * 32];  // 8 KB
  __shared__ __align__(16) short Bs[256 * 32];  // 16 KB
  int t = threadIdx.x, lane = t & 63, w = t >> 6;
  int lo = lane & 15, hi = lane >> 4;
  int bm = blockIdx.x >> 1, bn = blockIdx.x & 1;
  int row0 = bm * 128, n0 = bn * 256;
  int wm = w >> 2, wn = w & 3;
  f32x4 acc[4][4] = {};
  int pA = w * 64 + lane;
  int rA = pA >> 2, cA = (pA & 3) ^ ((rA >> 1) & 3);
  const short* srcA = abuf + (size_t)(row0 + rA) * 1024 + cA * 8;
  int pB0 = w * 128 + lane;
  int rB0 = pB0 >> 2, cB0 = (pB0 & 3) ^ ((rB0 >> 1) & 3);
  const short* srcB0 = wt + (size_t)(n0 + rB0) * 1024 + cB0 * 8;
  int pB1 = pB0 + 64;
  int rB1 = pB1 >> 2, cB1 = (pB1 & 3) ^ ((rB1 >> 1) & 3);
  const short* srcB1 = wt + (size_t)(n0 + rB1) * 1024 + cB1 * 8;
  int gl = (lo >> 1) & 3;
  int foff = (lo * 4 + (hi ^ gl)) * 8;
  for (int kt = 0; kt < 32; ++kt) {
    gload16(srcA + kt * 32, As + w * 512);
    gload16(srcB0 + kt * 32, Bs + w * 1024);
    gload16(srcB1 + kt * 32, Bs + w * 1024 + 512);
    __syncthreads();
    bf16x8 a[4], b[4];
#pragma unroll
    for (int m = 0; m < 4; ++m)
      a[m] = *(const bf16x8*)(As + (wm * 256 + m * 64) * 8 + foff);
#pragma unroll
    for (int n = 0; n < 4; ++n)
      b[n] = *(const bf16x8*)(Bs + (wn * 256 + n * 64) * 8 + foff);
#pragma unroll
    for (int m = 0; m < 4; ++m)
#pragma unroll
      for (int n = 0; n < 4; ++n)
        acc[m][n] = __builtin_amdgcn_mfma_f32_16x16x32_bf16(a[m], b[n], acc[m][n], 0, 0, 0);
    __syncthreads();
  }
#pragma unroll
  for (int m = 0; m < 4; ++m) {
    int rbase = row0 + wm * 64 + m * 16 + hi * 4;
#pragma unroll
    for (int j = 0; j < 4; ++j) {
      int row = rbase + j;
#pragma unroll
      for (int n = 0; n < 4; ++n) {
        int col = n0 + wn * 64 + n * 16 + lo;
        float g = sigmoidf_(acc[m][n][j] + gate_b[col]);
        float ringv = bf2f(abuf[(size_t)row * 1024 + col]);
        float ctvv  = bf2f(abuf[(size_t)row * 1024 + 512 + col]);
        fused_bf[(size_t)row * 512 + col] = f2bf(g * ringv + (1.f - g) * ctvv);
      }
    }
  }
}

// ---------------- 14. fus GEMM (MFMA) + residual + LayerNorm ----------------
__global__ __launch_bounds__(512) void k_gemm_fus(const short* __restrict__ fused_bf,
                                                  const short* __restrict__ wtf,
                                                  const float* __restrict__ x,
                                                  const float* __restrict__ fus_b,
                                                  const float* __restrict__ ln_g,
                                                  const float* __restrict__ ln_b,
                                                  float* __restrict__ out) {
  __shared__ __align__(16) short As[64 * 32];    // 4 KB
  __shared__ __align__(16) short Bs[512 * 32];   // 32 KB
  __shared__ float Ssh[8][64], Qsh[8][64];
  __shared__ float mus[64], rss[64];
  int t = threadIdx.x, lane = t & 63, w = t >> 6;
  int lo = lane & 15, hi = lane >> 4;
  int row0 = blockIdx.x * 64;
  f32x4 acc[4][4] = {};
  int pA = w * 64 + lane;
  int rA = pA >> 2, cA = (pA & 3) ^ ((rA >> 1) & 3);
  const short* srcA = fused_bf + (size_t)(row0 + rA) * 512 + cA * 8;
  int gl = (lo >> 1) & 3;
  int foff = (lo * 4 + (hi ^ gl)) * 8;
  for (int kt = 0; kt < 16; ++kt) {
    if (w < 4) gload16(srcA + kt * 32, As + w * 512);
#pragma unroll
    for (int q = 0; q < 4; ++q) {
      int pB = w * 256 + q * 64 + lane;
      int rB = pB >> 2, cB = (pB & 3) ^ ((rB >> 1) & 3);
      gload16(wtf + (size_t)rB * 512 + kt * 32 + cB * 8, Bs + (w * 256 + q * 64) * 8);
    }
    __syncthreads();
    bf16x8 a[4], b[4];
#pragma unroll
    for (int m = 0; m < 4; ++m)
      a[m] = *(const bf16x8*)(As + (m * 64) * 8 + foff);
#pragma unroll
    for (int n = 0; n < 4; ++n)
      b[n] = *(const bf16x8*)(Bs + (w * 256 + n * 64) * 8 + foff);
#pragma unroll
    for (int m = 0; m < 4; ++m)
#pragma unroll
      for (int n = 0; n < 4; ++n)
        acc[m][n] = __builtin_amdgcn_mfma_f32_16x16x32_bf16(a[m], b[n], acc[m][n], 0, 0, 0);
    __syncthreads();
  }
#pragma unroll
  for (int m = 0; m < 4; ++m) {
#pragma unroll
    for (int j = 0; j < 4; ++j) {
      int rl = m * 16 + hi * 4 + j;
      int row = row0 + rl;
      float ps = 0.f, pq = 0.f;
#pragma unroll
      for (int n = 0; n < 4; ++n) {
        int col = w * 64 + n * 16 + lo;
        float h = acc[m][n][j] + fus_b[col] + x[(size_t)row * 512 + col];
        acc[m][n][j] = h;
        ps += h; pq += h * h;
      }
#pragma unroll
      for (int o = 1; o < 16; o <<= 1) {
        ps += __shfl_xor(ps, o);
        pq += __shfl_xor(pq, o);
      }
      if (lo == 0) { Ssh[w][rl] = ps; Qsh[w][rl] = pq; }
    }
  }
  __syncthreads();
  if (t < 64) {
    float s = 0.f, q = 0.f;
#pragma unroll
    for (int ww = 0; ww < 8; ++ww) { s += Ssh[ww][t]; q += Qsh[ww][t]; }
    float mu = s * (1.f / N_);
    float var = q * (1.f / N_) - mu * mu;
    mus[t] = mu;
    rss[t] = rsqrtf(fmaxf(var, 0.f) + 1e-5f);
  }
  __syncthreads();
#pragma unroll
  for (int m = 0; m < 4; ++m) {
#pragma unroll
    for (int j = 0; j < 4; ++j) {
      int rl = m * 16 + hi * 4 + j;
      int row = row0 + rl;
      float mu = mus[rl], rs = rss[rl];
#pragma unroll
      for (int n = 0; n < 4; ++n) {
        int col = w * 64 + n * 16 + lo;
        out[(size_t)row * 512 + col] = (acc[m][n][j] - mu) * rs * ln_g[col] + ln_b[col];
      }
    }
  }
}

extern "C" void kernel_launch(void* const* d_in, const int* in_sizes, int n_in,
                              void* d_out, int out_size, void* d_ws, size_t ws_size,
                              hipStream_t stream) {
  (void)in_sizes; (void)n_in; (void)out_size; (void)ws_size;
  const float* x         = (const float*)d_in[0];
  const float* var_embed = (const float*)d_in[1];
  const float* temp_w    = (const float*)d_in[2];
  const float* temp_b    = (const float*)d_in[3];
  const float* q_w       = (const float*)d_in[4];
  const float* q_b       = (const float*)d_in[5];
  const float* k_w       = (const float*)d_in[6];
  const float* k_b       = (const float*)d_in[7];
  const float* imp_w     = (const float*)d_in[8];
  const float* imp_b     = (const float*)d_in[9];
  const float* cluster   = (const float*)d_in[10];
  const float* vp_w      = (const float*)d_in[11];
  const float* vp_b      = (const float*)d_in[12];
  const float* cp1_w     = (const float*)d_in[13];
  const float* cp1_b     = (const float*)d_in[14];
  const float* cp2_w     = (const float*)d_in[15];
  const float* cp2_b     = (const float*)d_in[16];
  const float* cg_w      = (const float*)d_in[17];
  const float* cg_b      = (const float*)d_in[18];
  const float* gate_w    = (const float*)d_in[19];
  const float* gate_b    = (const float*)d_in[20];
  const float* fus_w     = (const float*)d_in[21];
  const float* fus_b     = (const float*)d_in[22];
  const float* ln_g      = (const float*)d_in[23];
  const float* ln_b      = (const float*)d_in[24];
  float* out = (float*)d_out;
  float* ws  = (float*)d_ws;

  // workspace layout (float offsets)
  float* normed = ws + 0;                 // 1,048,576
  float* sim    = ws + 1048576;           //   262,144
  int*   idx_t  = (int*)(ws + 1310720);   //    23,040 ints (pad 24,576)
  float* Qb     = ws + 1335296;           //    65,536
  float* Kb     = ws + 1400832;           //    65,536
  float* impb   = ws + 1466368;           //     4,096
  float* summ   = ws + 1470464;           //     4,096
  float* w_t    = ws + 1474560;           //   184,320
  float* cw     = ws + 1658880;           //     8,192
  float* ct     = ws + 1667072;           //     8,192
  float* ctp    = ws + 1675264;           //     8,192
  float* cp2s   = ws + 1683456;           //       128 (pad 1,024)
  short* abuf     = (short*)(ws + 1684480);   // 16384*1024 bf16 = 32 MB
  short* fused_bf = (short*)(ws + 10073088);  // 16384*512 bf16 = 16 MB
  short* wt_gate  = (short*)(ws + 14267392);  // 512*1024 bf16
  short* wt_fus   = (short*)(ws + 14529536);  // 512*512 bf16
  float* psum     = ws + 14660608;            //   262,144
  float* psq      = ws + 14922752;            //   262,144  -> total ~60.7 MB

  k_normed<<<(L_ * N_) / 256, 256, 0, stream>>>(x, normed);
  k_sim<<<256, 256, 0, stream>>>(normed, sim);
  k_topk<<<N_, 256, 0, stream>>>(sim, idx_t);
  k_rstats<<<B_ * 64, 256, 0, stream>>>(x, psum, psq);
  k_rfinal<<<16, 256, 0, stream>>>(psum, psq, var_embed, temp_w, temp_b, q_w, q_b,
                                   k_w, k_b, imp_w, imp_b, Qb, Kb, impb, summ);
  k_cw<<<8, 64, 0, stream>>>(cluster, cw);
  k_ct<<<(B_ * 1024) / 256, 256, 0, stream>>>(summ, cg_w, cg_b, ct);
  k_ctp<<<(B_ * C_ * D_) / 256, 256, 0, stream>>>(ct, cp1_w, cp1_b, ctp);
  k_cp2s<<<1, 64, 0, stream>>>(cp2_w, cp2_b, cp2s);
  k_attn<<<B_ * N_, 64, 0, stream>>>(Qb, Kb, idx_t, w_t);
  k_wt<<<dim3(32, 16), 256, 0, stream>>>(gate_w, wt_gate, 1024, 512);
  k_wt<<<dim3(16, 16), 256, 0, stream>>>(fus_w, wt_fus, 512, 512);
  k_ring<<<B_ * (L_ / 8), 256, 0, stream>>>(x, w_t, idx_t, impb, abuf);
  k_center<<<B_ * (L_ / 4), 256, 0, stream>>>(x, cw, vp_w, vp_b, cp1_w, ctp, cp2s, abuf);
  k_gemm_gate<<<256, 512, 0, stream>>>(abuf, wt_gate, gate_b, fused_bf);
  k_gemm_fus<<<256, 512, 0, stream>>>(fused_bf, wt_fus, x, fus_b, ln_g, ln_b, out);
}

// Round 4
// 388.103 us; speedup vs baseline: 3.0845x; 1.3092x over previous
//
#include <hip/hip_runtime.h>

#define B_ 8
#define L_ 2048
#define N_ 512
#define H_ 16
#define C_ 16
#define D_ 64
#define TK_ 45
#define KS_ 16

typedef __attribute__((ext_vector_type(8))) short bf16x8;
typedef __attribute__((ext_vector_type(4))) float f32x4;

__device__ __forceinline__ float sigmoidf_(float v) { return 1.f / (1.f + expf(-v)); }

__device__ __forceinline__ short f2bf(float f) {
  union { float f; unsigned u; } v; v.f = f;
  unsigned r = (v.u + 0x7fffu + ((v.u >> 16) & 1u)) >> 16;
  return (short)r;
}
__device__ __forceinline__ float bf2f(short s) {
  union { unsigned u; float f; } v; v.u = ((unsigned)(unsigned short)s) << 16;
  return v.f;
}
__device__ __forceinline__ void gload16(const void* g, void* l) {
  __builtin_amdgcn_global_load_lds((const __attribute__((address_space(1))) unsigned int*)g,
                                   (__attribute__((address_space(3))) unsigned int*)l, 16, 0, 0);
}

// ---------------- 1. batch stats -> normed [L,N] ----------------
__global__ __launch_bounds__(256) void k_normed(const float* __restrict__ x,
                                                float* __restrict__ normed) {
  int i = blockIdx.x * 256 + threadIdx.x;
  float s = 0.f, ss = 0.f;
#pragma unroll
  for (int b = 0; b < B_; ++b) {
    float v = x[b * (L_ * N_) + i];
    s += v; ss += v * v;
  }
  float mean = s * (1.f / B_);
  float var  = fmaxf((ss - s * mean) * (1.f / (B_ - 1)), 0.f);
  normed[i] = mean / (sqrtf(var) + 1e-5f);
}

// ---------------- 2. sim partials: 64x64 tile, K-split 16, 4x4 reg tile ----------------
__global__ __launch_bounds__(256) void k_sim(const float* __restrict__ nrm,
                                             float* __restrict__ simP) {
  __shared__ float As[32 * 64];
  __shared__ float Bs[32 * 64];
  int bx = blockIdx.x;
  int ks = bx >> 6, tile = bx & 63;
  int bi = tile & 7, bj = tile >> 3;
  int t = threadIdx.x, tx = t & 15, ty = t >> 4;
  float acc[4][4] = {};
  int k0 = ks * (L_ / KS_);
  for (int kt = 0; kt < (L_ / KS_) / 32; ++kt) {
    for (int e = t; e < 2048; e += 256) {
      int kk = e >> 6, i = e & 63;
      int krow = k0 + kt * 32 + kk;
      As[e] = nrm[krow * N_ + bi * 64 + i];
      Bs[e] = nrm[krow * N_ + bj * 64 + i];
    }
    __syncthreads();
#pragma unroll
    for (int kk = 0; kk < 32; ++kk) {
      float4 a = *(const float4*)(As + kk * 64 + ty * 4);
      float4 b = *(const float4*)(Bs + kk * 64 + tx * 4);
      float av[4] = {a.x, a.y, a.z, a.w};
      float bv[4] = {b.x, b.y, b.z, b.w};
#pragma unroll
      for (int i = 0; i < 4; ++i)
#pragma unroll
        for (int j = 0; j < 4; ++j)
          acc[i][j] += av[i] * bv[j];
    }
    __syncthreads();
  }
  float* outp = simP + (size_t)ks * (N_ * N_);
#pragma unroll
  for (int i = 0; i < 4; ++i) {
    int row = bi * 64 + ty * 4 + i;
    float4 o = {acc[i][0], acc[i][1], acc[i][2], acc[i][3]};
    *(float4*)(outp + row * N_ + bj * 64 + tx * 4) = o;
  }
}

// ---------------- 2b. reduce K-split partials ----------------
__global__ __launch_bounds__(256) void k_simred(const float* __restrict__ simP,
                                                float* __restrict__ sim) {
  int gid = blockIdx.x * 256 + threadIdx.x;  // one float4 each, 65536 total
  float4 s = {0.f, 0.f, 0.f, 0.f};
#pragma unroll
  for (int ksi = 0; ksi < KS_; ++ksi) {
    float4 p = *(const float4*)(simP + (size_t)ksi * (N_ * N_) + gid * 4);
    s.x += p.x; s.y += p.y; s.z += p.z; s.w += p.w;
  }
  *(float4*)(sim + gid * 4) = s;
}

// ---------------- 3. top-45 per row: one wave per row, register-resident ----------------
__global__ __launch_bounds__(256) void k_topk(const float* __restrict__ sim,
                                              int* __restrict__ idx_t) {
  int t = threadIdx.x, lane = t & 63, wv = t >> 6;
  int n = blockIdx.x * 4 + wv;
  float v[8];
#pragma unroll
  for (int u = 0; u < 8; ++u) {
    int idx = u * 64 + lane;
    v[u] = (idx == n) ? -3e38f : sim[n * N_ + idx];
  }
  for (int k = 0; k < TK_; ++k) {
    float mv = v[0]; int mi = lane;
#pragma unroll
    for (int u = 1; u < 8; ++u) {
      if (v[u] > mv) { mv = v[u]; mi = u * 64 + lane; }  // strict > keeps lower idx
    }
#pragma unroll
    for (int o = 32; o > 0; o >>= 1) {
      float ov = __shfl_xor(mv, o);
      int   oi = __shfl_xor(mi, o);
      if (ov > mv || (ov == mv && oi < mi)) { mv = ov; mi = oi; }
    }
    if (lane == 0) idx_t[k * N_ + n] = mi;
#pragma unroll
    for (int u = 0; u < 8; ++u)
      if (mi == u * 64 + lane) v[u] = -3e38f;
  }
}

// ---------------- 4a. router stats partials: 32 l-rows per block ----------------
__global__ __launch_bounds__(256) void k_rstats(const float* __restrict__ x,
                                                float* __restrict__ psum,
                                                float* __restrict__ psq) {
  int b  = blockIdx.x >> 6;
  int ch = blockIdx.x & 63;
  int t = threadIdx.x;
  const float* xp = x + ((size_t)b * L_ + ch * 32) * N_;
#pragma unroll
  for (int u = 0; u < 2; ++u) {
    int n = t + u * 256;
    float s = 0.f, ss = 0.f;
#pragma unroll 8
    for (int r = 0; r < 32; ++r) {
      float v = xp[r * N_ + n];
      s += v; ss += v * v;
    }
    psum[(b * 64 + ch) * N_ + n] = s;
    psq [(b * 64 + ch) * N_ + n] = ss;
  }
}

// ---------------- 4b. finalize: stats -> Q/K/importance/summary ----------------
__global__ __launch_bounds__(256) void k_rfinal(
    const float* __restrict__ psum, const float* __restrict__ psq,
    const float* __restrict__ var_embed,
    const float* __restrict__ temp_w, const float* __restrict__ temp_b,
    const float* __restrict__ q_w, const float* __restrict__ q_b,
    const float* __restrict__ k_w, const float* __restrict__ k_b,
    const float* __restrict__ imp_w, const float* __restrict__ imp_b,
    float* __restrict__ Q, float* __restrict__ Kv,
    float* __restrict__ imp, float* __restrict__ summary) {
  int gid = blockIdx.x * 256 + threadIdx.x;  // 4096 = B*N
  int b = gid >> 9, n = gid & 511;
  float s = 0.f, ss = 0.f;
#pragma unroll 8
  for (int c = 0; c < 64; ++c) {
    s  += psum[(b * 64 + c) * N_ + n];
    ss += psq [(b * 64 + c) * N_ + n];
  }
  float mean = s * (1.f / L_);
  float var  = fmaxf((ss - s * mean) * (1.f / (L_ - 1)), 0.f);
  float stdv = sqrtf(var + 1e-5f);
  summary[b * N_ + n] = mean;
  float vf[32];
#pragma unroll
  for (int i = 0; i < 16; ++i) vf[i] = var_embed[n * 16 + i];
#pragma unroll
  for (int h = 0; h < 16; ++h)
    vf[16 + h] = mean * temp_w[h] + stdv * temp_w[16 + h] + temp_b[h];
#pragma unroll
  for (int h = 0; h < 16; ++h) {
    float qa = q_b[h], ka = k_b[h];
#pragma unroll
    for (int i = 0; i < 32; ++i) {
      qa += vf[i] * q_w[i * 16 + h];
      ka += vf[i] * k_w[i * 16 + h];
    }
    Q[(b * N_ + n) * 16 + h]  = qa;
    Kv[(b * N_ + n) * 16 + h] = ka;
  }
  float ia = imp_b[0];
#pragma unroll
  for (int i = 0; i < 32; ++i) ia += vf[i] * imp_w[i];
  imp[b * N_ + n] = sigmoidf_(ia);
}

// ---------------- 5. cw ----------------
__global__ __launch_bounds__(64) void k_cw(const float* __restrict__ cs,
                                           float* __restrict__ cw) {
  int n = blockIdx.x * 64 + threadIdx.x;
  if (n >= N_) return;
  float v[16], mx = -3e38f;
#pragma unroll
  for (int c = 0; c < 16; ++c) { v[c] = cs[n * 16 + c]; mx = fmaxf(mx, v[c]); }
  float s = 0.f;
#pragma unroll
  for (int c = 0; c < 16; ++c) { v[c] = expf(v[c] - mx); s += v[c]; }
  float inv = 1.f / s;
#pragma unroll
  for (int c = 0; c < 16; ++c) cw[n * 16 + c] = v[c] * inv;
}

// ---------------- 6. center tokens ----------------
__global__ __launch_bounds__(256) void k_ct(const float* __restrict__ summary,
                                            const float* __restrict__ cg_w,
                                            const float* __restrict__ cg_b,
                                            float* __restrict__ ct) {
  int i = blockIdx.x * 256 + threadIdx.x;
  int b = i >> 10, o = i & 1023;
  float a = cg_b[o];
  for (int n = 0; n < N_; ++n) a += summary[b * N_ + n] * cg_w[n * 1024 + o];
  ct[i] = a;
}

// ---------------- 7. ctp ----------------
__global__ __launch_bounds__(256) void k_ctp(const float* __restrict__ ct,
                                             const float* __restrict__ cp1_w,
                                             const float* __restrict__ cp1_b,
                                             float* __restrict__ ctp) {
  int i = blockIdx.x * 256 + threadIdx.x;
  int row = i >> 6, d2 = i & 63;
  float a = cp1_b[d2];
#pragma unroll 8
  for (int d = 0; d < 64; ++d) a += ct[row * 64 + d] * cp1_w[d * 64 + d2];
  ctp[i] = a;
}

// ---------------- 8. cp2 row-sums ----------------
__global__ __launch_bounds__(64) void k_cp2s(const float* __restrict__ cp2_w,
                                             const float* __restrict__ cp2_b,
                                             float* __restrict__ cp2s) {
  int t = threadIdx.x;
  float a = 0.f;
#pragma unroll 8
  for (int d = 0; d < 64; ++d) a += cp2_w[t * 64 + d];
  cp2s[t] = a;
  if (t == 0) {
    float bsum = 0.f;
    for (int d = 0; d < 64; ++d) bsum += cp2_b[d];
    cp2s[64] = bsum;
  }
}

// ---------------- 9. sparse attention weights ----------------
__global__ __launch_bounds__(64) void k_attn(const float* __restrict__ Q,
                                             const float* __restrict__ Kv,
                                             const int* __restrict__ idx_t,
                                             float* __restrict__ w_t) {
  int bn = blockIdx.x;
  int b = bn >> 9, n = bn & (N_ - 1);
  int j = threadIdx.x;
  float s = -3e38f;
  if (j < TK_) {
    int m = idx_t[j * N_ + n];
    const float* qp = Q + (b * N_ + n) * H_;
    const float* kp = Kv + (b * N_ + m) * H_;
    float a = 0.f;
#pragma unroll
    for (int h = 0; h < H_; ++h) a += qp[h] * kp[h];
    s = a * 0.25f;
  }
  float mx = s;
#pragma unroll
  for (int o = 32; o > 0; o >>= 1) mx = fmaxf(mx, __shfl_xor(mx, o));
  float e = (j < TK_) ? expf(s - mx) : 0.f;
  float sum = e;
#pragma unroll
  for (int o = 32; o > 0; o >>= 1) sum += __shfl_xor(sum, o);
  if (j < TK_) w_t[(b * TK_ + j) * N_ + n] = e / sum;
}

// ---------------- 10. ring -> abuf bf16 cols [0,512) ----------------
__global__ __launch_bounds__(256) void k_ring(const float* __restrict__ x,
                                              const float* __restrict__ w_t,
                                              const int* __restrict__ idx_t,
                                              const float* __restrict__ imp,
                                              short* __restrict__ abuf) {
  __shared__ float xs[8 * 516];
  int b = blockIdx.x >> 8;
  int l0 = (blockIdx.x & 255) * 8;
  int t = threadIdx.x;
  for (int e = t; e < 8 * N_; e += 256) {
    int r = e >> 9, n = e & 511;
    xs[r * 516 + n] = x[(b * L_ + l0 + r) * N_ + n];
  }
  __syncthreads();
#pragma unroll
  for (int u = 0; u < 2; ++u) {
    int n = t + u * 256;
    float acc[8] = {0.f, 0.f, 0.f, 0.f, 0.f, 0.f, 0.f, 0.f};
    for (int j = 0; j < TK_; ++j) {
      float wv = w_t[(b * TK_ + j) * N_ + n];
      int m = idx_t[j * N_ + n];
#pragma unroll
      for (int r = 0; r < 8; ++r) acc[r] += wv * xs[r * 516 + m];
    }
    float iv = imp[b * N_ + n];
#pragma unroll
    for (int r = 0; r < 8; ++r) {
      float xv = xs[r * 516 + n];
      abuf[(size_t)(b * L_ + l0 + r) * 1024 + n] = f2bf(iv * acc[r] + (1.f - iv) * xv);
    }
  }
}

// ---------------- 11. center path -> abuf bf16 cols [512,1024) ----------------
__global__ __launch_bounds__(256) void k_center(const float* __restrict__ x,
                                                const float* __restrict__ cw,
                                                const float* __restrict__ vp_w,
                                                const float* __restrict__ vp_b,
                                                const float* __restrict__ cp1_w,
                                                const float* __restrict__ ctp,
                                                const float* __restrict__ cp2s,
                                                short* __restrict__ abuf) {
  __shared__ float xs[4][512];
  __shared__ float tpart[4][4][16];
  __shared__ float tls[4][16];
  __shared__ float xcls[4][64];
  __shared__ float xcpls[4][64];
  __shared__ float spart[4][16][4];
  __shared__ float sls[4][16];
  int b = blockIdx.x >> 9;
  int l0 = (blockIdx.x & 511) * 4;
  int t = threadIdx.x;
  for (int e = t; e < 4 * 512; e += 256)
    xs[e >> 9][e & 511] = x[(b * L_ + l0 + (e >> 9)) * N_ + (e & 511)];
  __syncthreads();
  {
    int r = t >> 6, j = t & 63, c = j & 15, sl = j >> 4;
    float a = 0.f;
    for (int n = sl * 128; n < sl * 128 + 128; ++n) a += xs[r][n] * cw[n * 16 + c];
    tpart[r][sl][c] = a;
  }
  __syncthreads();
  if (t < 64) {
    int r = t >> 4, c = t & 15;
    tls[r][c] = tpart[r][0][c] + tpart[r][1][c] + tpart[r][2][c] + tpart[r][3][c];
  }
  __syncthreads();
  {
    int r = t >> 6, d = t & 63;
    float a = vp_b[d];
#pragma unroll
    for (int c = 0; c < 16; ++c) a += tls[r][c] * vp_w[c * 64 + d];
    xcls[r][d] = a;
  }
  __syncthreads();
  {
    int r = t >> 6, d2 = t & 63;
    float a = 0.f;
#pragma unroll 8
    for (int d = 0; d < 64; ++d) a += xcls[r][d] * cp1_w[d * 64 + d2];
    xcpls[r][d2] = a;
  }
  __syncthreads();
  {
    int r = t >> 6, j = t & 63, c = j >> 2, q = j & 3;
    float a = 0.f;
    for (int d2 = q * 16; d2 < q * 16 + 16; ++d2) {
      float u = ctp[(b * C_ + c) * D_ + d2] + xcpls[r][d2];
      float g = 0.5f * u * (1.f + erff(u * 0.70710678118654752f));
      a += g * cp2s[d2];
    }
    spart[r][c][q] = a;
  }
  __syncthreads();
  if (t < 64) {
    int r = t >> 4, c = t & 15;
    sls[r][c] = spart[r][c][0] + spart[r][c][1] + spart[r][c][2] + spart[r][c][3] + cp2s[64];
  }
  __syncthreads();
#pragma unroll
  for (int r = 0; r < 4; ++r) {
    for (int n = t; n < 512; n += 256) {
      float a = 0.f;
#pragma unroll
      for (int c = 0; c < 16; ++c) a += sls[r][c] * cw[n * 16 + c];
      abuf[(size_t)(b * L_ + l0 + r) * 1024 + 512 + n] = f2bf(a);
    }
  }
}

// ---------------- 12. W [K][N] f32 -> Wt [N][K] bf16 ----------------
__global__ __launch_bounds__(256) void k_wt(const float* __restrict__ W,
                                            short* __restrict__ Wt, int K, int N) {
  __shared__ float tile[32][33];
  int bk = blockIdx.x, bn = blockIdx.y;
  int t = threadIdx.x;
  int c = t & 31, r = t >> 5;
  for (int rr = r; rr < 32; rr += 8)
    tile[rr][c] = W[(bk * 32 + rr) * N + bn * 32 + c];
  __syncthreads();
  for (int rr = r; rr < 32; rr += 8)
    Wt[(bn * 32 + rr) * K + bk * 32 + c] = f2bf(tile[c][rr]);
}

// ---------------- 13. gate GEMM (MFMA): [16384,1024]@[1024,512] + blend ----------------
__global__ __launch_bounds__(512) void k_gemm_gate(const short* __restrict__ abuf,
                                                   const short* __restrict__ wt,
                                                   const float* __restrict__ gate_b,
                                                   short* __restrict__ fused_bf) {
  __shared__ __align__(16) short As[128 * 32];  // 8 KB
  __shared__ __align__(16) short Bs[256 * 32];  // 16 KB
  int t = threadIdx.x, lane = t & 63, w = t >> 6;
  int lo = lane & 15, hi = lane >> 4;
  int bm = blockIdx.x >> 1, bn = blockIdx.x & 1;
  int row0 = bm * 128, n0 = bn * 256;
  int wm = w >> 2, wn = w & 3;
  f32x4 acc[4][4] = {};
  int pA = w * 64 + lane;
  int rA = pA >> 2, cA = (pA & 3) ^ ((rA >> 1) & 3);
  const short* srcA = abuf + (size_t)(row0 + rA) * 1024 + cA * 8;
  int pB0 = w * 128 + lane;
  int rB0 = pB0 >> 2, cB0 = (pB0 & 3) ^ ((rB0 >> 1) & 3);
  const short* srcB0 = wt + (size_t)(n0 + rB0) * 1024 + cB0 * 8;
  int pB1 = pB0 + 64;
  int rB1 = pB1 >> 2, cB1 = (pB1 & 3) ^ ((rB1 >> 1) & 3);
  const short* srcB1 = wt + (size_t)(n0 + rB1) * 1024 + cB1 * 8;
  int gl = (lo >> 1) & 3;
  int foff = (lo * 4 + (hi ^ gl)) * 8;
  for (int kt = 0; kt < 32; ++kt) {
    gload16(srcA + kt * 32, As + w * 512);
    gload16(srcB0 + kt * 32, Bs + w * 1024);
    gload16(srcB1 + kt * 32, Bs + w * 1024 + 512);
    __syncthreads();
    bf16x8 a[4], b[4];
#pragma unroll
    for (int m = 0; m < 4; ++m)
      a[m] = *(const bf16x8*)(As + (wm * 256 + m * 64) * 8 + foff);
#pragma unroll
    for (int n = 0; n < 4; ++n)
      b[n] = *(const bf16x8*)(Bs + (wn * 256 + n * 64) * 8 + foff);
#pragma unroll
    for (int m = 0; m < 4; ++m)
#pragma unroll
      for (int n = 0; n < 4; ++n)
        acc[m][n] = __builtin_amdgcn_mfma_f32_16x16x32_bf16(a[m], b[n], acc[m][n], 0, 0, 0);
    __syncthreads();
  }
#pragma unroll
  for (int m = 0; m < 4; ++m) {
    int rbase = row0 + wm * 64 + m * 16 + hi * 4;
#pragma unroll
    for (int j = 0; j < 4; ++j) {
      int row = rbase + j;
#pragma unroll
      for (int n = 0; n < 4; ++n) {
        int col = n0 + wn * 64 + n * 16 + lo;
        float g = sigmoidf_(acc[m][n][j] + gate_b[col]);
        float ringv = bf2f(abuf[(size_t)row * 1024 + col]);
        float ctvv  = bf2f(abuf[(size_t)row * 1024 + 512 + col]);
        fused_bf[(size_t)row * 512 + col] = f2bf(g * ringv + (1.f - g) * ctvv);
      }
    }
  }
}

// ---------------- 14. fus GEMM (MFMA) + residual + LayerNorm ----------------
__global__ __launch_bounds__(512) void k_gemm_fus(const short* __restrict__ fused_bf,
                                                  const short* __restrict__ wtf,
                                                  const float* __restrict__ x,
                                                  const float* __restrict__ fus_b,
                                                  const float* __restrict__ ln_g,
                                                  const float* __restrict__ ln_b,
                                                  float* __restrict__ out) {
  __shared__ __align__(16) short As[64 * 32];    // 4 KB
  __shared__ __align__(16) short Bs[512 * 32];   // 32 KB
  __shared__ float Ssh[8][64], Qsh[8][64];
  __shared__ float mus[64], rss[64];
  int t = threadIdx.x, lane = t & 63, w = t >> 6;
  int lo = lane & 15, hi = lane >> 4;
  int row0 = blockIdx.x * 64;
  f32x4 acc[4][4] = {};
  int pA = w * 64 + lane;
  int rA = pA >> 2, cA = (pA & 3) ^ ((rA >> 1) & 3);
  const short* srcA = fused_bf + (size_t)(row0 + rA) * 512 + cA * 8;
  int gl = (lo >> 1) & 3;
  int foff = (lo * 4 + (hi ^ gl)) * 8;
  for (int kt = 0; kt < 16; ++kt) {
    if (w < 4) gload16(srcA + kt * 32, As + w * 512);
#pragma unroll
    for (int q = 0; q < 4; ++q) {
      int pB = w * 256 + q * 64 + lane;
      int rB = pB >> 2, cB = (pB & 3) ^ ((rB >> 1) & 3);
      gload16(wtf + (size_t)rB * 512 + kt * 32 + cB * 8, Bs + (w * 256 + q * 64) * 8);
    }
    __syncthreads();
    bf16x8 a[4], b[4];
#pragma unroll
    for (int m = 0; m < 4; ++m)
      a[m] = *(const bf16x8*)(As + (m * 64) * 8 + foff);
#pragma unroll
    for (int n = 0; n < 4; ++n)
      b[n] = *(const bf16x8*)(Bs + (w * 256 + n * 64) * 8 + foff);
#pragma unroll
    for (int m = 0; m < 4; ++m)
#pragma unroll
      for (int n = 0; n < 4; ++n)
        acc[m][n] = __builtin_amdgcn_mfma_f32_16x16x32_bf16(a[m], b[n], acc[m][n], 0, 0, 0);
    __syncthreads();
  }
#pragma unroll
  for (int m = 0; m < 4; ++m) {
#pragma unroll
    for (int j = 0; j < 4; ++j) {
      int rl = m * 16 + hi * 4 + j;
      int row = row0 + rl;
      float ps = 0.f, pq = 0.f;
#pragma unroll
      for (int n = 0; n < 4; ++n) {
        int col = w * 64 + n * 16 + lo;
        float h = acc[m][n][j] + fus_b[col] + x[(size_t)row * 512 + col];
        acc[m][n][j] = h;
        ps += h; pq += h * h;
      }
#pragma unroll
      for (int o = 1; o < 16; o <<= 1) {
        ps += __shfl_xor(ps, o);
        pq += __shfl_xor(pq, o);
      }
      if (lo == 0) { Ssh[w][rl] = ps; Qsh[w][rl] = pq; }
    }
  }
  __syncthreads();
  if (t < 64) {
    float s = 0.f, q = 0.f;
#pragma unroll
    for (int ww = 0; ww < 8; ++ww) { s += Ssh[ww][t]; q += Qsh[ww][t]; }
    float mu = s * (1.f / N_);
    float var = q * (1.f / N_) - mu * mu;
    mus[t] = mu;
    rss[t] = rsqrtf(fmaxf(var, 0.f) + 1e-5f);
  }
  __syncthreads();
#pragma unroll
  for (int m = 0; m < 4; ++m) {
#pragma unroll
    for (int j = 0; j < 4; ++j) {
      int rl = m * 16 + hi * 4 + j;
      int row = row0 + rl;
      float mu = mus[rl], rs = rss[rl];
#pragma unroll
      for (int n = 0; n < 4; ++n) {
        int col = w * 64 + n * 16 + lo;
        out[(size_t)row * 512 + col] = (acc[m][n][j] - mu) * rs * ln_g[col] + ln_b[col];
      }
    }
  }
}

extern "C" void kernel_launch(void* const* d_in, const int* in_sizes, int n_in,
                              void* d_out, int out_size, void* d_ws, size_t ws_size,
                              hipStream_t stream) {
  (void)in_sizes; (void)n_in; (void)out_size; (void)ws_size;
  const float* x         = (const float*)d_in[0];
  const float* var_embed = (const float*)d_in[1];
  const float* temp_w    = (const float*)d_in[2];
  const float* temp_b    = (const float*)d_in[3];
  const float* q_w       = (const float*)d_in[4];
  const float* q_b       = (const float*)d_in[5];
  const float* k_w       = (const float*)d_in[6];
  const float* k_b       = (const float*)d_in[7];
  const float* imp_w     = (const float*)d_in[8];
  const float* imp_b     = (const float*)d_in[9];
  const float* cluster   = (const float*)d_in[10];
  const float* vp_w      = (const float*)d_in[11];
  const float* vp_b      = (const float*)d_in[12];
  const float* cp1_w     = (const float*)d_in[13];
  const float* cp1_b     = (const float*)d_in[14];
  const float* cp2_w     = (const float*)d_in[15];
  const float* cp2_b     = (const float*)d_in[16];
  const float* cg_w      = (const float*)d_in[17];
  const float* cg_b      = (const float*)d_in[18];
  const float* gate_w    = (const float*)d_in[19];
  const float* gate_b    = (const float*)d_in[20];
  const float* fus_w     = (const float*)d_in[21];
  const float* fus_b     = (const float*)d_in[22];
  const float* ln_g      = (const float*)d_in[23];
  const float* ln_b      = (const float*)d_in[24];
  float* out = (float*)d_out;
  float* ws  = (float*)d_ws;

  // workspace layout (float offsets)
  float* normed = ws + 0;                 // 1,048,576
  float* sim    = ws + 1048576;           //   262,144
  int*   idx_t  = (int*)(ws + 1310720);   //    23,040 ints (pad 24,576)
  float* Qb     = ws + 1335296;           //    65,536
  float* Kb     = ws + 1400832;           //    65,536
  float* impb   = ws + 1466368;           //     4,096
  float* summ   = ws + 1470464;           //     4,096
  float* w_t    = ws + 1474560;           //   184,320
  float* cw     = ws + 1658880;           //     8,192
  float* ct     = ws + 1667072;           //     8,192
  float* ctp    = ws + 1675264;           //     8,192
  float* cp2s   = ws + 1683456;           //       128 (pad 1,024)
  short* abuf     = (short*)(ws + 1684480);   // 16384*1024 bf16 = 32 MB
  short* fused_bf = (short*)(ws + 10073088);  // 16384*512 bf16 = 16 MB
  short* wt_gate  = (short*)(ws + 14267392);  // 512*1024 bf16
  short* wt_fus   = (short*)(ws + 14529536);  // 512*512 bf16
  float* psum     = ws + 14660608;            //   262,144
  float* psq      = ws + 14922752;            //   262,144  -> total ~60.7 MB
  // simP (16 MB, only live between k_sim and k_simred) aliases the abuf
  // region: abuf is first written later, by k_ring/k_center (stream-ordered).
  float* simP     = (float*)abuf;             // 16*512*512 floats

  k_normed<<<(L_ * N_) / 256, 256, 0, stream>>>(x, normed);
  k_sim<<<64 * KS_, 256, 0, stream>>>(normed, simP);
  k_simred<<<256, 256, 0, stream>>>(simP, sim);
  k_topk<<<N_ / 4, 256, 0, stream>>>(sim, idx_t);
  k_rstats<<<B_ * 64, 256, 0, stream>>>(x, psum, psq);
  k_rfinal<<<16, 256, 0, stream>>>(psum, psq, var_embed, temp_w, temp_b, q_w, q_b,
                                   k_w, k_b, imp_w, imp_b, Qb, Kb, impb, summ);
  k_cw<<<8, 64, 0, stream>>>(cluster, cw);
  k_ct<<<(B_ * 1024) / 256, 256, 0, stream>>>(summ, cg_w, cg_b, ct);
  k_ctp<<<(B_ * C_ * D_) / 256, 256, 0, stream>>>(ct, cp1_w, cp1_b, ctp);
  k_cp2s<<<1, 64, 0, stream>>>(cp2_w, cp2_b, cp2s);
  k_attn<<<B_ * N_, 64, 0, stream>>>(Qb, Kb, idx_t, w_t);
  k_wt<<<dim3(32, 16), 256, 0, stream>>>(gate_w, wt_gate, 1024, 512);
  k_wt<<<dim3(16, 16), 256, 0, stream>>>(fus_w, wt_fus, 512, 512);
  k_ring<<<B_ * (L_ / 8), 256, 0, stream>>>(x, w_t, idx_t, impb, abuf);
  k_center<<<B_ * (L_ / 4), 256, 0, stream>>>(x, cw, vp_w, vp_b, cp1_w, ctp, cp2s, abuf);
  k_gemm_gate<<<256, 512, 0, stream>>>(abuf, wt_gate, gate_b, fused_bf);
  k_gemm_fus<<<256, 512, 0, stream>>>(fused_bf, wt_fus, x, fus_b, ln_g, ln_b, out);
}

// Round 5
// 360.891 us; speedup vs baseline: 3.3171x; 1.0754x over previous
//
#include <hip/hip_runtime.h>

#define B_ 8
#define L_ 2048
#define N_ 512
#define H_ 16
#define C_ 16
#define D_ 64
#define TK_ 45
#define KS_ 16

typedef __attribute__((ext_vector_type(8))) short bf16x8;
typedef __attribute__((ext_vector_type(4))) float f32x4;

__device__ __forceinline__ float sigmoidf_(float v) { return 1.f / (1.f + expf(-v)); }

__device__ __forceinline__ short f2bf(float f) {
  union { float f; unsigned u; } v; v.f = f;
  unsigned r = (v.u + 0x7fffu + ((v.u >> 16) & 1u)) >> 16;
  return (short)r;
}
__device__ __forceinline__ float bf2f(short s) {
  union { unsigned u; float f; } v; v.u = ((unsigned)(unsigned short)s) << 16;
  return v.f;
}
__device__ __forceinline__ void gload16(const void* g, void* l) {
  __builtin_amdgcn_global_load_lds((const __attribute__((address_space(1))) unsigned int*)g,
                                   (__attribute__((address_space(3))) unsigned int*)l, 16, 0, 0);
}

// ---------------- 1. batch stats -> normed [L,N] ----------------
__global__ __launch_bounds__(256) void k_normed(const float* __restrict__ x,
                                                float* __restrict__ normed) {
  int i = blockIdx.x * 256 + threadIdx.x;
  float s = 0.f, ss = 0.f;
#pragma unroll
  for (int b = 0; b < B_; ++b) {
    float v = x[b * (L_ * N_) + i];
    s += v; ss += v * v;
  }
  float mean = s * (1.f / B_);
  float var  = fmaxf((ss - s * mean) * (1.f / (B_ - 1)), 0.f);
  normed[i] = mean / (sqrtf(var) + 1e-5f);
}

// ---------------- 2. sim partials: 64x64 tile, K-split 16, 4x4 reg tile ----------------
__global__ __launch_bounds__(256) void k_sim(const float* __restrict__ nrm,
                                             float* __restrict__ simP) {
  __shared__ float As[32 * 64];
  __shared__ float Bs[32 * 64];
  int bx = blockIdx.x;
  int ks = bx >> 6, tile = bx & 63;
  int bi = tile & 7, bj = tile >> 3;
  int t = threadIdx.x, tx = t & 15, ty = t >> 4;
  float acc[4][4] = {};
  int k0 = ks * (L_ / KS_);
  for (int kt = 0; kt < (L_ / KS_) / 32; ++kt) {
    for (int e = t; e < 2048; e += 256) {
      int kk = e >> 6, i = e & 63;
      int krow = k0 + kt * 32 + kk;
      As[e] = nrm[krow * N_ + bi * 64 + i];
      Bs[e] = nrm[krow * N_ + bj * 64 + i];
    }
    __syncthreads();
#pragma unroll
    for (int kk = 0; kk < 32; ++kk) {
      float4 a = *(const float4*)(As + kk * 64 + ty * 4);
      float4 b = *(const float4*)(Bs + kk * 64 + tx * 4);
      float av[4] = {a.x, a.y, a.z, a.w};
      float bv[4] = {b.x, b.y, b.z, b.w};
#pragma unroll
      for (int i = 0; i < 4; ++i)
#pragma unroll
        for (int j = 0; j < 4; ++j)
          acc[i][j] += av[i] * bv[j];
    }
    __syncthreads();
  }
  float* outp = simP + (size_t)ks * (N_ * N_);
#pragma unroll
  for (int i = 0; i < 4; ++i) {
    int row = bi * 64 + ty * 4 + i;
    float4 o = {acc[i][0], acc[i][1], acc[i][2], acc[i][3]};
    *(float4*)(outp + row * N_ + bj * 64 + tx * 4) = o;
  }
}

// ---------------- 2b. reduce K-split partials ----------------
__global__ __launch_bounds__(256) void k_simred(const float* __restrict__ simP,
                                                float* __restrict__ sim) {
  int gid = blockIdx.x * 256 + threadIdx.x;
  float4 s = {0.f, 0.f, 0.f, 0.f};
#pragma unroll
  for (int ksi = 0; ksi < KS_; ++ksi) {
    float4 p = *(const float4*)(simP + (size_t)ksi * (N_ * N_) + gid * 4);
    s.x += p.x; s.y += p.y; s.z += p.z; s.w += p.w;
  }
  *(float4*)(sim + gid * 4) = s;
}

// ---------------- 3. top-45 per row: one wave per row, register-resident ----------------
__global__ __launch_bounds__(256) void k_topk(const float* __restrict__ sim,
                                              int* __restrict__ idx_t) {
  int t = threadIdx.x, lane = t & 63, wv = t >> 6;
  int n = blockIdx.x * 4 + wv;
  float v[8];
#pragma unroll
  for (int u = 0; u < 8; ++u) {
    int idx = u * 64 + lane;
    v[u] = (idx == n) ? -3e38f : sim[n * N_ + idx];
  }
  for (int k = 0; k < TK_; ++k) {
    float mv = v[0]; int mi = lane;
#pragma unroll
    for (int u = 1; u < 8; ++u) {
      if (v[u] > mv) { mv = v[u]; mi = u * 64 + lane; }
    }
#pragma unroll
    for (int o = 32; o > 0; o >>= 1) {
      float ov = __shfl_xor(mv, o);
      int   oi = __shfl_xor(mi, o);
      if (ov > mv || (ov == mv && oi < mi)) { mv = ov; mi = oi; }
    }
    if (lane == 0) idx_t[k * N_ + n] = mi;
#pragma unroll
    for (int u = 0; u < 8; ++u)
      if (mi == u * 64 + lane) v[u] = -3e38f;
  }
}

// ---------------- 4a. router stats partials + x->bf16 ----------------
__global__ __launch_bounds__(256) void k_rstats(const float* __restrict__ x,
                                                float* __restrict__ psum,
                                                float* __restrict__ psq,
                                                short* __restrict__ xbf) {
  int b  = blockIdx.x >> 6;
  int ch = blockIdx.x & 63;
  int t = threadIdx.x;
  size_t base = ((size_t)b * L_ + ch * 32) * N_;
  const float* xp = x + base;
  short* xq = xbf + base;
#pragma unroll
  for (int u = 0; u < 2; ++u) {
    int n = t + u * 256;
    float s = 0.f, ss = 0.f;
#pragma unroll 8
    for (int r = 0; r < 32; ++r) {
      float v = xp[r * N_ + n];
      s += v; ss += v * v;
      xq[r * N_ + n] = f2bf(v);
    }
    psum[(b * 64 + ch) * N_ + n] = s;
    psq [(b * 64 + ch) * N_ + n] = ss;
  }
}

// ---------------- 4b. finalize: stats -> Q/K/importance/summary ----------------
__global__ __launch_bounds__(256) void k_rfinal(
    const float* __restrict__ psum, const float* __restrict__ psq,
    const float* __restrict__ var_embed,
    const float* __restrict__ temp_w, const float* __restrict__ temp_b,
    const float* __restrict__ q_w, const float* __restrict__ q_b,
    const float* __restrict__ k_w, const float* __restrict__ k_b,
    const float* __restrict__ imp_w, const float* __restrict__ imp_b,
    float* __restrict__ Q, float* __restrict__ Kv,
    float* __restrict__ imp, float* __restrict__ summary) {
  int gid = blockIdx.x * 256 + threadIdx.x;
  int b = gid >> 9, n = gid & 511;
  float s = 0.f, ss = 0.f;
#pragma unroll 8
  for (int c = 0; c < 64; ++c) {
    s  += psum[(b * 64 + c) * N_ + n];
    ss += psq [(b * 64 + c) * N_ + n];
  }
  float mean = s * (1.f / L_);
  float var  = fmaxf((ss - s * mean) * (1.f / (L_ - 1)), 0.f);
  float stdv = sqrtf(var + 1e-5f);
  summary[b * N_ + n] = mean;
  float vf[32];
#pragma unroll
  for (int i = 0; i < 16; ++i) vf[i] = var_embed[n * 16 + i];
#pragma unroll
  for (int h = 0; h < 16; ++h)
    vf[16 + h] = mean * temp_w[h] + stdv * temp_w[16 + h] + temp_b[h];
#pragma unroll
  for (int h = 0; h < 16; ++h) {
    float qa = q_b[h], ka = k_b[h];
#pragma unroll
    for (int i = 0; i < 32; ++i) {
      qa += vf[i] * q_w[i * 16 + h];
      ka += vf[i] * k_w[i * 16 + h];
    }
    Q[(b * N_ + n) * 16 + h]  = qa;
    Kv[(b * N_ + n) * 16 + h] = ka;
  }
  float ia = imp_b[0];
#pragma unroll
  for (int i = 0; i < 32; ++i) ia += vf[i] * imp_w[i];
  imp[b * N_ + n] = sigmoidf_(ia);
}

// ---------------- 5. cw ----------------
__global__ __launch_bounds__(64) void k_cw(const float* __restrict__ cs,
                                           float* __restrict__ cw) {
  int n = blockIdx.x * 64 + threadIdx.x;
  if (n >= N_) return;
  float v[16], mx = -3e38f;
#pragma unroll
  for (int c = 0; c < 16; ++c) { v[c] = cs[n * 16 + c]; mx = fmaxf(mx, v[c]); }
  float s = 0.f;
#pragma unroll
  for (int c = 0; c < 16; ++c) { v[c] = expf(v[c] - mx); s += v[c]; }
  float inv = 1.f / s;
#pragma unroll
  for (int c = 0; c < 16; ++c) cw[n * 16 + c] = v[c] * inv;
}

// ---------------- 6. center tokens ----------------
__global__ __launch_bounds__(256) void k_ct(const float* __restrict__ summary,
                                            const float* __restrict__ cg_w,
                                            const float* __restrict__ cg_b,
                                            float* __restrict__ ct) {
  int i = blockIdx.x * 256 + threadIdx.x;
  int b = i >> 10, o = i & 1023;
  float a = cg_b[o];
  for (int n = 0; n < N_; ++n) a += summary[b * N_ + n] * cg_w[n * 1024 + o];
  ct[i] = a;
}

// ---------------- 7. misc: cp2 row-sums, bias-sum, vp_b@cp1, vp@cp1 ----------------
__global__ __launch_bounds__(1024) void k_cp2s(const float* __restrict__ cp2_w,
                                               const float* __restrict__ cp2_b,
                                               const float* __restrict__ vp_b,
                                               const float* __restrict__ vp_w,
                                               const float* __restrict__ cp1_w,
                                               float* __restrict__ misc) {
  int t = threadIdx.x;
  if (t < 64) {
    float a = 0.f;
#pragma unroll 8
    for (int d = 0; d < 64; ++d) a += cp2_w[t * 64 + d];
    misc[t] = a;
    float vb = 0.f;
#pragma unroll 8
    for (int e = 0; e < 64; ++e) vb += vp_b[e] * cp1_w[e * 64 + t];
    misc[80 + t] = vb;
  }
  if (t == 0) {
    float bsum = 0.f;
    for (int d = 0; d < 64; ++d) bsum += cp2_b[d];
    misc[64] = bsum;
  }
  {
    int c = t >> 6, d = t & 63;
    float a = 0.f;
#pragma unroll 8
    for (int e = 0; e < 64; ++e) a += vp_w[c * 64 + e] * cp1_w[e * 64 + d];
    misc[96 + t] = a;  // vp1[c][d]
  }
}

// ---------------- 8. ctp' = ct@cp1 + cp1_b + vp_b@cp1 ----------------
__global__ __launch_bounds__(256) void k_ctp(const float* __restrict__ ct,
                                             const float* __restrict__ cp1_w,
                                             const float* __restrict__ cp1_b,
                                             const float* __restrict__ misc,
                                             float* __restrict__ ctp) {
  int i = blockIdx.x * 256 + threadIdx.x;
  int row = i >> 6, d2 = i & 63;
  float a = cp1_b[d2] + misc[80 + d2];
#pragma unroll 8
  for (int d = 0; d < 64; ++d) a += ct[row * 64 + d] * cp1_w[d * 64 + d2];
  ctp[i] = a;
}

// ---------------- 9. W2t[d][m] = bf16( sum_c cw[m][c]*vp1[c][d] ) ----------------
__global__ __launch_bounds__(256) void k_w2(const float* __restrict__ cw,
                                            const float* __restrict__ misc,
                                            short* __restrict__ w2t) {
  int gid = blockIdx.x * 256 + threadIdx.x;  // 32768
  int d = gid >> 9, m = gid & 511;
  float a = 0.f;
#pragma unroll
  for (int c = 0; c < 16; ++c)
    a += cw[m * 16 + c] * misc[96 + c * 64 + d];
  w2t[d * 512 + m] = f2bf(a);
}

// ---------------- 10. wg2[c][n] = sum_m cw[m][c]*gate_w[512+m][n] ----------------
__global__ __launch_bounds__(256) void k_wg2(const float* __restrict__ cw,
                                             const float* __restrict__ gate_w,
                                             float* __restrict__ wg2) {
  int gid = blockIdx.x * 256 + threadIdx.x;  // 8192
  int c = gid >> 9, n = gid & 511;
  float a = 0.f;
  for (int m = 0; m < 512; ++m)
    a += cw[m * 16 + c] * gate_w[(size_t)(512 + m) * 512 + n];
  wg2[c * 512 + n] = a;
}

// ---------------- 11. xcp = xbf @ W2t  (MFMA, [16384,512]@[512->64]) ----------------
__global__ __launch_bounds__(256) void k_xcp(const short* __restrict__ xbf,
                                             const short* __restrict__ w2t,
                                             float* __restrict__ xcp) {
  __shared__ __align__(16) short As[64 * 32];
  __shared__ __align__(16) short Bs[64 * 32];
  int t = threadIdx.x, lane = t & 63, w = t >> 6;
  int lo = lane & 15, hi = lane >> 4;
  int row0 = blockIdx.x * 64;
  f32x4 acc[4] = {};
  int rA = t >> 2, cA = (t & 3) ^ ((rA >> 1) & 3);
  const short* srcA = xbf + (size_t)(row0 + rA) * 512 + cA * 8;
  const short* srcB = w2t + (size_t)rA * 512 + cA * 8;
  int gl = (lo >> 1) & 3;
  int foff = (lo * 4 + (hi ^ gl)) * 8;
  for (int kt = 0; kt < 16; ++kt) {
    gload16(srcA + kt * 32, As + t * 8);
    gload16(srcB + kt * 32, Bs + t * 8);
    __syncthreads();
    bf16x8 b = *(const bf16x8*)(Bs + (w * 64) * 8 + foff);
#pragma unroll
    for (int m = 0; m < 4; ++m) {
      bf16x8 a = *(const bf16x8*)(As + (m * 64) * 8 + foff);
      acc[m] = __builtin_amdgcn_mfma_f32_16x16x32_bf16(a, b, acc[m], 0, 0, 0);
    }
    __syncthreads();
  }
#pragma unroll
  for (int m = 0; m < 4; ++m)
#pragma unroll
    for (int j = 0; j < 4; ++j) {
      int row = row0 + m * 16 + hi * 4 + j;
      int col = w * 16 + lo;
      xcp[(size_t)row * 64 + col] = acc[m][j];
    }
}

// ---------------- 12. s2[row][c] = sum_d gelu(ctp'+xcp)*cp2s + bias -> abuf[512..543] ----------------
__global__ __launch_bounds__(256) void k_s(const float* __restrict__ xcp,
                                           const float* __restrict__ ctp,
                                           const float* __restrict__ misc,
                                           short* __restrict__ abuf) {
  int t = threadIdx.x, lane = t & 63, wv = t >> 6;
  int row = blockIdx.x * 4 + wv;
  int b = row >> 11;
  float v = xcp[(size_t)row * 64 + lane];
  float wgt = misc[lane];
  float bias = misc[64];
  float sval = 0.f;
#pragma unroll
  for (int c = 0; c < 16; ++c) {
    float u = ctp[(b * 16 + c) * 64 + lane] + v;
    float g = 0.5f * u * (1.f + erff(u * 0.70710678118654752f));
    float a = g * wgt;
#pragma unroll
    for (int o = 32; o > 0; o >>= 1) a += __shfl_xor(a, o);
    if (lane == c) sval = a + bias;
  }
  if (lane < 32)
    abuf[(size_t)row * 1024 + 512 + lane] = (lane < 16) ? f2bf(sval) : (short)0;
}

// ---------------- 13. sparse attention weights ----------------
__global__ __launch_bounds__(64) void k_attn(const float* __restrict__ Q,
                                             const float* __restrict__ Kv,
                                             const int* __restrict__ idx_t,
                                             float* __restrict__ w_t) {
  int bn = blockIdx.x;
  int b = bn >> 9, n = bn & (N_ - 1);
  int j = threadIdx.x;
  float s = -3e38f;
  if (j < TK_) {
    int m = idx_t[j * N_ + n];
    const float* qp = Q + (b * N_ + n) * H_;
    const float* kp = Kv + (b * N_ + m) * H_;
    float a = 0.f;
#pragma unroll
    for (int h = 0; h < H_; ++h) a += qp[h] * kp[h];
    s = a * 0.25f;
  }
  float mx = s;
#pragma unroll
  for (int o = 32; o > 0; o >>= 1) mx = fmaxf(mx, __shfl_xor(mx, o));
  float e = (j < TK_) ? expf(s - mx) : 0.f;
  float sum = e;
#pragma unroll
  for (int o = 32; o > 0; o >>= 1) sum += __shfl_xor(sum, o);
  if (j < TK_) w_t[(b * TK_ + j) * N_ + n] = e / sum;
}

// ---------------- 14. ring -> abuf bf16 cols [0,512) ----------------
__global__ __launch_bounds__(256) void k_ring(const float* __restrict__ x,
                                              const float* __restrict__ w_t,
                                              const int* __restrict__ idx_t,
                                              const float* __restrict__ imp,
                                              short* __restrict__ abuf) {
  __shared__ float xs[8 * 516];
  int b = blockIdx.x >> 8;
  int l0 = (blockIdx.x & 255) * 8;
  int t = threadIdx.x;
  for (int e = t; e < 8 * N_; e += 256) {
    int r = e >> 9, n = e & 511;
    xs[r * 516 + n] = x[(b * L_ + l0 + r) * N_ + n];
  }
  __syncthreads();
#pragma unroll
  for (int u = 0; u < 2; ++u) {
    int n = t + u * 256;
    float acc[8] = {0.f, 0.f, 0.f, 0.f, 0.f, 0.f, 0.f, 0.f};
    for (int j = 0; j < TK_; ++j) {
      float wv = w_t[(b * TK_ + j) * N_ + n];
      int m = idx_t[j * N_ + n];
#pragma unroll
      for (int r = 0; r < 8; ++r) acc[r] += wv * xs[r * 516 + m];
    }
    float iv = imp[b * N_ + n];
#pragma unroll
    for (int r = 0; r < 8; ++r) {
      float xv = xs[r * 516 + n];
      abuf[(size_t)(b * L_ + l0 + r) * 1024 + n] = f2bf(iv * acc[r] + (1.f - iv) * xv);
    }
  }
}

// ---------------- 15. wt_gate [512][1024]: k<512 gate_w^T, 512..527 wg2', 528..543 zero ----------------
__global__ __launch_bounds__(256) void k_wtg(const float* __restrict__ gate_w,
                                             const float* __restrict__ wg2,
                                             short* __restrict__ wt) {
  __shared__ float tile[32][33];
  int bk = blockIdx.x;  // 0..16
  int bn = blockIdx.y;  // 0..15
  int t = threadIdx.x;
  int c = t & 31, r = t >> 5;
  if (bk < 16) {
    for (int rr = r; rr < 32; rr += 8)
      tile[rr][c] = gate_w[(size_t)(bk * 32 + rr) * 512 + bn * 32 + c];
  } else {
    for (int rr = r; rr < 32; rr += 8)
      tile[rr][c] = (rr < 16) ? wg2[rr * 512 + bn * 32 + c] : 0.f;
  }
  __syncthreads();
  for (int rr = r; rr < 32; rr += 8)
    wt[(size_t)(bn * 32 + rr) * 1024 + bk * 32 + c] = f2bf(tile[c][rr]);
}

// ---------------- 16. W [K][N] f32 -> Wt [N][K] bf16 (fus weights) ----------------
__global__ __launch_bounds__(256) void k_wt(const float* __restrict__ W,
                                            short* __restrict__ Wt, int K, int N) {
  __shared__ float tile[32][33];
  int bk = blockIdx.x, bn = blockIdx.y;
  int t = threadIdx.x;
  int c = t & 31, r = t >> 5;
  for (int rr = r; rr < 32; rr += 8)
    tile[rr][c] = W[(bk * 32 + rr) * N + bn * 32 + c];
  __syncthreads();
  for (int rr = r; rr < 32; rr += 8)
    Wt[(bn * 32 + rr) * K + bk * 32 + c] = f2bf(tile[c][rr]);
}

// ---------------- 17. cwb [512][32] bf16: kk<16 -> cw[n][kk], else 0 ----------------
__global__ __launch_bounds__(256) void k_cwb(const float* __restrict__ cw,
                                             short* __restrict__ cwb) {
  int gid = blockIdx.x * 256 + threadIdx.x;  // 16384
  int n = gid >> 5, kk = gid & 31;
  cwb[gid] = (kk < 16) ? f2bf(cw[n * 16 + kk]) : (short)0;
}

// ---------------- 18. gate GEMM (MFMA): K=544, + acc2 ctv pass + blend ----------------
__global__ __launch_bounds__(512) void k_gemm_gate(const short* __restrict__ abuf,
                                                   const short* __restrict__ wt,
                                                   const short* __restrict__ cwb,
                                                   const float* __restrict__ gate_b,
                                                   short* __restrict__ fused_bf) {
  __shared__ __align__(16) short As[128 * 32];  // 8 KB
  __shared__ __align__(16) short Bs[256 * 32];  // 16 KB
  int t = threadIdx.x, lane = t & 63, w = t >> 6;
  int lo = lane & 15, hi = lane >> 4;
  int bm = blockIdx.x >> 1, bn = blockIdx.x & 1;
  int row0 = bm * 128, n0 = bn * 256;
  int wm = w >> 2, wn = w & 3;
  f32x4 acc[4][4] = {};
  f32x4 acc2[4][4] = {};
  int pA = w * 64 + lane;
  int rA = pA >> 2, cA = (pA & 3) ^ ((rA >> 1) & 3);
  const short* srcA = abuf + (size_t)(row0 + rA) * 1024 + cA * 8;
  int pB0 = w * 128 + lane;
  int rB0 = pB0 >> 2, cB0 = (pB0 & 3) ^ ((rB0 >> 1) & 3);
  const short* srcB0 = wt + (size_t)(n0 + rB0) * 1024 + cB0 * 8;
  int pB1 = pB0 + 64;
  int rB1 = pB1 >> 2, cB1 = (pB1 & 3) ^ ((rB1 >> 1) & 3);
  const short* srcB1 = wt + (size_t)(n0 + rB1) * 1024 + cB1 * 8;
  int gl = (lo >> 1) & 3;
  int foff = (lo * 4 + (hi ^ gl)) * 8;

  // ---- prologue: acc2 = A_s-tile(kt=16) @ cwb ----
  gload16(srcA + 16 * 32, As + w * 512);
  gload16(cwb + (size_t)(n0 + rB0) * 32 + cB0 * 8, Bs + w * 1024);
  gload16(cwb + (size_t)(n0 + rB1) * 32 + cB1 * 8, Bs + w * 1024 + 512);
  __syncthreads();
  {
    bf16x8 aS[4], b2[4];
#pragma unroll
    for (int m = 0; m < 4; ++m)
      aS[m] = *(const bf16x8*)(As + (wm * 256 + m * 64) * 8 + foff);
#pragma unroll
    for (int n = 0; n < 4; ++n)
      b2[n] = *(const bf16x8*)(Bs + (wn * 256 + n * 64) * 8 + foff);
#pragma unroll
    for (int m = 0; m < 4; ++m)
#pragma unroll
      for (int n = 0; n < 4; ++n)
        acc2[m][n] = __builtin_amdgcn_mfma_f32_16x16x32_bf16(aS[m], b2[n], acc2[m][n], 0, 0, 0);
  }
  __syncthreads();

  // ---- main loop: 17 K-tiles (544 cols: ring 512 + s2 16 + zeros 16) ----
  for (int kt = 0; kt < 17; ++kt) {
    gload16(srcA + kt * 32, As + w * 512);
    gload16(srcB0 + kt * 32, Bs + w * 1024);
    gload16(srcB1 + kt * 32, Bs + w * 1024 + 512);
    __syncthreads();
    bf16x8 a[4], b[4];
#pragma unroll
    for (int m = 0; m < 4; ++m)
      a[m] = *(const bf16x8*)(As + (wm * 256 + m * 64) * 8 + foff);
#pragma unroll
    for (int n = 0; n < 4; ++n)
      b[n] = *(const bf16x8*)(Bs + (wn * 256 + n * 64) * 8 + foff);
#pragma unroll
    for (int m = 0; m < 4; ++m)
#pragma unroll
      for (int n = 0; n < 4; ++n)
        acc[m][n] = __builtin_amdgcn_mfma_f32_16x16x32_bf16(a[m], b[n], acc[m][n], 0, 0, 0);
    __syncthreads();
  }

  // ---- epilogue: gate + blend (ctv = acc2) ----
#pragma unroll
  for (int m = 0; m < 4; ++m) {
    int rbase = row0 + wm * 64 + m * 16 + hi * 4;
#pragma unroll
    for (int j = 0; j < 4; ++j) {
      int row = rbase + j;
#pragma unroll
      for (int n = 0; n < 4; ++n) {
        int col = n0 + wn * 64 + n * 16 + lo;
        float g = sigmoidf_(acc[m][n][j] + gate_b[col]);
        float ringv = bf2f(abuf[(size_t)row * 1024 + col]);
        fused_bf[(size_t)row * 512 + col] = f2bf(g * ringv + (1.f - g) * acc2[m][n][j]);
      }
    }
  }
}

// ---------------- 19. fus GEMM (MFMA) + residual + LayerNorm ----------------
__global__ __launch_bounds__(512) void k_gemm_fus(const short* __restrict__ fused_bf,
                                                  const short* __restrict__ wtf,
                                                  const float* __restrict__ x,
                                                  const float* __restrict__ fus_b,
                                                  const float* __restrict__ ln_g,
                                                  const float* __restrict__ ln_b,
                                                  float* __restrict__ out) {
  __shared__ __align__(16) short As[64 * 32];
  __shared__ __align__(16) short Bs[512 * 32];
  __shared__ float Ssh[8][64], Qsh[8][64];
  __shared__ float mus[64], rss[64];
  int t = threadIdx.x, lane = t & 63, w = t >> 6;
  int lo = lane & 15, hi = lane >> 4;
  int row0 = blockIdx.x * 64;
  f32x4 acc[4][4] = {};
  int pA = w * 64 + lane;
  int rA = pA >> 2, cA = (pA & 3) ^ ((rA >> 1) & 3);
  const short* srcA = fused_bf + (size_t)(row0 + rA) * 512 + cA * 8;
  int gl = (lo >> 1) & 3;
  int foff = (lo * 4 + (hi ^ gl)) * 8;
  for (int kt = 0; kt < 16; ++kt) {
    if (w < 4) gload16(srcA + kt * 32, As + w * 512);
#pragma unroll
    for (int q = 0; q < 4; ++q) {
      int pB = w * 256 + q * 64 + lane;
      int rB = pB >> 2, cB = (pB & 3) ^ ((rB >> 1) & 3);
      gload16(wtf + (size_t)rB * 512 + kt * 32 + cB * 8, Bs + (w * 256 + q * 64) * 8);
    }
    __syncthreads();
    bf16x8 a[4], b[4];
#pragma unroll
    for (int m = 0; m < 4; ++m)
      a[m] = *(const bf16x8*)(As + (m * 64) * 8 + foff);
#pragma unroll
    for (int n = 0; n < 4; ++n)
      b[n] = *(const bf16x8*)(Bs + (w * 256 + n * 64) * 8 + foff);
#pragma unroll
    for (int m = 0; m < 4; ++m)
#pragma unroll
      for (int n = 0; n < 4; ++n)
        acc[m][n] = __builtin_amdgcn_mfma_f32_16x16x32_bf16(a[m], b[n], acc[m][n], 0, 0, 0);
    __syncthreads();
  }
#pragma unroll
  for (int m = 0; m < 4; ++m) {
#pragma unroll
    for (int j = 0; j < 4; ++j) {
      int rl = m * 16 + hi * 4 + j;
      int row = row0 + rl;
      float ps = 0.f, pq = 0.f;
#pragma unroll
      for (int n = 0; n < 4; ++n) {
        int col = w * 64 + n * 16 + lo;
        float h = acc[m][n][j] + fus_b[col] + x[(size_t)row * 512 + col];
        acc[m][n][j] = h;
        ps += h; pq += h * h;
      }
#pragma unroll
      for (int o = 1; o < 16; o <<= 1) {
        ps += __shfl_xor(ps, o);
        pq += __shfl_xor(pq, o);
      }
      if (lo == 0) { Ssh[w][rl] = ps; Qsh[w][rl] = pq; }
    }
  }
  __syncthreads();
  if (t < 64) {
    float s = 0.f, q = 0.f;
#pragma unroll
    for (int ww = 0; ww < 8; ++ww) { s += Ssh[ww][t]; q += Qsh[ww][t]; }
    float mu = s * (1.f / N_);
    float var = q * (1.f / N_) - mu * mu;
    mus[t] = mu;
    rss[t] = rsqrtf(fmaxf(var, 0.f) + 1e-5f);
  }
  __syncthreads();
#pragma unroll
  for (int m = 0; m < 4; ++m) {
#pragma unroll
    for (int j = 0; j < 4; ++j) {
      int rl = m * 16 + hi * 4 + j;
      int row = row0 + rl;
      float mu = mus[rl], rs = rss[rl];
#pragma unroll
      for (int n = 0; n < 4; ++n) {
        int col = w * 64 + n * 16 + lo;
        out[(size_t)row * 512 + col] = (acc[m][n][j] - mu) * rs * ln_g[col] + ln_b[col];
      }
    }
  }
}

extern "C" void kernel_launch(void* const* d_in, const int* in_sizes, int n_in,
                              void* d_out, int out_size, void* d_ws, size_t ws_size,
                              hipStream_t stream) {
  (void)in_sizes; (void)n_in; (void)out_size; (void)ws_size;
  const float* x         = (const float*)d_in[0];
  const float* var_embed = (const float*)d_in[1];
  const float* temp_w    = (const float*)d_in[2];
  const float* temp_b    = (const float*)d_in[3];
  const float* q_w       = (const float*)d_in[4];
  const float* q_b       = (const float*)d_in[5];
  const float* k_w       = (const float*)d_in[6];
  const float* k_b       = (const float*)d_in[7];
  const float* imp_w     = (const float*)d_in[8];
  const float* imp_b     = (const float*)d_in[9];
  const float* cluster   = (const float*)d_in[10];
  const float* vp_w      = (const float*)d_in[11];
  const float* vp_b      = (const float*)d_in[12];
  const float* cp1_w     = (const float*)d_in[13];
  const float* cp1_b     = (const float*)d_in[14];
  const float* cp2_w     = (const float*)d_in[15];
  const float* cp2_b     = (const float*)d_in[16];
  const float* cg_w      = (const float*)d_in[17];
  const float* cg_b      = (const float*)d_in[18];
  const float* gate_w    = (const float*)d_in[19];
  const float* gate_b    = (const float*)d_in[20];
  const float* fus_w     = (const float*)d_in[21];
  const float* fus_b     = (const float*)d_in[22];
  const float* ln_g      = (const float*)d_in[23];
  const float* ln_b      = (const float*)d_in[24];
  float* out = (float*)d_out;
  float* ws  = (float*)d_ws;

  // workspace layout (float offsets)
  float* normed = ws + 0;                 // 1,048,576 (later reused as xcp)
  float* sim    = ws + 1048576;           //   262,144
  int*   idx_t  = (int*)(ws + 1310720);   //    23,040 ints (pad 24,576)
  float* Qb     = ws + 1335296;           //    65,536
  float* Kb     = ws + 1400832;           //    65,536
  float* impb   = ws + 1466368;           //     4,096
  float* summ   = ws + 1470464;           //     4,096
  float* w_t    = ws + 1474560;           //   184,320
  float* cw     = ws + 1658880;           //     8,192
  float* ct     = ws + 1667072;           //     8,192
  float* ctp    = ws + 1675264;           //     8,192
  float* misc   = ws + 1683456;           //     2,048 (cp2sums|bias|vpb1|vp1)
  float* wg2    = ws + 1685504;           //     8,192
  short* w2t    = (short*)(ws + 1693696); //    32,768 shorts
  short* cwb    = (short*)(ws + 1710080); //    16,384 shorts
  short* abuf     = (short*)(ws + 1720320);   // 16384*1024 bf16 = 32 MB
  short* fused_bf = (short*)(ws + 10108928);  // 16384*512 bf16 = 16 MB (also xbf)
  short* wt_gate  = (short*)(ws + 14303232);  // 512*1024 bf16
  short* wt_fus   = (short*)(ws + 14565376);  // 512*512 bf16
  float* psum     = ws + 14696448;            //   262,144
  float* psq      = ws + 14958592;            //   262,144 -> total ~60.9 MB
  // aliases (stream-ordered lifetimes):
  float* simP = (float*)abuf;   // 16x512x512 f32, dead after k_simred
  float* xcp  = normed;         // [16384][64] f32, written after k_sim read normed
  short* xbf  = fused_bf;       // bf16 x, dead before k_gemm_gate writes fused_bf

  k_normed<<<(L_ * N_) / 256, 256, 0, stream>>>(x, normed);
  k_sim<<<64 * KS_, 256, 0, stream>>>(normed, simP);
  k_simred<<<256, 256, 0, stream>>>(simP, sim);
  k_topk<<<N_ / 4, 256, 0, stream>>>(sim, idx_t);
  k_rstats<<<B_ * 64, 256, 0, stream>>>(x, psum, psq, xbf);
  k_rfinal<<<16, 256, 0, stream>>>(psum, psq, var_embed, temp_w, temp_b, q_w, q_b,
                                   k_w, k_b, imp_w, imp_b, Qb, Kb, impb, summ);
  k_cw<<<8, 64, 0, stream>>>(cluster, cw);
  k_cp2s<<<1, 1024, 0, stream>>>(cp2_w, cp2_b, vp_b, vp_w, cp1_w, misc);
  k_ct<<<(B_ * 1024) / 256, 256, 0, stream>>>(summ, cg_w, cg_b, ct);
  k_ctp<<<(B_ * C_ * D_) / 256, 256, 0, stream>>>(ct, cp1_w, cp1_b, misc, ctp);
  k_w2<<<128, 256, 0, stream>>>(cw, misc, w2t);
  k_wg2<<<32, 256, 0, stream>>>(cw, gate_w, wg2);
  k_xcp<<<L_ * B_ / 64, 256, 0, stream>>>(xbf, w2t, xcp);
  k_s<<<L_ * B_ / 4, 256, 0, stream>>>(xcp, ctp, misc, abuf);
  k_attn<<<B_ * N_, 64, 0, stream>>>(Qb, Kb, idx_t, w_t);
  k_wtg<<<dim3(17, 16), 256, 0, stream>>>(gate_w, wg2, wt_gate);
  k_wt<<<dim3(16, 16), 256, 0, stream>>>(fus_w, wt_fus, 512, 512);
  k_cwb<<<64, 256, 0, stream>>>(cw, cwb);
  k_ring<<<B_ * (L_ / 8), 256, 0, stream>>>(x, w_t, idx_t, impb, abuf);
  k_gemm_gate<<<256, 512, 0, stream>>>(abuf, wt_gate, cwb, gate_b, fused_bf);
  k_gemm_fus<<<256, 512, 0, stream>>>(fused_bf, wt_fus, x, fus_b, ln_g, ln_b, out);
}

// Round 6
// 304.671 us; speedup vs baseline: 3.9292x; 1.1845x over previous
//
#include <hip/hip_runtime.h>

#define B_ 8
#define L_ 2048
#define N_ 512
#define H_ 16
#define C_ 16
#define D_ 64
#define TK_ 45
#define KS_ 16

typedef __attribute__((ext_vector_type(8))) short bf16x8;
typedef __attribute__((ext_vector_type(4))) float f32x4;

__device__ __forceinline__ float sigmoidf_(float v) { return 1.f / (1.f + expf(-v)); }

__device__ __forceinline__ short f2bf(float f) {
  union { float f; unsigned u; } v; v.f = f;
  unsigned r = (v.u + 0x7fffu + ((v.u >> 16) & 1u)) >> 16;
  return (short)r;
}
__device__ __forceinline__ float bf2f(short s) {
  union { unsigned u; float f; } v; v.u = ((unsigned)(unsigned short)s) << 16;
  return v.f;
}
__device__ __forceinline__ void gload16(const void* g, void* l) {
  __builtin_amdgcn_global_load_lds((const __attribute__((address_space(1))) unsigned int*)g,
                                   (__attribute__((address_space(3))) unsigned int*)l, 16, 0, 0);
}

// ---------------- 1. batch stats -> normed [L,N] ----------------
__global__ __launch_bounds__(256) void k_normed(const float* __restrict__ x,
                                                float* __restrict__ normed) {
  int i = blockIdx.x * 256 + threadIdx.x;
  float s = 0.f, ss = 0.f;
#pragma unroll
  for (int b = 0; b < B_; ++b) {
    float v = x[b * (L_ * N_) + i];
    s += v; ss += v * v;
  }
  float mean = s * (1.f / B_);
  float var  = fmaxf((ss - s * mean) * (1.f / (B_ - 1)), 0.f);
  normed[i] = mean / (sqrtf(var) + 1e-5f);
}

// ---------------- 2. sim partials: 64x64 tile, K-split 16, 4x4 reg tile ----------------
__global__ __launch_bounds__(256) void k_sim(const float* __restrict__ nrm,
                                             float* __restrict__ simP) {
  __shared__ float As[32 * 64];
  __shared__ float Bs[32 * 64];
  int bx = blockIdx.x;
  int ks = bx >> 6, tile = bx & 63;
  int bi = tile & 7, bj = tile >> 3;
  int t = threadIdx.x, tx = t & 15, ty = t >> 4;
  float acc[4][4] = {};
  int k0 = ks * (L_ / KS_);
  for (int kt = 0; kt < (L_ / KS_) / 32; ++kt) {
    for (int e = t; e < 2048; e += 256) {
      int kk = e >> 6, i = e & 63;
      int krow = k0 + kt * 32 + kk;
      As[e] = nrm[krow * N_ + bi * 64 + i];
      Bs[e] = nrm[krow * N_ + bj * 64 + i];
    }
    __syncthreads();
#pragma unroll
    for (int kk = 0; kk < 32; ++kk) {
      float4 a = *(const float4*)(As + kk * 64 + ty * 4);
      float4 b = *(const float4*)(Bs + kk * 64 + tx * 4);
      float av[4] = {a.x, a.y, a.z, a.w};
      float bv[4] = {b.x, b.y, b.z, b.w};
#pragma unroll
      for (int i = 0; i < 4; ++i)
#pragma unroll
        for (int j = 0; j < 4; ++j)
          acc[i][j] += av[i] * bv[j];
    }
    __syncthreads();
  }
  float* outp = simP + (size_t)ks * (N_ * N_);
#pragma unroll
  for (int i = 0; i < 4; ++i) {
    int row = bi * 64 + ty * 4 + i;
    float4 o = {acc[i][0], acc[i][1], acc[i][2], acc[i][3]};
    *(float4*)(outp + row * N_ + bj * 64 + tx * 4) = o;
  }
}

// ---------------- 2b. reduce K-split partials ----------------
__global__ __launch_bounds__(256) void k_simred(const float* __restrict__ simP,
                                                float* __restrict__ sim) {
  int gid = blockIdx.x * 256 + threadIdx.x;
  float4 s = {0.f, 0.f, 0.f, 0.f};
#pragma unroll
  for (int ksi = 0; ksi < KS_; ++ksi) {
    float4 p = *(const float4*)(simP + (size_t)ksi * (N_ * N_) + gid * 4);
    s.x += p.x; s.y += p.y; s.z += p.z; s.w += p.w;
  }
  *(float4*)(sim + gid * 4) = s;
}

// ---------------- 3. top-45 per row: one wave per row, register-resident ----------------
__global__ __launch_bounds__(256) void k_topk(const float* __restrict__ sim,
                                              int* __restrict__ idx_t) {
  int t = threadIdx.x, lane = t & 63, wv = t >> 6;
  int n = blockIdx.x * 4 + wv;
  float v[8];
#pragma unroll
  for (int u = 0; u < 8; ++u) {
    int idx = u * 64 + lane;
    v[u] = (idx == n) ? -3e38f : sim[n * N_ + idx];
  }
  for (int k = 0; k < TK_; ++k) {
    float mv = v[0]; int mi = lane;
#pragma unroll
    for (int u = 1; u < 8; ++u) {
      if (v[u] > mv) { mv = v[u]; mi = u * 64 + lane; }
    }
#pragma unroll
    for (int o = 32; o > 0; o >>= 1) {
      float ov = __shfl_xor(mv, o);
      int   oi = __shfl_xor(mi, o);
      if (ov > mv || (ov == mv && oi < mi)) { mv = ov; mi = oi; }
    }
    if (lane == 0) idx_t[k * N_ + n] = mi;
#pragma unroll
    for (int u = 0; u < 8; ++u)
      if (mi == u * 64 + lane) v[u] = -3e38f;
  }
}

// ---------------- 4a. router stats partials + x->bf16 ----------------
__global__ __launch_bounds__(256) void k_rstats(const float* __restrict__ x,
                                                float* __restrict__ psum,
                                                float* __restrict__ psq,
                                                short* __restrict__ xbf) {
  int b  = blockIdx.x >> 6;
  int ch = blockIdx.x & 63;
  int t = threadIdx.x;
  size_t base = ((size_t)b * L_ + ch * 32) * N_;
  const float* xp = x + base;
  short* xq = xbf + base;
#pragma unroll
  for (int u = 0; u < 2; ++u) {
    int n = t + u * 256;
    float s = 0.f, ss = 0.f;
#pragma unroll 8
    for (int r = 0; r < 32; ++r) {
      float v = xp[r * N_ + n];
      s += v; ss += v * v;
      xq[r * N_ + n] = f2bf(v);
    }
    psum[(b * 64 + ch) * N_ + n] = s;
    psq [(b * 64 + ch) * N_ + n] = ss;
  }
}

// ---------------- 4b. finalize: stats -> Q/K/importance/summary ----------------
__global__ __launch_bounds__(256) void k_rfinal(
    const float* __restrict__ psum, const float* __restrict__ psq,
    const float* __restrict__ var_embed,
    const float* __restrict__ temp_w, const float* __restrict__ temp_b,
    const float* __restrict__ q_w, const float* __restrict__ q_b,
    const float* __restrict__ k_w, const float* __restrict__ k_b,
    const float* __restrict__ imp_w, const float* __restrict__ imp_b,
    float* __restrict__ Q, float* __restrict__ Kv,
    float* __restrict__ imp, float* __restrict__ summary) {
  int gid = blockIdx.x * 256 + threadIdx.x;
  int b = gid >> 9, n = gid & 511;
  float s = 0.f, ss = 0.f;
#pragma unroll 8
  for (int c = 0; c < 64; ++c) {
    s  += psum[(b * 64 + c) * N_ + n];
    ss += psq [(b * 64 + c) * N_ + n];
  }
  float mean = s * (1.f / L_);
  float var  = fmaxf((ss - s * mean) * (1.f / (L_ - 1)), 0.f);
  float stdv = sqrtf(var + 1e-5f);
  summary[b * N_ + n] = mean;
  float vf[32];
#pragma unroll
  for (int i = 0; i < 16; ++i) vf[i] = var_embed[n * 16 + i];
#pragma unroll
  for (int h = 0; h < 16; ++h)
    vf[16 + h] = mean * temp_w[h] + stdv * temp_w[16 + h] + temp_b[h];
#pragma unroll
  for (int h = 0; h < 16; ++h) {
    float qa = q_b[h], ka = k_b[h];
#pragma unroll
    for (int i = 0; i < 32; ++i) {
      qa += vf[i] * q_w[i * 16 + h];
      ka += vf[i] * k_w[i * 16 + h];
    }
    Q[(b * N_ + n) * 16 + h]  = qa;
    Kv[(b * N_ + n) * 16 + h] = ka;
  }
  float ia = imp_b[0];
#pragma unroll
  for (int i = 0; i < 32; ++i) ia += vf[i] * imp_w[i];
  imp[b * N_ + n] = sigmoidf_(ia);
}

// ---------------- 5. cw ----------------
__global__ __launch_bounds__(64) void k_cw(const float* __restrict__ cs,
                                           float* __restrict__ cw) {
  int n = blockIdx.x * 64 + threadIdx.x;
  if (n >= N_) return;
  float v[16], mx = -3e38f;
#pragma unroll
  for (int c = 0; c < 16; ++c) { v[c] = cs[n * 16 + c]; mx = fmaxf(mx, v[c]); }
  float s = 0.f;
#pragma unroll
  for (int c = 0; c < 16; ++c) { v[c] = expf(v[c] - mx); s += v[c]; }
  float inv = 1.f / s;
#pragma unroll
  for (int c = 0; c < 16; ++c) cw[n * 16 + c] = v[c] * inv;
}

// ---------------- 6. center tokens ----------------
__global__ __launch_bounds__(256) void k_ct(const float* __restrict__ summary,
                                            const float* __restrict__ cg_w,
                                            const float* __restrict__ cg_b,
                                            float* __restrict__ ct) {
  int i = blockIdx.x * 256 + threadIdx.x;
  int b = i >> 10, o = i & 1023;
  float a = cg_b[o];
  for (int n = 0; n < N_; ++n) a += summary[b * N_ + n] * cg_w[n * 1024 + o];
  ct[i] = a;
}

// ---------------- 7. misc: cp2 row-sums, bias-sum, vp_b@cp1, vp@cp1 ----------------
__global__ __launch_bounds__(1024) void k_cp2s(const float* __restrict__ cp2_w,
                                               const float* __restrict__ cp2_b,
                                               const float* __restrict__ vp_b,
                                               const float* __restrict__ vp_w,
                                               const float* __restrict__ cp1_w,
                                               float* __restrict__ misc) {
  int t = threadIdx.x;
  if (t < 64) {
    float a = 0.f;
#pragma unroll 8
    for (int d = 0; d < 64; ++d) a += cp2_w[t * 64 + d];
    misc[t] = a;
    float vb = 0.f;
#pragma unroll 8
    for (int e = 0; e < 64; ++e) vb += vp_b[e] * cp1_w[e * 64 + t];
    misc[80 + t] = vb;
  }
  if (t == 0) {
    float bsum = 0.f;
    for (int d = 0; d < 64; ++d) bsum += cp2_b[d];
    misc[64] = bsum;
  }
  {
    int c = t >> 6, d = t & 63;
    float a = 0.f;
#pragma unroll 8
    for (int e = 0; e < 64; ++e) a += vp_w[c * 64 + e] * cp1_w[e * 64 + d];
    misc[96 + t] = a;  // vp1[c][d]
  }
}

// ---------------- 8. ctp' = ct@cp1 + cp1_b + vp_b@cp1 ----------------
__global__ __launch_bounds__(256) void k_ctp(const float* __restrict__ ct,
                                             const float* __restrict__ cp1_w,
                                             const float* __restrict__ cp1_b,
                                             const float* __restrict__ misc,
                                             float* __restrict__ ctp) {
  int i = blockIdx.x * 256 + threadIdx.x;
  int row = i >> 6, d2 = i & 63;
  float a = cp1_b[d2] + misc[80 + d2];
#pragma unroll 8
  for (int d = 0; d < 64; ++d) a += ct[row * 64 + d] * cp1_w[d * 64 + d2];
  ctp[i] = a;
}

// ---------------- 9. W2t[d][m] = bf16( sum_c cw[m][c]*vp1[c][d] ) ----------------
__global__ __launch_bounds__(256) void k_w2(const float* __restrict__ cw,
                                            const float* __restrict__ misc,
                                            short* __restrict__ w2t) {
  int gid = blockIdx.x * 256 + threadIdx.x;  // 32768
  int d = gid >> 9, m = gid & 511;
  float a = 0.f;
#pragma unroll
  for (int c = 0; c < 16; ++c)
    a += cw[m * 16 + c] * misc[96 + c * 64 + d];
  w2t[d * 512 + m] = f2bf(a);
}

// ---------------- 10. wg2[c][n] = sum_m cw[m][c]*gate_w[512+m][n] ----------------
__global__ __launch_bounds__(256) void k_wg2(const float* __restrict__ cw,
                                             const float* __restrict__ gate_w,
                                             float* __restrict__ wg2) {
  int gid = blockIdx.x * 256 + threadIdx.x;  // 8192
  int c = gid >> 9, n = gid & 511;
  float a = 0.f;
  for (int m = 0; m < 512; ++m)
    a += cw[m * 16 + c] * gate_w[(size_t)(512 + m) * 512 + n];
  wg2[c * 512 + n] = a;
}

// ---------------- 11. xcp = xbf @ W2t  (MFMA, [16384,512]@[512->64]) ----------------
__global__ __launch_bounds__(256) void k_xcp(const short* __restrict__ xbf,
                                             const short* __restrict__ w2t,
                                             float* __restrict__ xcp) {
  __shared__ __align__(16) short As[64 * 32];
  __shared__ __align__(16) short Bs[64 * 32];
  int t = threadIdx.x, lane = t & 63, w = t >> 6;
  int lo = lane & 15, hi = lane >> 4;
  int row0 = blockIdx.x * 64;
  f32x4 acc[4] = {};
  int rA = t >> 2, cA = (t & 3) ^ ((rA >> 1) & 3);
  const short* srcA = xbf + (size_t)(row0 + rA) * 512 + cA * 8;
  const short* srcB = w2t + (size_t)rA * 512 + cA * 8;
  int gl = (lo >> 1) & 3;
  int foff = (lo * 4 + (hi ^ gl)) * 8;
  for (int kt = 0; kt < 16; ++kt) {
    gload16(srcA + kt * 32, As + t * 8);
    gload16(srcB + kt * 32, Bs + t * 8);
    __syncthreads();
    bf16x8 b = *(const bf16x8*)(Bs + (w * 64) * 8 + foff);
#pragma unroll
    for (int m = 0; m < 4; ++m) {
      bf16x8 a = *(const bf16x8*)(As + (m * 64) * 8 + foff);
      acc[m] = __builtin_amdgcn_mfma_f32_16x16x32_bf16(a, b, acc[m], 0, 0, 0);
    }
    __syncthreads();
  }
#pragma unroll
  for (int m = 0; m < 4; ++m)
#pragma unroll
    for (int j = 0; j < 4; ++j) {
      int row = row0 + m * 16 + hi * 4 + j;
      int col = w * 16 + lo;
      xcp[(size_t)row * 64 + col] = acc[m][j];
    }
}

// ---------------- 12. s2[row][c] -> abuf[512..543] ----------------
__global__ __launch_bounds__(256) void k_s(const float* __restrict__ xcp,
                                           const float* __restrict__ ctp,
                                           const float* __restrict__ misc,
                                           short* __restrict__ abuf) {
  int t = threadIdx.x, lane = t & 63, wv = t >> 6;
  int row = blockIdx.x * 4 + wv;
  int b = row >> 11;
  float v = xcp[(size_t)row * 64 + lane];
  float wgt = misc[lane];
  float bias = misc[64];
  float sval = 0.f;
#pragma unroll
  for (int c = 0; c < 16; ++c) {
    float u = ctp[(b * 16 + c) * 64 + lane] + v;
    float g = 0.5f * u * (1.f + erff(u * 0.70710678118654752f));
    float a = g * wgt;
#pragma unroll
    for (int o = 32; o > 0; o >>= 1) a += __shfl_xor(a, o);
    if (lane == c) sval = a + bias;
  }
  if (lane < 32)
    abuf[(size_t)row * 1024 + 512 + lane] = (lane < 16) ? f2bf(sval) : (short)0;
}

// ---------------- 13. attention -> dense At[b][n][m] bf16 scatter ----------------
__global__ __launch_bounds__(64) void k_attn(const float* __restrict__ Q,
                                             const float* __restrict__ Kv,
                                             const int* __restrict__ idx_t,
                                             short* __restrict__ At) {
  int bn = blockIdx.x;
  int b = bn >> 9, n = bn & (N_ - 1);
  int j = threadIdx.x;
  float s = -3e38f;
  int m = 0;
  if (j < TK_) {
    m = idx_t[j * N_ + n];
    const float* qp = Q + (b * N_ + n) * H_;
    const float* kp = Kv + (b * N_ + m) * H_;
    float a = 0.f;
#pragma unroll
    for (int h = 0; h < H_; ++h) a += qp[h] * kp[h];
    s = a * 0.25f;
  }
  float mx = s;
#pragma unroll
  for (int o = 32; o > 0; o >>= 1) mx = fmaxf(mx, __shfl_xor(mx, o));
  float e = (j < TK_) ? expf(s - mx) : 0.f;
  float sum = e;
#pragma unroll
  for (int o = 32; o > 0; o >>= 1) sum += __shfl_xor(sum, o);
  if (j < TK_) At[((size_t)b * N_ + n) * N_ + m] = f2bf(e / sum);
}

// ---------------- 14. ring GEMM: routed = xbf @ At^T(b), blend -> abuf[0,512) ----------------
__global__ __launch_bounds__(512) void k_rgemm(const short* __restrict__ xbf,
                                               const short* __restrict__ At,
                                               const float* __restrict__ imp,
                                               const float* __restrict__ x,
                                               short* __restrict__ abuf) {
  __shared__ __align__(16) short As[128 * 32];
  __shared__ __align__(16) short Bs[256 * 32];
  int t = threadIdx.x, lane = t & 63, w = t >> 6;
  int lo = lane & 15, hi = lane >> 4;
  int b = blockIdx.x >> 5;
  int tile = blockIdx.x & 31;
  int bm = tile >> 1, bn = tile & 1;
  int row0 = b * L_ + bm * 128, n0 = bn * 256;
  int wm = w >> 2, wn = w & 3;
  f32x4 acc[4][4] = {};
  int pA = w * 64 + lane;
  int rA = pA >> 2, cA = (pA & 3) ^ ((rA >> 1) & 3);
  const short* srcA = xbf + (size_t)(row0 + rA) * 512 + cA * 8;
  int pB0 = w * 128 + lane;
  int rB0 = pB0 >> 2, cB0 = (pB0 & 3) ^ ((rB0 >> 1) & 3);
  const short* srcB0 = At + ((size_t)b * N_ + n0 + rB0) * 512 + cB0 * 8;
  int pB1 = pB0 + 64;
  int rB1 = pB1 >> 2, cB1 = (pB1 & 3) ^ ((rB1 >> 1) & 3);
  const short* srcB1 = At + ((size_t)b * N_ + n0 + rB1) * 512 + cB1 * 8;
  int gl = (lo >> 1) & 3;
  int foff = (lo * 4 + (hi ^ gl)) * 8;
  for (int kt = 0; kt < 16; ++kt) {
    gload16(srcA + kt * 32, As + w * 512);
    gload16(srcB0 + kt * 32, Bs + w * 1024);
    gload16(srcB1 + kt * 32, Bs + w * 1024 + 512);
    __syncthreads();
    bf16x8 a[4], bb[4];
#pragma unroll
    for (int m = 0; m < 4; ++m)
      a[m] = *(const bf16x8*)(As + (wm * 256 + m * 64) * 8 + foff);
#pragma unroll
    for (int n = 0; n < 4; ++n)
      bb[n] = *(const bf16x8*)(Bs + (wn * 256 + n * 64) * 8 + foff);
#pragma unroll
    for (int m = 0; m < 4; ++m)
#pragma unroll
      for (int n = 0; n < 4; ++n)
        acc[m][n] = __builtin_amdgcn_mfma_f32_16x16x32_bf16(a[m], bb[n], acc[m][n], 0, 0, 0);
    __syncthreads();
  }
#pragma unroll
  for (int m = 0; m < 4; ++m) {
    int rbase = row0 + wm * 64 + m * 16 + hi * 4;
#pragma unroll
    for (int j = 0; j < 4; ++j) {
      int row = rbase + j;
#pragma unroll
      for (int n = 0; n < 4; ++n) {
        int col = n0 + wn * 64 + n * 16 + lo;
        float iv = imp[b * N_ + col];
        float xv = x[(size_t)row * 512 + col];
        abuf[(size_t)row * 1024 + col] = f2bf(iv * acc[m][n][j] + (1.f - iv) * xv);
      }
    }
  }
}

// ---------------- 15. wt_gate [512][1024] ----------------
__global__ __launch_bounds__(256) void k_wtg(const float* __restrict__ gate_w,
                                             const float* __restrict__ wg2,
                                             short* __restrict__ wt) {
  __shared__ float tile[32][33];
  int bk = blockIdx.x;  // 0..16
  int bn = blockIdx.y;  // 0..15
  int t = threadIdx.x;
  int c = t & 31, r = t >> 5;
  if (bk < 16) {
    for (int rr = r; rr < 32; rr += 8)
      tile[rr][c] = gate_w[(size_t)(bk * 32 + rr) * 512 + bn * 32 + c];
  } else {
    for (int rr = r; rr < 32; rr += 8)
      tile[rr][c] = (rr < 16) ? wg2[rr * 512 + bn * 32 + c] : 0.f;
  }
  __syncthreads();
  for (int rr = r; rr < 32; rr += 8)
    wt[(size_t)(bn * 32 + rr) * 1024 + bk * 32 + c] = f2bf(tile[c][rr]);
}

// ---------------- 16. W [K][N] f32 -> Wt [N][K] bf16 (fus weights) ----------------
__global__ __launch_bounds__(256) void k_wt(const float* __restrict__ W,
                                            short* __restrict__ Wt, int K, int N) {
  __shared__ float tile[32][33];
  int bk = blockIdx.x, bn = blockIdx.y;
  int t = threadIdx.x;
  int c = t & 31, r = t >> 5;
  for (int rr = r; rr < 32; rr += 8)
    tile[rr][c] = W[(bk * 32 + rr) * N + bn * 32 + c];
  __syncthreads();
  for (int rr = r; rr < 32; rr += 8)
    Wt[(bn * 32 + rr) * K + bk * 32 + c] = f2bf(tile[c][rr]);
}

// ---------------- 17. cwb [512][32] bf16 ----------------
__global__ __launch_bounds__(256) void k_cwb(const float* __restrict__ cw,
                                             short* __restrict__ cwb) {
  int gid = blockIdx.x * 256 + threadIdx.x;  // 16384
  int n = gid >> 5, kk = gid & 31;
  cwb[gid] = (kk < 16) ? f2bf(cw[n * 16 + kk]) : (short)0;
}

// ---------------- 18. gate GEMM (MFMA): K=544, + acc2 ctv pass + blend ----------------
__global__ __launch_bounds__(512) void k_gemm_gate(const short* __restrict__ abuf,
                                                   const short* __restrict__ wt,
                                                   const short* __restrict__ cwb,
                                                   const float* __restrict__ gate_b,
                                                   short* __restrict__ fused_bf) {
  __shared__ __align__(16) short As[128 * 32];
  __shared__ __align__(16) short Bs[256 * 32];
  int t = threadIdx.x, lane = t & 63, w = t >> 6;
  int lo = lane & 15, hi = lane >> 4;
  int bm = blockIdx.x >> 1, bn = blockIdx.x & 1;
  int row0 = bm * 128, n0 = bn * 256;
  int wm = w >> 2, wn = w & 3;
  f32x4 acc[4][4] = {};
  f32x4 acc2[4][4] = {};
  int pA = w * 64 + lane;
  int rA = pA >> 2, cA = (pA & 3) ^ ((rA >> 1) & 3);
  const short* srcA = abuf + (size_t)(row0 + rA) * 1024 + cA * 8;
  int pB0 = w * 128 + lane;
  int rB0 = pB0 >> 2, cB0 = (pB0 & 3) ^ ((rB0 >> 1) & 3);
  const short* srcB0 = wt + (size_t)(n0 + rB0) * 1024 + cB0 * 8;
  int pB1 = pB0 + 64;
  int rB1 = pB1 >> 2, cB1 = (pB1 & 3) ^ ((rB1 >> 1) & 3);
  const short* srcB1 = wt + (size_t)(n0 + rB1) * 1024 + cB1 * 8;
  int gl = (lo >> 1) & 3;
  int foff = (lo * 4 + (hi ^ gl)) * 8;

  gload16(srcA + 16 * 32, As + w * 512);
  gload16(cwb + (size_t)(n0 + rB0) * 32 + cB0 * 8, Bs + w * 1024);
  gload16(cwb + (size_t)(n0 + rB1) * 32 + cB1 * 8, Bs + w * 1024 + 512);
  __syncthreads();
  {
    bf16x8 aS[4], b2[4];
#pragma unroll
    for (int m = 0; m < 4; ++m)
      aS[m] = *(const bf16x8*)(As + (wm * 256 + m * 64) * 8 + foff);
#pragma unroll
    for (int n = 0; n < 4; ++n)
      b2[n] = *(const bf16x8*)(Bs + (wn * 256 + n * 64) * 8 + foff);
#pragma unroll
    for (int m = 0; m < 4; ++m)
#pragma unroll
      for (int n = 0; n < 4; ++n)
        acc2[m][n] = __builtin_amdgcn_mfma_f32_16x16x32_bf16(aS[m], b2[n], acc2[m][n], 0, 0, 0);
  }
  __syncthreads();

  for (int kt = 0; kt < 17; ++kt) {
    gload16(srcA + kt * 32, As + w * 512);
    gload16(srcB0 + kt * 32, Bs + w * 1024);
    gload16(srcB1 + kt * 32, Bs + w * 1024 + 512);
    __syncthreads();
    bf16x8 a[4], b[4];
#pragma unroll
    for (int m = 0; m < 4; ++m)
      a[m] = *(const bf16x8*)(As + (wm * 256 + m * 64) * 8 + foff);
#pragma unroll
    for (int n = 0; n < 4; ++n)
      b[n] = *(const bf16x8*)(Bs + (wn * 256 + n * 64) * 8 + foff);
#pragma unroll
    for (int m = 0; m < 4; ++m)
#pragma unroll
      for (int n = 0; n < 4; ++n)
        acc[m][n] = __builtin_amdgcn_mfma_f32_16x16x32_bf16(a[m], b[n], acc[m][n], 0, 0, 0);
    __syncthreads();
  }

#pragma unroll
  for (int m = 0; m < 4; ++m) {
    int rbase = row0 + wm * 64 + m * 16 + hi * 4;
#pragma unroll
    for (int j = 0; j < 4; ++j) {
      int row = rbase + j;
#pragma unroll
      for (int n = 0; n < 4; ++n) {
        int col = n0 + wn * 64 + n * 16 + lo;
        float g = sigmoidf_(acc[m][n][j] + gate_b[col]);
        float ringv = bf2f(abuf[(size_t)row * 1024 + col]);
        fused_bf[(size_t)row * 512 + col] = f2bf(g * ringv + (1.f - g) * acc2[m][n][j]);
      }
    }
  }
}

// ---------------- 19. fus GEMM (MFMA) + residual + LayerNorm ----------------
__global__ __launch_bounds__(512) void k_gemm_fus(const short* __restrict__ fused_bf,
                                                  const short* __restrict__ wtf,
                                                  const float* __restrict__ x,
                                                  const float* __restrict__ fus_b,
                                                  const float* __restrict__ ln_g,
                                                  const float* __restrict__ ln_b,
                                                  float* __restrict__ out) {
  __shared__ __align__(16) short As[64 * 32];
  __shared__ __align__(16) short Bs[512 * 32];
  __shared__ float Ssh[8][64], Qsh[8][64];
  __shared__ float mus[64], rss[64];
  int t = threadIdx.x, lane = t & 63, w = t >> 6;
  int lo = lane & 15, hi = lane >> 4;
  int row0 = blockIdx.x * 64;
  f32x4 acc[4][4] = {};
  int pA = w * 64 + lane;
  int rA = pA >> 2, cA = (pA & 3) ^ ((rA >> 1) & 3);
  const short* srcA = fused_bf + (size_t)(row0 + rA) * 512 + cA * 8;
  int gl = (lo >> 1) & 3;
  int foff = (lo * 4 + (hi ^ gl)) * 8;
  for (int kt = 0; kt < 16; ++kt) {
    if (w < 4) gload16(srcA + kt * 32, As + w * 512);
#pragma unroll
    for (int q = 0; q < 4; ++q) {
      int pB = w * 256 + q * 64 + lane;
      int rB = pB >> 2, cB = (pB & 3) ^ ((rB >> 1) & 3);
      gload16(wtf + (size_t)rB * 512 + kt * 32 + cB * 8, Bs + (w * 256 + q * 64) * 8);
    }
    __syncthreads();
    bf16x8 a[4], b[4];
#pragma unroll
    for (int m = 0; m < 4; ++m)
      a[m] = *(const bf16x8*)(As + (m * 64) * 8 + foff);
#pragma unroll
    for (int n = 0; n < 4; ++n)
      b[n] = *(const bf16x8*)(Bs + (w * 256 + n * 64) * 8 + foff);
#pragma unroll
    for (int m = 0; m < 4; ++m)
#pragma unroll
      for (int n = 0; n < 4; ++n)
        acc[m][n] = __builtin_amdgcn_mfma_f32_16x16x32_bf16(a[m], b[n], acc[m][n], 0, 0, 0);
    __syncthreads();
  }
#pragma unroll
  for (int m = 0; m < 4; ++m) {
#pragma unroll
    for (int j = 0; j < 4; ++j) {
      int rl = m * 16 + hi * 4 + j;
      int row = row0 + rl;
      float ps = 0.f, pq = 0.f;
#pragma unroll
      for (int n = 0; n < 4; ++n) {
        int col = w * 64 + n * 16 + lo;
        float h = acc[m][n][j] + fus_b[col] + x[(size_t)row * 512 + col];
        acc[m][n][j] = h;
        ps += h; pq += h * h;
      }
#pragma unroll
      for (int o = 1; o < 16; o <<= 1) {
        ps += __shfl_xor(ps, o);
        pq += __shfl_xor(pq, o);
      }
      if (lo == 0) { Ssh[w][rl] = ps; Qsh[w][rl] = pq; }
    }
  }
  __syncthreads();
  if (t < 64) {
    float s = 0.f, q = 0.f;
#pragma unroll
    for (int ww = 0; ww < 8; ++ww) { s += Ssh[ww][t]; q += Qsh[ww][t]; }
    float mu = s * (1.f / N_);
    float var = q * (1.f / N_) - mu * mu;
    mus[t] = mu;
    rss[t] = rsqrtf(fmaxf(var, 0.f) + 1e-5f);
  }
  __syncthreads();
#pragma unroll
  for (int m = 0; m < 4; ++m) {
#pragma unroll
    for (int j = 0; j < 4; ++j) {
      int rl = m * 16 + hi * 4 + j;
      int row = row0 + rl;
      float mu = mus[rl], rs = rss[rl];
#pragma unroll
      for (int n = 0; n < 4; ++n) {
        int col = w * 64 + n * 16 + lo;
        out[(size_t)row * 512 + col] = (acc[m][n][j] - mu) * rs * ln_g[col] + ln_b[col];
      }
    }
  }
}

extern "C" void kernel_launch(void* const* d_in, const int* in_sizes, int n_in,
                              void* d_out, int out_size, void* d_ws, size_t ws_size,
                              hipStream_t stream) {
  (void)in_sizes; (void)n_in; (void)out_size; (void)ws_size;
  const float* x         = (const float*)d_in[0];
  const float* var_embed = (const float*)d_in[1];
  const float* temp_w    = (const float*)d_in[2];
  const float* temp_b    = (const float*)d_in[3];
  const float* q_w       = (const float*)d_in[4];
  const float* q_b       = (const float*)d_in[5];
  const float* k_w       = (const float*)d_in[6];
  const float* k_b       = (const float*)d_in[7];
  const float* imp_w     = (const float*)d_in[8];
  const float* imp_b     = (const float*)d_in[9];
  const float* cluster   = (const float*)d_in[10];
  const float* vp_w      = (const float*)d_in[11];
  const float* vp_b      = (const float*)d_in[12];
  const float* cp1_w     = (const float*)d_in[13];
  const float* cp1_b     = (const float*)d_in[14];
  const float* cp2_w     = (const float*)d_in[15];
  const float* cp2_b     = (const float*)d_in[16];
  const float* cg_w      = (const float*)d_in[17];
  const float* cg_b      = (const float*)d_in[18];
  const float* gate_w    = (const float*)d_in[19];
  const float* gate_b    = (const float*)d_in[20];
  const float* fus_w     = (const float*)d_in[21];
  const float* fus_b     = (const float*)d_in[22];
  const float* ln_g      = (const float*)d_in[23];
  const float* ln_b      = (const float*)d_in[24];
  float* out = (float*)d_out;
  float* ws  = (float*)d_ws;

  // workspace layout (float offsets)
  float* normed = ws + 0;                 // 1,048,576: normed -> xcp -> At (3 lives)
  float* sim    = ws + 1048576;           //   262,144
  int*   idx_t  = (int*)(ws + 1310720);   //    23,040 ints (pad 24,576)
  float* Qb     = ws + 1335296;           //    65,536
  float* Kb     = ws + 1400832;           //    65,536
  float* impb   = ws + 1466368;           //     4,096
  float* summ   = ws + 1470464;           //     4,096
  float* cw     = ws + 1658880;           //     8,192
  float* ct     = ws + 1667072;           //     8,192
  float* ctp    = ws + 1675264;           //     8,192
  float* misc   = ws + 1683456;           //     2,048
  float* wg2    = ws + 1685504;           //     8,192
  short* w2t    = (short*)(ws + 1693696); //    32,768 shorts
  short* cwb    = (short*)(ws + 1710080); //    16,384 shorts
  short* abuf     = (short*)(ws + 1720320);   // 16384*1024 bf16 = 32 MB
  short* fused_bf = (short*)(ws + 10108928);  // 16384*512 bf16 = 16 MB (also xbf)
  short* wt_gate  = (short*)(ws + 14303232);  // 512*1024 bf16
  short* wt_fus   = (short*)(ws + 14565376);  // 512*512 bf16
  float* psum     = ws + 14696448;            //   262,144
  float* psq      = ws + 14958592;            //   262,144 -> total ~60.9 MB
  // aliases (stream-ordered lifetimes):
  float* simP = (float*)abuf;   // dead after k_simred
  float* xcp  = normed;         // written after k_sim consumed normed
  short* At   = (short*)normed; // 8*512*512 bf16 = 4MB, after k_s consumed xcp
  short* xbf  = fused_bf;       // dead before k_gemm_gate writes fused_bf

  k_normed<<<(L_ * N_) / 256, 256, 0, stream>>>(x, normed);
  k_sim<<<64 * KS_, 256, 0, stream>>>(normed, simP);
  k_simred<<<256, 256, 0, stream>>>(simP, sim);
  k_topk<<<N_ / 4, 256, 0, stream>>>(sim, idx_t);
  k_rstats<<<B_ * 64, 256, 0, stream>>>(x, psum, psq, xbf);
  k_rfinal<<<16, 256, 0, stream>>>(psum, psq, var_embed, temp_w, temp_b, q_w, q_b,
                                   k_w, k_b, imp_w, imp_b, Qb, Kb, impb, summ);
  k_cw<<<8, 64, 0, stream>>>(cluster, cw);
  k_cp2s<<<1, 1024, 0, stream>>>(cp2_w, cp2_b, vp_b, vp_w, cp1_w, misc);
  k_ct<<<(B_ * 1024) / 256, 256, 0, stream>>>(summ, cg_w, cg_b, ct);
  k_ctp<<<(B_ * C_ * D_) / 256, 256, 0, stream>>>(ct, cp1_w, cp1_b, misc, ctp);
  k_w2<<<128, 256, 0, stream>>>(cw, misc, w2t);
  k_wg2<<<32, 256, 0, stream>>>(cw, gate_w, wg2);
  k_xcp<<<L_ * B_ / 64, 256, 0, stream>>>(xbf, w2t, xcp);
  k_s<<<L_ * B_ / 4, 256, 0, stream>>>(xcp, ctp, misc, abuf);
  // At aliases xcp/normed: zero AFTER k_s consumed xcp
  hipMemsetAsync(At, 0, (size_t)B_ * N_ * N_ * 2, stream);
  k_attn<<<B_ * N_, 64, 0, stream>>>(Qb, Kb, idx_t, At);
  k_wtg<<<dim3(17, 16), 256, 0, stream>>>(gate_w, wg2, wt_gate);
  k_wt<<<dim3(16, 16), 256, 0, stream>>>(fus_w, wt_fus, 512, 512);
  k_cwb<<<64, 256, 0, stream>>>(cw, cwb);
  k_rgemm<<<B_ * 32, 512, 0, stream>>>(xbf, At, impb, x, abuf);
  k_gemm_gate<<<256, 512, 0, stream>>>(abuf, wt_gate, cwb, gate_b, fused_bf);
  k_gemm_fus<<<256, 512, 0, stream>>>(fused_bf, wt_fus, x, fus_b, ln_g, ln_b, out);
}

// Round 7
// 292.967 us; speedup vs baseline: 4.0861x; 1.0399x over previous
//
#include <hip/hip_runtime.h>

#define B_ 8
#define L_ 2048
#define N_ 512
#define H_ 16
#define C_ 16
#define D_ 64
#define TK_ 45
#define KS_ 16

typedef __attribute__((ext_vector_type(8))) short bf16x8;
typedef __attribute__((ext_vector_type(4))) float f32x4;

__device__ __forceinline__ float sigmoidf_(float v) { return 1.f / (1.f + expf(-v)); }

__device__ __forceinline__ short f2bf(float f) {
  union { float f; unsigned u; } v; v.f = f;
  unsigned r = (v.u + 0x7fffu + ((v.u >> 16) & 1u)) >> 16;
  return (short)r;
}
__device__ __forceinline__ float bf2f(short s) {
  union { unsigned u; float f; } v; v.u = ((unsigned)(unsigned short)s) << 16;
  return v.f;
}
__device__ __forceinline__ void gload16(const void* g, void* l) {
  __builtin_amdgcn_global_load_lds((const __attribute__((address_space(1))) unsigned int*)g,
                                   (__attribute__((address_space(3))) unsigned int*)l, 16, 0, 0);
}

// ---------------- 1. batch stats -> normed [L,N] ----------------
__global__ __launch_bounds__(256) void k_normed(const float* __restrict__ x,
                                                float* __restrict__ normed) {
  int i = blockIdx.x * 256 + threadIdx.x;
  float s = 0.f, ss = 0.f;
#pragma unroll
  for (int b = 0; b < B_; ++b) {
    float v = x[b * (L_ * N_) + i];
    s += v; ss += v * v;
  }
  float mean = s * (1.f / B_);
  float var  = fmaxf((ss - s * mean) * (1.f / (B_ - 1)), 0.f);
  normed[i] = mean / (sqrtf(var) + 1e-5f);
}

// ---------------- 2. sim partials ----------------
__global__ __launch_bounds__(256) void k_sim(const float* __restrict__ nrm,
                                             float* __restrict__ simP) {
  __shared__ float As[32 * 64];
  __shared__ float Bs[32 * 64];
  int bx = blockIdx.x;
  int ks = bx >> 6, tile = bx & 63;
  int bi = tile & 7, bj = tile >> 3;
  int t = threadIdx.x, tx = t & 15, ty = t >> 4;
  float acc[4][4] = {};
  int k0 = ks * (L_ / KS_);
  for (int kt = 0; kt < (L_ / KS_) / 32; ++kt) {
    for (int e = t; e < 2048; e += 256) {
      int kk = e >> 6, i = e & 63;
      int krow = k0 + kt * 32 + kk;
      As[e] = nrm[krow * N_ + bi * 64 + i];
      Bs[e] = nrm[krow * N_ + bj * 64 + i];
    }
    __syncthreads();
#pragma unroll
    for (int kk = 0; kk < 32; ++kk) {
      float4 a = *(const float4*)(As + kk * 64 + ty * 4);
      float4 b = *(const float4*)(Bs + kk * 64 + tx * 4);
      float av[4] = {a.x, a.y, a.z, a.w};
      float bv[4] = {b.x, b.y, b.z, b.w};
#pragma unroll
      for (int i = 0; i < 4; ++i)
#pragma unroll
        for (int j = 0; j < 4; ++j)
          acc[i][j] += av[i] * bv[j];
    }
    __syncthreads();
  }
  float* outp = simP + (size_t)ks * (N_ * N_);
#pragma unroll
  for (int i = 0; i < 4; ++i) {
    int row = bi * 64 + ty * 4 + i;
    float4 o = {acc[i][0], acc[i][1], acc[i][2], acc[i][3]};
    *(float4*)(outp + row * N_ + bj * 64 + tx * 4) = o;
  }
}

// ---------------- 2b. reduce K-split partials ----------------
__global__ __launch_bounds__(256) void k_simred(const float* __restrict__ simP,
                                                float* __restrict__ sim) {
  int gid = blockIdx.x * 256 + threadIdx.x;
  float4 s = {0.f, 0.f, 0.f, 0.f};
#pragma unroll
  for (int ksi = 0; ksi < KS_; ++ksi) {
    float4 p = *(const float4*)(simP + (size_t)ksi * (N_ * N_) + gid * 4);
    s.x += p.x; s.y += p.y; s.z += p.z; s.w += p.w;
  }
  *(float4*)(sim + gid * 4) = s;
}

// ---------------- 3. top-45 per row ----------------
__global__ __launch_bounds__(256) void k_topk(const float* __restrict__ sim,
                                              int* __restrict__ idx_t) {
  int t = threadIdx.x, lane = t & 63, wv = t >> 6;
  int n = blockIdx.x * 4 + wv;
  float v[8];
#pragma unroll
  for (int u = 0; u < 8; ++u) {
    int idx = u * 64 + lane;
    v[u] = (idx == n) ? -3e38f : sim[n * N_ + idx];
  }
  for (int k = 0; k < TK_; ++k) {
    float mv = v[0]; int mi = lane;
#pragma unroll
    for (int u = 1; u < 8; ++u) {
      if (v[u] > mv) { mv = v[u]; mi = u * 64 + lane; }
    }
#pragma unroll
    for (int o = 32; o > 0; o >>= 1) {
      float ov = __shfl_xor(mv, o);
      int   oi = __shfl_xor(mi, o);
      if (ov > mv || (ov == mv && oi < mi)) { mv = ov; mi = oi; }
    }
    if (lane == 0) idx_t[k * N_ + n] = mi;
#pragma unroll
    for (int u = 0; u < 8; ++u)
      if (mi == u * 64 + lane) v[u] = -3e38f;
  }
}

// ---------------- 4a. router stats partials + x->bf16 ----------------
__global__ __launch_bounds__(256) void k_rstats(const float* __restrict__ x,
                                                float* __restrict__ psum,
                                                float* __restrict__ psq,
                                                short* __restrict__ xbf) {
  int b  = blockIdx.x >> 6;
  int ch = blockIdx.x & 63;
  int t = threadIdx.x;
  size_t base = ((size_t)b * L_ + ch * 32) * N_;
  const float* xp = x + base;
  short* xq = xbf + base;
#pragma unroll
  for (int u = 0; u < 2; ++u) {
    int n = t + u * 256;
    float s = 0.f, ss = 0.f;
#pragma unroll 8
    for (int r = 0; r < 32; ++r) {
      float v = xp[r * N_ + n];
      s += v; ss += v * v;
      xq[r * N_ + n] = f2bf(v);
    }
    psum[(b * 64 + ch) * N_ + n] = s;
    psq [(b * 64 + ch) * N_ + n] = ss;
  }
}

// ---------------- 4b. finalize ----------------
__global__ __launch_bounds__(256) void k_rfinal(
    const float* __restrict__ psum, const float* __restrict__ psq,
    const float* __restrict__ var_embed,
    const float* __restrict__ temp_w, const float* __restrict__ temp_b,
    const float* __restrict__ q_w, const float* __restrict__ q_b,
    const float* __restrict__ k_w, const float* __restrict__ k_b,
    const float* __restrict__ imp_w, const float* __restrict__ imp_b,
    float* __restrict__ Q, float* __restrict__ Kv,
    float* __restrict__ imp, float* __restrict__ summary) {
  int gid = blockIdx.x * 256 + threadIdx.x;
  int b = gid >> 9, n = gid & 511;
  float s = 0.f, ss = 0.f;
#pragma unroll 8
  for (int c = 0; c < 64; ++c) {
    s  += psum[(b * 64 + c) * N_ + n];
    ss += psq [(b * 64 + c) * N_ + n];
  }
  float mean = s * (1.f / L_);
  float var  = fmaxf((ss - s * mean) * (1.f / (L_ - 1)), 0.f);
  float stdv = sqrtf(var + 1e-5f);
  summary[b * N_ + n] = mean;
  float vf[32];
#pragma unroll
  for (int i = 0; i < 16; ++i) vf[i] = var_embed[n * 16 + i];
#pragma unroll
  for (int h = 0; h < 16; ++h)
    vf[16 + h] = mean * temp_w[h] + stdv * temp_w[16 + h] + temp_b[h];
#pragma unroll
  for (int h = 0; h < 16; ++h) {
    float qa = q_b[h], ka = k_b[h];
#pragma unroll
    for (int i = 0; i < 32; ++i) {
      qa += vf[i] * q_w[i * 16 + h];
      ka += vf[i] * k_w[i * 16 + h];
    }
    Q[(b * N_ + n) * 16 + h]  = qa;
    Kv[(b * N_ + n) * 16 + h] = ka;
  }
  float ia = imp_b[0];
#pragma unroll
  for (int i = 0; i < 32; ++i) ia += vf[i] * imp_w[i];
  imp[b * N_ + n] = sigmoidf_(ia);
}

// ---------------- 5. cw ----------------
__global__ __launch_bounds__(64) void k_cw(const float* __restrict__ cs,
                                           float* __restrict__ cw) {
  int n = blockIdx.x * 64 + threadIdx.x;
  if (n >= N_) return;
  float v[16], mx = -3e38f;
#pragma unroll
  for (int c = 0; c < 16; ++c) { v[c] = cs[n * 16 + c]; mx = fmaxf(mx, v[c]); }
  float s = 0.f;
#pragma unroll
  for (int c = 0; c < 16; ++c) { v[c] = expf(v[c] - mx); s += v[c]; }
  float inv = 1.f / s;
#pragma unroll
  for (int c = 0; c < 16; ++c) cw[n * 16 + c] = v[c] * inv;
}

// ---------------- 6. center tokens ----------------
__global__ __launch_bounds__(256) void k_ct(const float* __restrict__ summary,
                                            const float* __restrict__ cg_w,
                                            const float* __restrict__ cg_b,
                                            float* __restrict__ ct) {
  int i = blockIdx.x * 256 + threadIdx.x;
  int b = i >> 10, o = i & 1023;
  float a = cg_b[o];
  for (int n = 0; n < N_; ++n) a += summary[b * N_ + n] * cg_w[n * 1024 + o];
  ct[i] = a;
}

// ---------------- 7. misc precomputes ----------------
__global__ __launch_bounds__(1024) void k_cp2s(const float* __restrict__ cp2_w,
                                               const float* __restrict__ cp2_b,
                                               const float* __restrict__ vp_b,
                                               const float* __restrict__ vp_w,
                                               const float* __restrict__ cp1_w,
                                               float* __restrict__ misc) {
  int t = threadIdx.x;
  if (t < 64) {
    float a = 0.f;
#pragma unroll 8
    for (int d = 0; d < 64; ++d) a += cp2_w[t * 64 + d];
    misc[t] = a;
    float vb = 0.f;
#pragma unroll 8
    for (int e = 0; e < 64; ++e) vb += vp_b[e] * cp1_w[e * 64 + t];
    misc[80 + t] = vb;
  }
  if (t == 0) {
    float bsum = 0.f;
    for (int d = 0; d < 64; ++d) bsum += cp2_b[d];
    misc[64] = bsum;
  }
  {
    int c = t >> 6, d = t & 63;
    float a = 0.f;
#pragma unroll 8
    for (int e = 0; e < 64; ++e) a += vp_w[c * 64 + e] * cp1_w[e * 64 + d];
    misc[96 + t] = a;  // vp1[c][d]
  }
}

// ---------------- 8. ctp' ----------------
__global__ __launch_bounds__(256) void k_ctp(const float* __restrict__ ct,
                                             const float* __restrict__ cp1_w,
                                             const float* __restrict__ cp1_b,
                                             const float* __restrict__ misc,
                                             float* __restrict__ ctp) {
  int i = blockIdx.x * 256 + threadIdx.x;
  int row = i >> 6, d2 = i & 63;
  float a = cp1_b[d2] + misc[80 + d2];
#pragma unroll 8
  for (int d = 0; d < 64; ++d) a += ct[row * 64 + d] * cp1_w[d * 64 + d2];
  ctp[i] = a;
}

// ---------------- 9. W2t ----------------
__global__ __launch_bounds__(256) void k_w2(const float* __restrict__ cw,
                                            const float* __restrict__ misc,
                                            short* __restrict__ w2t) {
  int gid = blockIdx.x * 256 + threadIdx.x;
  int d = gid >> 9, m = gid & 511;
  float a = 0.f;
#pragma unroll
  for (int c = 0; c < 16; ++c)
    a += cw[m * 16 + c] * misc[96 + c * 64 + d];
  w2t[d * 512 + m] = f2bf(a);
}

// ---------------- 10. wg2 ----------------
__global__ __launch_bounds__(256) void k_wg2(const float* __restrict__ cw,
                                             const float* __restrict__ gate_w,
                                             float* __restrict__ wg2) {
  int gid = blockIdx.x * 256 + threadIdx.x;
  int c = gid >> 9, n = gid & 511;
  float a = 0.f;
  for (int m = 0; m < 512; ++m)
    a += cw[m * 16 + c] * gate_w[(size_t)(512 + m) * 512 + n];
  wg2[c * 512 + n] = a;
}

// ---------------- 11. xcp = xbf @ W2t ----------------
__global__ __launch_bounds__(256) void k_xcp(const short* __restrict__ xbf,
                                             const short* __restrict__ w2t,
                                             float* __restrict__ xcp) {
  __shared__ __align__(16) short As[64 * 32];
  __shared__ __align__(16) short Bs[64 * 32];
  int t = threadIdx.x, lane = t & 63, w = t >> 6;
  int lo = lane & 15, hi = lane >> 4;
  int row0 = blockIdx.x * 64;
  f32x4 acc[4] = {};
  int rA = t >> 2, cA = (t & 3) ^ ((rA >> 1) & 3);
  const short* srcA = xbf + (size_t)(row0 + rA) * 512 + cA * 8;
  const short* srcB = w2t + (size_t)rA * 512 + cA * 8;
  int gl = (lo >> 1) & 3;
  int foff = (lo * 4 + (hi ^ gl)) * 8;
  for (int kt = 0; kt < 16; ++kt) {
    gload16(srcA + kt * 32, As + t * 8);
    gload16(srcB + kt * 32, Bs + t * 8);
    __syncthreads();
    bf16x8 b = *(const bf16x8*)(Bs + (w * 64) * 8 + foff);
#pragma unroll
    for (int m = 0; m < 4; ++m) {
      bf16x8 a = *(const bf16x8*)(As + (m * 64) * 8 + foff);
      acc[m] = __builtin_amdgcn_mfma_f32_16x16x32_bf16(a, b, acc[m], 0, 0, 0);
    }
    __syncthreads();
  }
#pragma unroll
  for (int m = 0; m < 4; ++m)
#pragma unroll
    for (int j = 0; j < 4; ++j) {
      int row = row0 + m * 16 + hi * 4 + j;
      int col = w * 16 + lo;
      xcp[(size_t)row * 64 + col] = acc[m][j];
    }
}

// ---------------- 12. s2 -> abuf[512..543] ----------------
__global__ __launch_bounds__(256) void k_s(const float* __restrict__ xcp,
                                           const float* __restrict__ ctp,
                                           const float* __restrict__ misc,
                                           short* __restrict__ abuf) {
  int t = threadIdx.x, lane = t & 63, wv = t >> 6;
  int row = blockIdx.x * 4 + wv;
  int b = row >> 11;
  float v = xcp[(size_t)row * 64 + lane];
  float wgt = misc[lane];
  float bias = misc[64];
  float sval = 0.f;
#pragma unroll
  for (int c = 0; c < 16; ++c) {
    float u = ctp[(b * 16 + c) * 64 + lane] + v;
    float g = 0.5f * u * (1.f + erff(u * 0.70710678118654752f));
    float a = g * wgt;
#pragma unroll
    for (int o = 32; o > 0; o >>= 1) a += __shfl_xor(a, o);
    if (lane == c) sval = a + bias;
  }
  if (lane < 32)
    abuf[(size_t)row * 1024 + 512 + lane] = (lane < 16) ? f2bf(sval) : (short)0;
}

// ---------------- 13. attention -> dense At scatter ----------------
__global__ __launch_bounds__(64) void k_attn(const float* __restrict__ Q,
                                             const float* __restrict__ Kv,
                                             const int* __restrict__ idx_t,
                                             short* __restrict__ At) {
  int bn = blockIdx.x;
  int b = bn >> 9, n = bn & (N_ - 1);
  int j = threadIdx.x;
  float s = -3e38f;
  int m = 0;
  if (j < TK_) {
    m = idx_t[j * N_ + n];
    const float* qp = Q + (b * N_ + n) * H_;
    const float* kp = Kv + (b * N_ + m) * H_;
    float a = 0.f;
#pragma unroll
    for (int h = 0; h < H_; ++h) a += qp[h] * kp[h];
    s = a * 0.25f;
  }
  float mx = s;
#pragma unroll
  for (int o = 32; o > 0; o >>= 1) mx = fmaxf(mx, __shfl_xor(mx, o));
  float e = (j < TK_) ? expf(s - mx) : 0.f;
  float sum = e;
#pragma unroll
  for (int o = 32; o > 0; o >>= 1) sum += __shfl_xor(sum, o);
  if (j < TK_) At[((size_t)b * N_ + n) * N_ + m] = f2bf(e / sum);
}

// ---------------- 14. ring GEMM (pipelined 128x128): routed + blend ----------------
__global__ __launch_bounds__(256) void k_rgemm(const short* __restrict__ xbf,
                                               const short* __restrict__ At,
                                               const float* __restrict__ imp,
                                               const float* __restrict__ x,
                                               short* __restrict__ abuf) {
  __shared__ __align__(16) short As[2][128 * 32];
  __shared__ __align__(16) short Bs[2][128 * 32];
  int t = threadIdx.x, lane = t & 63, w = t >> 6;
  int lo = lane & 15, hi = lane >> 4;
  int b = blockIdx.x >> 6;
  int tile = blockIdx.x & 63;
  int bm = tile >> 2, bn = tile & 3;
  int row0 = b * L_ + bm * 128, n0 = bn * 128;
  int wm = w >> 1, wn = w & 1;
  f32x4 acc[4][4] = {};
  int p0 = t, p1 = t + 256;
  int r0s = p0 >> 2, c0s = (p0 & 3) ^ ((r0s >> 1) & 3);
  int r1s = p1 >> 2, c1s = (p1 & 3) ^ ((r1s >> 1) & 3);
  const short* sA0 = xbf + (size_t)(row0 + r0s) * 512 + c0s * 8;
  const short* sA1 = xbf + (size_t)(row0 + r1s) * 512 + c1s * 8;
  const short* sB0 = At + ((size_t)b * N_ + n0 + r0s) * 512 + c0s * 8;
  const short* sB1 = At + ((size_t)b * N_ + n0 + r1s) * 512 + c1s * 8;
  int gl = (lo >> 1) & 3;
  int foff = (lo * 4 + (hi ^ gl)) * 8;
  // prologue: stage tile 0
  gload16(sA0, As[0] + p0 * 8);
  gload16(sA1, As[0] + p1 * 8);
  gload16(sB0, Bs[0] + p0 * 8);
  gload16(sB1, Bs[0] + p1 * 8);
  __syncthreads();
  int cur = 0;
  for (int i = 0; i < 16; ++i) {
    if (i < 15) {
      int kt = i + 1;
      gload16(sA0 + kt * 32, As[cur ^ 1] + p0 * 8);
      gload16(sA1 + kt * 32, As[cur ^ 1] + p1 * 8);
      gload16(sB0 + kt * 32, Bs[cur ^ 1] + p0 * 8);
      gload16(sB1 + kt * 32, Bs[cur ^ 1] + p1 * 8);
    }
    bf16x8 a[4], bb[4];
#pragma unroll
    for (int m = 0; m < 4; ++m)
      a[m] = *(const bf16x8*)(As[cur] + (wm * 64 + m * 16) * 32 + foff);
#pragma unroll
    for (int n = 0; n < 4; ++n)
      bb[n] = *(const bf16x8*)(Bs[cur] + (wn * 64 + n * 16) * 32 + foff);
#pragma unroll
    for (int m = 0; m < 4; ++m)
#pragma unroll
      for (int n = 0; n < 4; ++n)
        acc[m][n] = __builtin_amdgcn_mfma_f32_16x16x32_bf16(a[m], bb[n], acc[m][n], 0, 0, 0);
    __syncthreads();
    cur ^= 1;
  }
#pragma unroll
  for (int m = 0; m < 4; ++m) {
    int rbase = row0 + wm * 64 + m * 16 + hi * 4;
#pragma unroll
    for (int j = 0; j < 4; ++j) {
      int row = rbase + j;
#pragma unroll
      for (int n = 0; n < 4; ++n) {
        int col = n0 + wn * 64 + n * 16 + lo;
        float iv = imp[b * N_ + col];
        float xv = x[(size_t)row * 512 + col];
        abuf[(size_t)row * 1024 + col] = f2bf(iv * acc[m][n][j] + (1.f - iv) * xv);
      }
    }
  }
}

// ---------------- 15. wt_gate ----------------
__global__ __launch_bounds__(256) void k_wtg(const float* __restrict__ gate_w,
                                             const float* __restrict__ wg2,
                                             short* __restrict__ wt) {
  __shared__ float tile[32][33];
  int bk = blockIdx.x;
  int bn = blockIdx.y;
  int t = threadIdx.x;
  int c = t & 31, r = t >> 5;
  if (bk < 16) {
    for (int rr = r; rr < 32; rr += 8)
      tile[rr][c] = gate_w[(size_t)(bk * 32 + rr) * 512 + bn * 32 + c];
  } else {
    for (int rr = r; rr < 32; rr += 8)
      tile[rr][c] = (rr < 16) ? wg2[rr * 512 + bn * 32 + c] : 0.f;
  }
  __syncthreads();
  for (int rr = r; rr < 32; rr += 8)
    wt[(size_t)(bn * 32 + rr) * 1024 + bk * 32 + c] = f2bf(tile[c][rr]);
}

// ---------------- 16. fus weights transpose ----------------
__global__ __launch_bounds__(256) void k_wt(const float* __restrict__ W,
                                            short* __restrict__ Wt, int K, int N) {
  __shared__ float tile[32][33];
  int bk = blockIdx.x, bn = blockIdx.y;
  int t = threadIdx.x;
  int c = t & 31, r = t >> 5;
  for (int rr = r; rr < 32; rr += 8)
    tile[rr][c] = W[(bk * 32 + rr) * N + bn * 32 + c];
  __syncthreads();
  for (int rr = r; rr < 32; rr += 8)
    Wt[(bn * 32 + rr) * K + bk * 32 + c] = f2bf(tile[c][rr]);
}

// ---------------- 17. cwb ----------------
__global__ __launch_bounds__(256) void k_cwb(const float* __restrict__ cw,
                                             short* __restrict__ cwb) {
  int gid = blockIdx.x * 256 + threadIdx.x;
  int n = gid >> 5, kk = gid & 31;
  cwb[gid] = (kk < 16) ? f2bf(cw[n * 16 + kk]) : (short)0;
}

// ---------------- 18. gate GEMM (pipelined 128x128, K=544) ----------------
__global__ __launch_bounds__(256) void k_gemm_gate(const short* __restrict__ abuf,
                                                   const short* __restrict__ wt,
                                                   const short* __restrict__ cwb,
                                                   const float* __restrict__ gate_b,
                                                   short* __restrict__ fused_bf) {
  __shared__ __align__(16) short As[2][128 * 32];
  __shared__ __align__(16) short Bs[2][128 * 32];
  int t = threadIdx.x, lane = t & 63, w = t >> 6;
  int lo = lane & 15, hi = lane >> 4;
  int bm = blockIdx.x >> 2, bn = blockIdx.x & 3;
  int row0 = bm * 128, n0 = bn * 128;
  int wm = w >> 1, wn = w & 1;
  f32x4 acc[4][4] = {};
  f32x4 acc2[4][4] = {};
  int p0 = t, p1 = t + 256;
  int r0s = p0 >> 2, c0s = (p0 & 3) ^ ((r0s >> 1) & 3);
  int r1s = p1 >> 2, c1s = (p1 & 3) ^ ((r1s >> 1) & 3);
  const short* sA0 = abuf + (size_t)(row0 + r0s) * 1024 + c0s * 8;
  const short* sA1 = abuf + (size_t)(row0 + r1s) * 1024 + c1s * 8;
  const short* sB0 = wt + (size_t)(n0 + r0s) * 1024 + c0s * 8;
  const short* sB1 = wt + (size_t)(n0 + r1s) * 1024 + c1s * 8;
  int gl = (lo >> 1) & 3;
  int foff = (lo * 4 + (hi ^ gl)) * 8;
  // prologue: buf0 <- {A s2-tile (kt=16), cwb}; buf1 <- main tile 0
  gload16(sA0 + 16 * 32, As[0] + p0 * 8);
  gload16(sA1 + 16 * 32, As[0] + p1 * 8);
  gload16(cwb + (size_t)(n0 + r0s) * 32 + c0s * 8, Bs[0] + p0 * 8);
  gload16(cwb + (size_t)(n0 + r1s) * 32 + c1s * 8, Bs[0] + p1 * 8);
  gload16(sA0, As[1] + p0 * 8);
  gload16(sA1, As[1] + p1 * 8);
  gload16(sB0, Bs[1] + p0 * 8);
  gload16(sB1, Bs[1] + p1 * 8);
  __syncthreads();
  // i=0: acc2 = s2-tile @ cwb
  {
    bf16x8 a[4], bb[4];
#pragma unroll
    for (int m = 0; m < 4; ++m)
      a[m] = *(const bf16x8*)(As[0] + (wm * 64 + m * 16) * 32 + foff);
#pragma unroll
    for (int n = 0; n < 4; ++n)
      bb[n] = *(const bf16x8*)(Bs[0] + (wn * 64 + n * 16) * 32 + foff);
#pragma unroll
    for (int m = 0; m < 4; ++m)
#pragma unroll
      for (int n = 0; n < 4; ++n)
        acc2[m][n] = __builtin_amdgcn_mfma_f32_16x16x32_bf16(a[m], bb[n], acc2[m][n], 0, 0, 0);
  }
  __syncthreads();
  int cur = 1;
  for (int i = 1; i <= 17; ++i) {
    if (i < 17) {
      int kt = i;  // consumed at i+1
      gload16(sA0 + kt * 32, As[cur ^ 1] + p0 * 8);
      gload16(sA1 + kt * 32, As[cur ^ 1] + p1 * 8);
      gload16(sB0 + kt * 32, Bs[cur ^ 1] + p0 * 8);
      gload16(sB1 + kt * 32, Bs[cur ^ 1] + p1 * 8);
    }
    bf16x8 a[4], bb[4];
#pragma unroll
    for (int m = 0; m < 4; ++m)
      a[m] = *(const bf16x8*)(As[cur] + (wm * 64 + m * 16) * 32 + foff);
#pragma unroll
    for (int n = 0; n < 4; ++n)
      bb[n] = *(const bf16x8*)(Bs[cur] + (wn * 64 + n * 16) * 32 + foff);
#pragma unroll
    for (int m = 0; m < 4; ++m)
#pragma unroll
      for (int n = 0; n < 4; ++n)
        acc[m][n] = __builtin_amdgcn_mfma_f32_16x16x32_bf16(a[m], bb[n], acc[m][n], 0, 0, 0);
    __syncthreads();
    cur ^= 1;
  }
#pragma unroll
  for (int m = 0; m < 4; ++m) {
    int rbase = row0 + wm * 64 + m * 16 + hi * 4;
#pragma unroll
    for (int j = 0; j < 4; ++j) {
      int row = rbase + j;
#pragma unroll
      for (int n = 0; n < 4; ++n) {
        int col = n0 + wn * 64 + n * 16 + lo;
        float g = sigmoidf_(acc[m][n][j] + gate_b[col]);
        float ringv = bf2f(abuf[(size_t)row * 1024 + col]);
        fused_bf[(size_t)row * 512 + col] = f2bf(g * ringv + (1.f - g) * acc2[m][n][j]);
      }
    }
  }
}

// ---------------- 19. fus GEMM (pipelined) + residual + LayerNorm ----------------
__global__ __launch_bounds__(512) void k_gemm_fus(const short* __restrict__ fused_bf,
                                                  const short* __restrict__ wtf,
                                                  const float* __restrict__ x,
                                                  const float* __restrict__ fus_b,
                                                  const float* __restrict__ ln_g,
                                                  const float* __restrict__ ln_b,
                                                  float* __restrict__ out) {
  __shared__ __align__(16) short As[2][64 * 32];
  __shared__ __align__(16) short Bs[2][512 * 32];
  __shared__ float Ssh[8][64], Qsh[8][64];
  __shared__ float mus[64], rss[64];
  int t = threadIdx.x, lane = t & 63, w = t >> 6;
  int lo = lane & 15, hi = lane >> 4;
  int row0 = blockIdx.x * 64;
  f32x4 acc[4][4] = {};
  int pA = w * 64 + lane;
  int rA = pA >> 2, cA = (pA & 3) ^ ((rA >> 1) & 3);
  const short* srcA = fused_bf + (size_t)(row0 + rA) * 512 + cA * 8;
  int rB[4], cB[4];
  const short* srcB[4];
#pragma unroll
  for (int q = 0; q < 4; ++q) {
    int pB = w * 256 + q * 64 + lane;
    rB[q] = pB >> 2; cB[q] = (pB & 3) ^ ((rB[q] >> 1) & 3);
    srcB[q] = wtf + (size_t)rB[q] * 512 + cB[q] * 8;
  }
  int gl = (lo >> 1) & 3;
  int foff = (lo * 4 + (hi ^ gl)) * 8;
  // prologue: stage tile 0
  if (w < 4) gload16(srcA, As[0] + pA * 8);
#pragma unroll
  for (int q = 0; q < 4; ++q)
    gload16(srcB[q], Bs[0] + (w * 256 + q * 64) * 8);
  __syncthreads();
  int cur = 0;
  for (int i = 0; i < 16; ++i) {
    if (i < 15) {
      int kt = i + 1;
      if (w < 4) gload16(srcA + kt * 32, As[cur ^ 1] + pA * 8);
#pragma unroll
      for (int q = 0; q < 4; ++q)
        gload16(srcB[q] + kt * 32, Bs[cur ^ 1] + (w * 256 + q * 64) * 8);
    }
    bf16x8 a[4], b[4];
#pragma unroll
    for (int m = 0; m < 4; ++m)
      a[m] = *(const bf16x8*)(As[cur] + (m * 64) * 8 + foff);
#pragma unroll
    for (int n = 0; n < 4; ++n)
      b[n] = *(const bf16x8*)(Bs[cur] + (w * 256 + n * 64) * 8 + foff);
#pragma unroll
    for (int m = 0; m < 4; ++m)
#pragma unroll
      for (int n = 0; n < 4; ++n)
        acc[m][n] = __builtin_amdgcn_mfma_f32_16x16x32_bf16(a[m], b[n], acc[m][n], 0, 0, 0);
    __syncthreads();
    cur ^= 1;
  }
#pragma unroll
  for (int m = 0; m < 4; ++m) {
#pragma unroll
    for (int j = 0; j < 4; ++j) {
      int rl = m * 16 + hi * 4 + j;
      int row = row0 + rl;
      float ps = 0.f, pq = 0.f;
#pragma unroll
      for (int n = 0; n < 4; ++n) {
        int col = w * 64 + n * 16 + lo;
        float h = acc[m][n][j] + fus_b[col] + x[(size_t)row * 512 + col];
        acc[m][n][j] = h;
        ps += h; pq += h * h;
      }
#pragma unroll
      for (int o = 1; o < 16; o <<= 1) {
        ps += __shfl_xor(ps, o);
        pq += __shfl_xor(pq, o);
      }
      if (lo == 0) { Ssh[w][rl] = ps; Qsh[w][rl] = pq; }
    }
  }
  __syncthreads();
  if (t < 64) {
    float s = 0.f, q = 0.f;
#pragma unroll
    for (int ww = 0; ww < 8; ++ww) { s += Ssh[ww][t]; q += Qsh[ww][t]; }
    float mu = s * (1.f / N_);
    float var = q * (1.f / N_) - mu * mu;
    mus[t] = mu;
    rss[t] = rsqrtf(fmaxf(var, 0.f) + 1e-5f);
  }
  __syncthreads();
#pragma unroll
  for (int m = 0; m < 4; ++m) {
#pragma unroll
    for (int j = 0; j < 4; ++j) {
      int rl = m * 16 + hi * 4 + j;
      int row = row0 + rl;
      float mu = mus[rl], rs = rss[rl];
#pragma unroll
      for (int n = 0; n < 4; ++n) {
        int col = w * 64 + n * 16 + lo;
        out[(size_t)row * 512 + col] = (acc[m][n][j] - mu) * rs * ln_g[col] + ln_b[col];
      }
    }
  }
}

extern "C" void kernel_launch(void* const* d_in, const int* in_sizes, int n_in,
                              void* d_out, int out_size, void* d_ws, size_t ws_size,
                              hipStream_t stream) {
  (void)in_sizes; (void)n_in; (void)out_size; (void)ws_size;
  const float* x         = (const float*)d_in[0];
  const float* var_embed = (const float*)d_in[1];
  const float* temp_w    = (const float*)d_in[2];
  const float* temp_b    = (const float*)d_in[3];
  const float* q_w       = (const float*)d_in[4];
  const float* q_b       = (const float*)d_in[5];
  const float* k_w       = (const float*)d_in[6];
  const float* k_b       = (const float*)d_in[7];
  const float* imp_w     = (const float*)d_in[8];
  const float* imp_b     = (const float*)d_in[9];
  const float* cluster   = (const float*)d_in[10];
  const float* vp_w      = (const float*)d_in[11];
  const float* vp_b      = (const float*)d_in[12];
  const float* cp1_w     = (const float*)d_in[13];
  const float* cp1_b     = (const float*)d_in[14];
  const float* cp2_w     = (const float*)d_in[15];
  const float* cp2_b     = (const float*)d_in[16];
  const float* cg_w      = (const float*)d_in[17];
  const float* cg_b      = (const float*)d_in[18];
  const float* gate_w    = (const float*)d_in[19];
  const float* gate_b    = (const float*)d_in[20];
  const float* fus_w     = (const float*)d_in[21];
  const float* fus_b     = (const float*)d_in[22];
  const float* ln_g      = (const float*)d_in[23];
  const float* ln_b      = (const float*)d_in[24];
  float* out = (float*)d_out;
  float* ws  = (float*)d_ws;

  float* normed = ws + 0;                 // normed -> xcp -> At (3 lives)
  float* sim    = ws + 1048576;
  int*   idx_t  = (int*)(ws + 1310720);
  float* Qb     = ws + 1335296;
  float* Kb     = ws + 1400832;
  float* impb   = ws + 1466368;
  float* summ   = ws + 1470464;
  float* cw     = ws + 1658880;
  float* ct     = ws + 1667072;
  float* ctp    = ws + 1675264;
  float* misc   = ws + 1683456;
  float* wg2    = ws + 1685504;
  short* w2t    = (short*)(ws + 1693696);
  short* cwb    = (short*)(ws + 1710080);
  short* abuf     = (short*)(ws + 1720320);   // 32 MB
  short* fused_bf = (short*)(ws + 10108928);  // 16 MB (also xbf)
  short* wt_gate  = (short*)(ws + 14303232);
  short* wt_fus   = (short*)(ws + 14565376);
  float* psum     = ws + 14696448;
  float* psq      = ws + 14958592;
  float* simP = (float*)abuf;
  float* xcp  = normed;
  short* At   = (short*)normed;
  short* xbf  = fused_bf;

  k_normed<<<(L_ * N_) / 256, 256, 0, stream>>>(x, normed);
  k_sim<<<64 * KS_, 256, 0, stream>>>(normed, simP);
  k_simred<<<256, 256, 0, stream>>>(simP, sim);
  k_topk<<<N_ / 4, 256, 0, stream>>>(sim, idx_t);
  k_rstats<<<B_ * 64, 256, 0, stream>>>(x, psum, psq, xbf);
  k_rfinal<<<16, 256, 0, stream>>>(psum, psq, var_embed, temp_w, temp_b, q_w, q_b,
                                   k_w, k_b, imp_w, imp_b, Qb, Kb, impb, summ);
  k_cw<<<8, 64, 0, stream>>>(cluster, cw);
  k_cp2s<<<1, 1024, 0, stream>>>(cp2_w, cp2_b, vp_b, vp_w, cp1_w, misc);
  k_ct<<<(B_ * 1024) / 256, 256, 0, stream>>>(summ, cg_w, cg_b, ct);
  k_ctp<<<(B_ * C_ * D_) / 256, 256, 0, stream>>>(ct, cp1_w, cp1_b, misc, ctp);
  k_w2<<<128, 256, 0, stream>>>(cw, misc, w2t);
  k_wg2<<<32, 256, 0, stream>>>(cw, gate_w, wg2);
  k_xcp<<<L_ * B_ / 64, 256, 0, stream>>>(xbf, w2t, xcp);
  k_s<<<L_ * B_ / 4, 256, 0, stream>>>(xcp, ctp, misc, abuf);
  hipMemsetAsync(At, 0, (size_t)B_ * N_ * N_ * 2, stream);
  k_attn<<<B_ * N_, 64, 0, stream>>>(Qb, Kb, idx_t, At);
  k_wtg<<<dim3(17, 16), 256, 0, stream>>>(gate_w, wg2, wt_gate);
  k_wt<<<dim3(16, 16), 256, 0, stream>>>(fus_w, wt_fus, 512, 512);
  k_cwb<<<64, 256, 0, stream>>>(cw, cwb);
  k_rgemm<<<B_ * 64, 256, 0, stream>>>(xbf, At, impb, x, abuf);
  k_gemm_gate<<<512, 256, 0, stream>>>(abuf, wt_gate, cwb, gate_b, fused_bf);
  k_gemm_fus<<<256, 512, 0, stream>>>(fused_bf, wt_fus, x, fus_b, ln_g, ln_b, out);
}